// Round 8
// baseline (3874.927 us; speedup 1.0000x reference)
//
#include <hip/hip_runtime.h>

#define NEG_INF_F (-1e30f)
#define MAX_S 2048
#define MAX_C 3008
#define NCH   128

// ============================ build helpers (deterministic) ============================

__global__ void zero_kernel(int* __restrict__ p, int n) {
  int i = blockIdx.x * blockDim.x + threadIdx.x;
  if (i < n) p[i] = 0;
}

__global__ void hist_kernel(const int* __restrict__ dst, int A, int A_stride,
                            int* __restrict__ cnt, int S) {
  int b = blockIdx.y;
  int i = blockIdx.x * blockDim.x + threadIdx.x;
  if (i < A) atomicAdd(&cnt[b * S + dst[(size_t)b * A_stride + i]], 1);
}

__global__ void hist_chunk_kernel(const int* __restrict__ dst, int A, int chunk, int S,
                                  int* __restrict__ hist) {
  int c = blockIdx.x;
  int i1 = min(A, (c + 1) * chunk);
  for (int i = c * chunk + threadIdx.x; i < i1; i += blockDim.x)
    atomicAdd(&hist[c * S + dst[i]], 1);
}

__global__ void colsum_kernel(const int* __restrict__ hist, int nch, int S,
                              int* __restrict__ cnt) {
  int s = blockIdx.x * blockDim.x + threadIdx.x;
  if (s < S) {
    int t = 0;
    for (int c = 0; c < nch; ++c) t += hist[c * S + s];
    cnt[s] = t;
  }
}

// Stable in-degree rank (desc) -> slot permutation pairing heavy with light.
__global__ __launch_bounds__(1024)
void rank_perm_kernel(const int* __restrict__ cnt, int S,
                      int* __restrict__ perm, int* __restrict__ invperm) {
  __shared__ int c[2048];
  __shared__ int R[2048];
  const int tid = threadIdx.x;
  for (int i = tid; i < 2048; i += 1024) c[i] = (i < S) ? cnt[i] : -1;
  __syncthreads();
  for (int u = 0; u < 2; ++u) {
    int s = tid + u * 1024;
    if (s < S) {
      int cs = c[s], r = 0;
      for (int j = 0; j < S; ++j) {
        int cj = c[j];
        r += (cj > cs) || (cj == cs && j < s);
      }
      R[r] = s;
    }
  }
  __syncthreads();
  for (int u = 0; u < 2; ++u) {
    int slot = tid + u * 1024;
    if (slot < S) {
      int state = (slot < 1024) ? R[slot] : R[S - 1 - (slot - 1024)];
      perm[slot] = state;
      invperm[state] = slot;
    }
  }
}

__global__ void pc_kernel(const int* __restrict__ cnt, const int* __restrict__ perm,
                          int S, int* __restrict__ pc) {
  int slot = blockIdx.x * blockDim.x + threadIdx.x;
  if (slot < 2048) pc[slot] = (slot < S) ? ((cnt[perm[slot]] + 3) & ~3) : 0;
}

__global__ void padcnt_kernel(const int* __restrict__ cnt, int n, int* __restrict__ out) {
  int i = blockIdx.x * blockDim.x + threadIdx.x;
  if (i < n) out[i] = (cnt[i] + 3) & ~3;
}

__global__ __launch_bounds__(1024) void scan_kernel(const int* __restrict__ cnt,
                                                    int* __restrict__ rp, int S) {
  __shared__ int buf[2][2048];
  const int tid = threadIdx.x;
  const int b = blockIdx.x;
  const int* c = cnt + (size_t)b * S;
  int* r = rp + (size_t)b * (S + 1);
  for (int u = 0; u < 2; ++u) {
    int i = tid + u * 1024;
    buf[0][i] = (i < S) ? c[i] : 0;
  }
  __syncthreads();
  int cur = 0;
  for (int off = 1; off < 2048; off <<= 1) {
    for (int u = 0; u < 2; ++u) {
      int i = tid + u * 1024;
      buf[cur ^ 1][i] = buf[cur][i] + ((i >= off) ? buf[cur][i - off] : 0);
    }
    __syncthreads();
    cur ^= 1;
  }
  for (int u = 0; u < 2; ++u) {
    int i = tid + u * 1024;
    if (i <= S) r[i] = (i == 0) ? 0 : buf[cur][i - 1];
  }
  if (tid == 0) r[S] = buf[cur][S - 1];
}

__global__ void off_perm_kernel(int* __restrict__ hist, int nch, int S,
                                const int* __restrict__ rp, const int* __restrict__ perm) {
  int slot = blockIdx.x * blockDim.x + threadIdx.x;
  if (slot < S) {
    int state = perm[slot];
    int run = rp[slot];
    for (int c = 0; c < nch; ++c) {
      int h = hist[c * S + slot * 0 + state];
      hist[c * S + state] = run;
      run += h;
    }
  }
}

// fill pad arcs at row tails (den): y==0 marks pad (ew = 0)
__global__ void pad_den_kernel(const int* __restrict__ rp, const int* __restrict__ cnt,
                               const int* __restrict__ perm, int S, uint2* __restrict__ meta) {
  int slot = blockIdx.x * blockDim.x + threadIdx.x;
  if (slot < S) {
    int p = rp[slot] + cnt[perm[slot]];
    int e = rp[slot + 1];
    uint2 pad = make_uint2(0u, 0u);
    for (; p < e; ++p) meta[p] = pad;
  }
}

// DEN meta: x = (src_slot*4) | ((pdf*4)<<16)  (pre-scaled LDS byte offsets), y = exp(w).
__global__ void fill_chunk_kernel(const int* __restrict__ src, const int* __restrict__ dst,
                                  const int* __restrict__ pdf, const float* __restrict__ w,
                                  int A, int chunk, int S, int* __restrict__ hoff,
                                  const int* __restrict__ inv, uint2* __restrict__ meta) {
  int c = blockIdx.y;
  int s = blockIdx.x * blockDim.x + threadIdx.x;
  if (s >= S) return;
  int i1 = min(A, (c + 1) * chunk);
  int p = hoff[c * S + s];
  for (int i = c * chunk; i < i1; ++i) {
    if (dst[i] == s) {
      meta[p++] = make_uint2((unsigned)(inv[src[i]] * 4) | ((unsigned)(pdf[i] * 4) << 16),
                             __float_as_uint(__expf(w[i])));
    }
  }
}

// numerator meta keeps index packing (src | pdf<<16) + raw w
__global__ void fill_kernel(const int* __restrict__ src, const int* __restrict__ dst,
                            const int* __restrict__ pdf, const float* __restrict__ w,
                            int A, int A_stride, const int* __restrict__ rp, int S,
                            uint2* __restrict__ meta, int meta_stride) {
  int b = blockIdx.y;
  int s = blockIdx.x * blockDim.x + threadIdx.x;
  if (s >= S) return;
  const int*   sb = src + (size_t)b * A_stride;
  const int*   db = dst + (size_t)b * A_stride;
  const int*   pb = pdf + (size_t)b * A_stride;
  const float* wb = w   + (size_t)b * A_stride;
  const int*   rpb = rp + (size_t)b * (S + 1);
  uint2* mb = meta + (size_t)b * meta_stride;
  int p = rpb[s];
  for (int i = 0; i < A; ++i) {
    if (db[i] == s) {
      mb[p++] = make_uint2((unsigned)sb[i] | ((unsigned)pb[i] << 16), __float_as_uint(wb[i]));
    }
  }
  uint2 pad = make_uint2(0u, __float_as_uint(NEG_INF_F));
  int e = rpb[s + 1];
  for (; p < e; ++p) mb[p] = pad;
}

// ---- wave-interleaved den meta: desc = offA[16],offB[16],wmaxA[16],wmaxB[16],ok,total ----
__global__ __launch_bounds__(1024)
void wave_desc_kernel(const int* __restrict__ rp, int cap4, int* __restrict__ desc) {
  __shared__ int wm[32];
  const int tid = threadIdx.x;
  const int w = tid >> 6;
  int cA = (rp[tid + 1] - rp[tid]) >> 2;
  int sB = 2047 - tid;
  int cB = (rp[sB + 1] - rp[sB]) >> 2;
  for (int off = 32; off; off >>= 1) {
    cA = max(cA, __shfl_down(cA, off));
    cB = max(cB, __shfl_down(cB, off));
  }
  if ((tid & 63) == 0) { wm[w] = cA; wm[16 + w] = cB; }
  __syncthreads();
  if (tid == 0) {
    int off = 0;
    for (int i = 0; i < 16; ++i) { desc[i] = off; off += wm[i] * 128; }
    for (int i = 0; i < 16; ++i) { desc[16 + i] = off; off += wm[16 + i] * 128; }
    for (int i = 0; i < 16; ++i) { desc[32 + i] = wm[i]; desc[48 + i] = wm[16 + i]; }
    desc[64] = (off <= cap4) ? 1 : 0;
    desc[65] = off;
  }
}

// Greedy bank-aware arc placement. grid 32 blocks x 64 lanes (1 wave each).
// Linear-space row sums are order-invariant (all terms >= 0), so any per-row
// arc->position assignment is numerically safe. Greedy minimizes per-position
// (gather) bank collisions for BOTH the vbuf(src) and elbuf(pdf) gathers.
__global__ __launch_bounds__(64)
void repack_greedy_kernel(const uint2* __restrict__ meta, const int* __restrict__ rp,
                          const int* __restrict__ desc, int C, uint2* __restrict__ ilv) {
  if (!desc[64]) return;
  const int w = blockIdx.x & 15;
  const bool isB = blockIdx.x >= 16;
  const int l = threadIdx.x;
  const int tid = w * 64 + l;
  const int s = isB ? (2047 - tid) : tid;
  const int base4 = desc[(isB ? 16 : 0) + w];
  const int wmax  = desc[(isB ? 48 : 32) + w];
  const int P = wmax * 4;
  const int r0 = rp[s];
  const int nA = rp[s + 1] - r0;

  if (P == 0) return;

  if (P > 64) {
    // fallback: order-preserving interleave copy
    const int n = nA >> 2;
    for (int c = 0; c < wmax; ++c) {
      for (int part = 0; part < 2; ++part) {
        int u4 = base4 + c * 128 + part * 64 + l;
        uint2 v0 = make_uint2(0u, 0u), v1 = make_uint2(0u, 0u);
        if (c < n) {
          v0 = meta[r0 + 4 * c + 2 * part];
          v1 = meta[r0 + 4 * c + 2 * part + 1];
        }
        ilv[2 * u4]     = v0;
        ilv[2 * u4 + 1] = v1;
      }
    }
    return;
  }

  __shared__ int loadS[64][32];
  __shared__ int loadP[64][32];
  __shared__ unsigned long long freeM[64];
  __shared__ int r0s[64], ns[64];

  for (int i = l; i < 64 * 32; i += 64) {
    ((int*)loadS)[i] = 0;
    ((int*)loadP)[i] = 0;
  }
  freeM[l] = (P >= 64) ? ~0ULL : ((1ULL << P) - 1ULL);
  r0s[l] = r0;
  ns[l]  = nA;
  __syncthreads();

  for (int r = 0; r < 64; ++r) {
    const int rr0 = r0s[r], rn = ns[r];
    for (int k = 0; k < rn; ++k) {
      uint2 a = meta[rr0 + k];           // uniform address -> broadcast
      if (a.y == 0u) continue;           // pad / zero-weight arc: contributes 0, drop
      const int bs = (a.x >> 2) & 31;    // vbuf bank (x stores src*4 in low16)
      const int bp = (a.x >> 18) & 31;   // elbuf bank (pdf*4 in high16)
      const bool valid = (l < P) && ((freeM[r] >> l) & 1ULL);
      int score = valid ? (loadS[l][bs] + loadP[l][bp]) : 0x7FFF;
      int v = score * 64 + l;
      for (int off = 32; off; off >>= 1) v = min(v, __shfl_xor(v, off));
      const int p = v & 63;
      if (l == p) {
        freeM[r] &= ~(1ULL << p);
        loadS[p][bs]++;
        loadP[p][bp]++;
        int idx = 2 * (base4 + (p >> 2) * 128 + (((p >> 1) & 1) * 64) + r) + (p & 1);
        ilv[idx] = a;
      }
      __syncthreads();
    }
  }

  // fill own row's remaining positions with bank-spread pads (ew = 0)
  unsigned long long fm = freeM[l];
  const int pc = min(s, C - 1);
  const uint2 pad = make_uint2((unsigned)(s * 4) | ((unsigned)(pc * 4) << 16), 0u);
  while (fm) {
    int p = __ffsll(fm) - 1;
    fm &= fm - 1ULL;
    int idx = 2 * (base4 + (p >> 2) * 128 + (((p >> 1) & 1) * 64) + l) + (p & 1);
    ilv[idx] = pad;
  }
}

// ============================ exact row LSE (numerator path) ============================

__device__ __forceinline__ float row_lse(const uint2* __restrict__ meta, int k, int e,
                                         const float* __restrict__ alpha,
                                         const float* __restrict__ lcur) {
  float mm0 = NEG_INF_F, ss0 = 0.0f, mm1 = NEG_INF_F, ss1 = 0.0f;
  const int n4 = (e - k) >> 2;
  const uint4* p = (const uint4*)(meta + k);
  if (n4 > 0) {
    uint4 A = p[0], Bv = p[1];
    float t0 = alpha[A.x & 0xFFFFu] + __uint_as_float(A.y) + lcur[A.x >> 16];
    float t1 = alpha[A.z & 0xFFFFu] + __uint_as_float(A.w) + lcur[A.z >> 16];
    float t2 = alpha[Bv.x & 0xFFFFu] + __uint_as_float(Bv.y) + lcur[Bv.x >> 16];
    float t3 = alpha[Bv.z & 0xFFFFu] + __uint_as_float(Bv.w) + lcur[Bv.z >> 16];
    for (int c2 = 1; c2 < n4; ++c2) {
      uint4 A2 = p[2 * c2], B2 = p[2 * c2 + 1];
      float u0 = alpha[A2.x & 0xFFFFu] + __uint_as_float(A2.y) + lcur[A2.x >> 16];
      float u1 = alpha[A2.z & 0xFFFFu] + __uint_as_float(A2.w) + lcur[A2.z >> 16];
      float u2 = alpha[B2.x & 0xFFFFu] + __uint_as_float(B2.y) + lcur[B2.x >> 16];
      float u3 = alpha[B2.z & 0xFFFFu] + __uint_as_float(B2.w) + lcur[B2.z >> 16];
      float mc = fmaxf(fmaxf(t0, t1), fmaxf(t2, t3));
      if ((c2 & 1) != 0) {
        float nm = fmaxf(mm0, mc);
        ss0 = ss0 * __expf(mm0 - nm) +
              ((__expf(t0 - nm) + __expf(t1 - nm)) + (__expf(t2 - nm) + __expf(t3 - nm)));
        mm0 = nm;
      } else {
        float nm = fmaxf(mm1, mc);
        ss1 = ss1 * __expf(mm1 - nm) +
              ((__expf(t0 - nm) + __expf(t1 - nm)) + (__expf(t2 - nm) + __expf(t3 - nm)));
        mm1 = nm;
      }
      t0 = u0; t1 = u1; t2 = u2; t3 = u3;
    }
    float mc = fmaxf(fmaxf(t0, t1), fmaxf(t2, t3));
    if ((n4 & 1) != 0) {
      float nm = fmaxf(mm0, mc);
      ss0 = ss0 * __expf(mm0 - nm) +
            ((__expf(t0 - nm) + __expf(t1 - nm)) + (__expf(t2 - nm) + __expf(t3 - nm)));
      mm0 = nm;
    } else {
      float nm = fmaxf(mm1, mc);
      ss1 = ss1 * __expf(mm1 - nm) +
            ((__expf(t0 - nm) + __expf(t1 - nm)) + (__expf(t2 - nm) + __expf(t3 - nm)));
      mm1 = nm;
    }
  }
  float nm = fmaxf(mm0, mm1);
  float ssc = ss0 * __expf(mm0 - nm) + ss1 * __expf(mm1 - nm);
  return (ssc > 0.0f) ? (__logf(ssc) + nm) : NEG_INF_F;
}

__device__ __forceinline__ void stage_row(const float* __restrict__ row,
                                          float* __restrict__ lds, int C, int tid, int nt) {
  if (((C & 3) == 0) && ((((uintptr_t)row) & 15) == 0)) {
    const float4* r4 = (const float4*)row;
    const int n = C >> 2;
    for (int i = tid; i < n; i += nt) ((float4*)lds)[i] = r4[i];
  } else {
    for (int i = tid; i < C; i += nt) lds[i] = row[i];
  }
}

// LDS read with pre-scaled byte offset
__device__ __forceinline__ float ldsF(const float* base, unsigned boff) {
  return *(const float*)((const char*)base + boff);
}

#define ACC4(X, Y, s0, s1, s2, s3)                                                         \
  s0 = fmaf(__uint_as_float((X).y), ldsF(vbuf, (X).x & 0xFFFFu) * ldsF(el, (X).x >> 16), s0); \
  s1 = fmaf(__uint_as_float((X).w), ldsF(vbuf, (X).z & 0xFFFFu) * ldsF(el, (X).z >> 16), s1); \
  s2 = fmaf(__uint_as_float((Y).y), ldsF(vbuf, (Y).x & 0xFFFFu) * ldsF(el, (Y).x >> 16), s2); \
  s3 = fmaf(__uint_as_float((Y).w), ldsF(vbuf, (Y).z & 0xFFFFu) * ldsF(el, (Y).z >> 16), s3);

// ============================ forward: den linear-space (greedy-interleaved), num exact-LSE ============================
__global__ __launch_bounds__(1024, 4)
void fsa_forward_lin(const float* __restrict__ ll, const int* __restrict__ seqlen,
                     const uint2* __restrict__ den_meta, const uint4* __restrict__ den_ilv,
                     const int* __restrict__ den_desc,
                     const int* __restrict__ den_rp, const int* __restrict__ den_perm, int S_den,
                     const uint2* __restrict__ num_meta, const int* __restrict__ num_rp,
                     int num_stride, int S_num,
                     const float* __restrict__ den_init, const float* __restrict__ den_final,
                     const float* __restrict__ num_init, const float* __restrict__ num_final,
                     int T, int C, int B, float* __restrict__ out_llh)
{
  __shared__ float alpha[MAX_S];
  __shared__ float vbuf[MAX_S];
  __shared__ float elbuf[2 * MAX_C];   // den: exp(ll) double-buffered ; num: raw ll (half 0)
  __shared__ float red[16];
  __shared__ int   sdesc[66];

  const int tid = threadIdx.x;
  const int nt  = 1024;
  const bool is_den = ((int)blockIdx.x) < B;
  const int b = is_den ? (int)blockIdx.x : ((int)blockIdx.x - B);
  const int S = is_den ? S_den : S_num;
  const float* fin  = is_den ? den_final : num_final;
  const int*   perm = is_den ? den_perm  : nullptr;

  const int L = seqlen[b];
  const float* llb = ll + ((size_t)b * T) * C;

  if (is_den) {
    // ---- linear-space denominator, 2 barriers/step ----
    for (int i = tid; i < 66; i += nt) sdesc[i] = den_desc[i];

    const int w = tid >> 6, l = tid & 63;
    const int slotA = tid;            // heavy ranks
    const int slotB = 2047 - tid;     // paired light ranks
    const int rA0 = den_rp[slotA], rA1 = den_rp[slotA + 1];
    const int rB0 = den_rp[slotB], rB1 = den_rp[slotB + 1];
    float a0 = (slotA < S) ? den_init[den_perm[slotA]] : NEG_INF_F;
    float a1 = (slotB < S) ? den_init[den_perm[slotB]] : NEG_INF_F;

    const int nvec = C >> 2;
    const bool pf = ((C & 3) == 0) && ((((uintptr_t)llb) & 15) == 0) &&
                    (nvec <= nt) && (C <= MAX_C);

    // initial M reduce + EL stage for row 0 (buffer 0)
    float lm = fmaxf(a0, a1);
    for (int off = 32; off; off >>= 1) lm = fmaxf(lm, __shfl_down(lm, off));
    if ((tid & 63) == 0) red[tid >> 6] = lm;
    if (L > 0) {
      if (pf) {
        if (tid < nvec) {
          float4 r = ((const float4*)llb)[tid];
          elbuf[4 * tid + 0] = __expf(r.x); elbuf[4 * tid + 1] = __expf(r.y);
          elbuf[4 * tid + 2] = __expf(r.z); elbuf[4 * tid + 3] = __expf(r.w);
        }
      } else {
        for (int i = tid; i < C; i += nt) elbuf[i] = __expf(llb[i]);
      }
    }
    __syncthreads();
    float M = red[0];
#pragma unroll
    for (int i = 1; i < 16; ++i) M = fmaxf(M, red[i]);

    const bool ilv_ok = sdesc[64] != 0;
    const uint4* pA4 = den_ilv + sdesc[w] + l;
    const uint4* pB4 = den_ilv + sdesc[16 + w] + l;
    const int nA = sdesc[32 + w], nB = sdesc[48 + w];

    int cur = 0;
    for (int t = 0; t < L; ++t) {
      vbuf[slotA] = __expf(a0 - M);
      vbuf[slotB] = __expf(a1 - M);
      __syncthreads();                       // B1: vbuf + elbuf[cur] ready

      const float* el = elbuf + (cur ? MAX_C : 0);

      float4 nx;
      const bool donx = pf && (t + 1 < L) && (tid < nvec);
      if (donx) nx = ((const float4*)(llb + (size_t)(t + 1) * C))[tid];

      float sA0 = 0, sA1 = 0, sA2 = 0, sA3 = 0;
      float sB0 = 0, sB1 = 0, sB2 = 0, sB3 = 0;
      if (ilv_ok) {
        if (nA > 0) {
          uint4 X0 = pA4[0], Y0 = pA4[64];
          if (nA > 1) {
            uint4 X1 = pA4[128], Y1 = pA4[192];
            for (int c = 2; c < nA; ++c) {
              uint4 X2 = pA4[c * 128], Y2 = pA4[c * 128 + 64];
              ACC4(X0, Y0, sA0, sA1, sA2, sA3);
              X0 = X1; Y0 = Y1; X1 = X2; Y1 = Y2;
            }
            ACC4(X0, Y0, sA0, sA1, sA2, sA3);
            X0 = X1; Y0 = Y1;
          }
          ACC4(X0, Y0, sA0, sA1, sA2, sA3);
        }
        if (nB > 0) {
          uint4 X0 = pB4[0], Y0 = pB4[64];
          for (int c = 1; c < nB; ++c) {
            uint4 X1 = pB4[c * 128], Y1 = pB4[c * 128 + 64];
            ACC4(X0, Y0, sB0, sB1, sB2, sB3);
            X0 = X1; Y0 = Y1;
          }
          ACC4(X0, Y0, sB0, sB1, sB2, sB3);
        }
      } else {
        const uint4* pA = (const uint4*)(den_meta + rA0);
        const uint4* pB = (const uint4*)(den_meta + rB0);
        const int nAr = (rA1 - rA0) >> 2, nBr = (rB1 - rB0) >> 2;
        const int n = nAr > nBr ? nAr : nBr;
        for (int c = 0; c < n; ++c) {
          if (c < nAr) {
            uint4 X = pA[2 * c], Y = pA[2 * c + 1];
            ACC4(X, Y, sA0, sA1, sA2, sA3);
          }
          if (c < nBr) {
            uint4 X = pB[2 * c], Y = pB[2 * c + 1];
            ACC4(X, Y, sB0, sB1, sB2, sB3);
          }
        }
      }
      float sA = (sA0 + sA1) + (sA2 + sA3);
      float sB = (sB0 + sB1) + (sB2 + sB3);

      a0 = (sA > 0.0f) ? (__logf(sA) + M) : NEG_INF_F;
      a1 = (sB > 0.0f) ? (__logf(sB) + M) : NEG_INF_F;

      float* eln = elbuf + (cur ? 0 : MAX_C);
      if (donx) {
        eln[4 * tid + 0] = __expf(nx.x); eln[4 * tid + 1] = __expf(nx.y);
        eln[4 * tid + 2] = __expf(nx.z); eln[4 * tid + 3] = __expf(nx.w);
      } else if (!pf && t + 1 < L) {
        const float* nr = llb + (size_t)(t + 1) * C;
        for (int i = tid; i < C; i += nt) eln[i] = __expf(nr[i]);
      }

      float lm2 = fmaxf(a0, a1);
      for (int off = 32; off; off >>= 1) lm2 = fmaxf(lm2, __shfl_down(lm2, off));
      if ((tid & 63) == 0) red[tid >> 6] = lm2;
      __syncthreads();                       // B2: sums done, red + elbuf[nxt] visible
      M = red[0];
#pragma unroll
      for (int i = 1; i < 16; ++i) M = fmaxf(M, red[i]);
      cur ^= 1;
    }
    alpha[slotA] = a0;
    alpha[slotB] = a1;
    __syncthreads();
  } else {
    // ---- exact-LSE numerator (tiny) ----
    const uint2* meta = num_meta + (size_t)b * num_stride;
    const int*   rp   = num_rp + (size_t)b * (S_num + 1);
    for (int s = tid; s < MAX_S; s += nt) alpha[s] = (s < S) ? num_init[s] : NEG_INF_F;
    int rs[2] = {0, 0}, re[2] = {0, 0};
    for (int u = 0; u < 2; ++u) {
      int s = tid + u * nt;
      if (s < S) { rs[u] = rp[s]; re[u] = rp[s + 1]; }
    }
    __syncthreads();
    for (int t = 0; t < L; ++t) {
      stage_row(llb + (size_t)t * C, elbuf, C, tid, nt);
      __syncthreads();
      float nv[2];
      for (int u = 0; u < 2; ++u) {
        int s = tid + u * nt;
        nv[u] = (s < S) ? row_lse(meta, rs[u], re[u], alpha, elbuf) : NEG_INF_F;
      }
      __syncthreads();
      for (int u = 0; u < 2; ++u) {
        int s = tid + u * nt;
        if (s < S) alpha[s] = nv[u];
      }
      __syncthreads();
    }
  }

  // final logsumexp(alpha + final_logp)
  float lm = -3.0e38f;
  for (int s = tid; s < S; s += nt) lm = fmaxf(lm, alpha[s] + fin[perm ? perm[s] : s]);
  for (int off = 32; off; off >>= 1) lm = fmaxf(lm, __shfl_down(lm, off));
  if ((tid & 63) == 0) red[tid >> 6] = lm;
  __syncthreads();
  if (tid < 64) {
    float v = (tid < 16) ? red[tid] : -3.0e38f;
    for (int off = 32; off; off >>= 1) v = fmaxf(v, __shfl_down(v, off));
    if (tid == 0) red[0] = v;
  }
  __syncthreads();
  const float M = red[0];

  float ls = 0.0f;
  for (int s = tid; s < S; s += nt) ls += __expf(alpha[s] + fin[perm ? perm[s] : s] - M);
  for (int off = 32; off; off >>= 1) ls += __shfl_down(ls, off);
  __syncthreads();
  if ((tid & 63) == 0) red[tid >> 6] = ls;
  __syncthreads();
  if (tid < 64) {
    float v = (tid < 16) ? red[tid] : 0.0f;
    for (int off = 32; off; off >>= 1) v += __shfl_down(v, off);
    if (tid == 0) out_llh[(is_den ? 0 : B) + b] = __logf(v) + M;
  }
}

// ============================ fallback (atomic path, tiny ws) ============================

__device__ __forceinline__ unsigned enc_f(float x) {
  unsigned u = __float_as_uint(x);
  return u ^ (unsigned)(((int)u >> 31) | 0x80000000);
}
__device__ __forceinline__ float dec_f(unsigned e) {
  unsigned mask = ((int)e >= 0) ? 0xFFFFFFFFu : 0x80000000u;
  return __uint_as_float(e ^ mask);
}

__global__ __launch_bounds__(1024)
void fsa_forward_fallback(
    const float* __restrict__ ll, const int* __restrict__ seqlen,
    const int* __restrict__ den_src, const int* __restrict__ den_dst,
    const int* __restrict__ den_pdf, const float* __restrict__ den_w,
    int A_den, const float* __restrict__ den_init, const float* __restrict__ den_final, int S_den,
    const int* __restrict__ num_src, const int* __restrict__ num_dst,
    const int* __restrict__ num_pdf, const float* __restrict__ num_w,
    int A_num, const float* __restrict__ num_init, const float* __restrict__ num_final, int S_num,
    int T, int C, int B, float* __restrict__ out_llh)
{
  __shared__ float    alpha[MAX_S];
  __shared__ unsigned menc[MAX_S];
  __shared__ float    msafe[MAX_S];
  __shared__ float    ssum[MAX_S];
  __shared__ float    llrow[MAX_C];

  const int tid = threadIdx.x;
  const int nt  = blockDim.x;
  const bool is_den = ((int)blockIdx.x) < B;
  const int b = is_den ? (int)blockIdx.x : ((int)blockIdx.x - B);
  const int S = is_den ? S_den : S_num;
  const int A = is_den ? A_den : A_num;
  const float* init = is_den ? den_init  : num_init;
  const float* fin  = is_den ? den_final : num_final;
  const int*   asrc = is_den ? den_src  : (num_src + (size_t)b * A_num);
  const int*   adst = is_den ? den_dst  : (num_dst + (size_t)b * A_num);
  const int*   apdf = is_den ? den_pdf  : (num_pdf + (size_t)b * A_num);
  const float* aw   = is_den ? den_w    : (num_w   + (size_t)b * A_num);

  for (int s = tid; s < S; s += nt) { alpha[s] = init[s]; menc[s] = 0u; ssum[s] = 0.0f; }
  __syncthreads();

  const int L = seqlen[b];
  const float* llb = ll + ((size_t)b * T) * C;

  for (int t = 0; t < L; ++t) {
    const float* row = llb + (size_t)t * C;
    for (int i = tid; i < C; i += nt) llrow[i] = row[i];
    __syncthreads();
    for (int i = tid; i < A; i += nt) {
      float score = alpha[asrc[i]] + aw[i] + llrow[apdf[i]];
      atomicMax(&menc[adst[i]], enc_f(score));
    }
    __syncthreads();
    for (int s = tid; s < S; s += nt) {
      float m = dec_f(menc[s]);
      msafe[s] = (m > -5e29f) ? m : 0.0f;
    }
    __syncthreads();
    for (int i = tid; i < A; i += nt) {
      int d = adst[i];
      float score = alpha[asrc[i]] + aw[i] + llrow[apdf[i]];
      atomicAdd(&ssum[d], __expf(score - msafe[d]));
    }
    __syncthreads();
    for (int s = tid; s < S; s += nt) {
      float sum = ssum[s];
      alpha[s] = (sum > 0.0f) ? (__logf(sum) + msafe[s]) : NEG_INF_F;
      menc[s] = 0u; ssum[s] = 0.0f;
    }
    __syncthreads();
  }

  float lm = -3.0e38f;
  for (int s = tid; s < S; s += nt) lm = fmaxf(lm, alpha[s] + fin[s]);
  for (int off = 32; off; off >>= 1) lm = fmaxf(lm, __shfl_down(lm, off));
  const int nwaves = nt >> 6;
  if ((tid & 63) == 0) msafe[tid >> 6] = lm;
  __syncthreads();
  if (tid < 64) {
    float v = (tid < nwaves) ? msafe[tid] : -3.0e38f;
    for (int off = 32; off; off >>= 1) v = fmaxf(v, __shfl_down(v, off));
    if (tid == 0) msafe[MAX_S - 1] = v;
  }
  __syncthreads();
  const float M = msafe[MAX_S - 1];
  float ls = 0.0f;
  for (int s = tid; s < S; s += nt) ls += __expf(alpha[s] + fin[s] - M);
  for (int off = 32; off; off >>= 1) ls += __shfl_down(ls, off);
  if ((tid & 63) == 0) ssum[tid >> 6] = ls;
  __syncthreads();
  if (tid < 64) {
    float v = (tid < nwaves) ? ssum[tid] : 0.0f;
    for (int off = 32; off; off >>= 1) v += __shfl_down(v, off);
    if (tid == 0) out_llh[(is_den ? 0 : B) + b] = __logf(v) + M;
  }
}

// loss = sum_b (den_llh[b] - num_llh[b])
__global__ void final_loss_kernel(const float* __restrict__ llh, int B, float* __restrict__ out) {
  int lane = threadIdx.x;
  float v = (lane < B) ? (llh[lane] - llh[B + lane]) : 0.0f;
  for (int off = 32; off; off >>= 1) v += __shfl_down(v, off);
  if (lane == 0) out[0] = v;
}

extern "C" void kernel_launch(void* const* d_in, const int* in_sizes, int n_in,
                              void* d_out, int out_size, void* d_ws, size_t ws_size,
                              hipStream_t stream) {
  const float* ll        = (const float*)d_in[0];
  const int*   seqlen    = (const int*)  d_in[1];
  const int*   num_src   = (const int*)  d_in[2];
  const int*   num_dst   = (const int*)  d_in[3];
  const int*   num_pdf   = (const int*)  d_in[4];
  const float* num_w     = (const float*)d_in[5];
  const float* num_init  = (const float*)d_in[6];
  const float* num_final = (const float*)d_in[7];
  const int*   den_src   = (const int*)  d_in[8];
  const int*   den_dst   = (const int*)  d_in[9];
  const int*   den_pdf   = (const int*)  d_in[10];
  const float* den_w     = (const float*)d_in[11];
  const float* den_init  = (const float*)d_in[12];
  const float* den_final = (const float*)d_in[13];

  const int B     = in_sizes[1];
  const int A_num = in_sizes[2] / B;
  const int S_num = in_sizes[6];
  const int A_den = in_sizes[8];
  const int S_den = in_sizes[12];
  const int T     = 500;                       // problem spec
  const int C     = in_sizes[0] / (B * T);

  const int den_cap    = A_den + 3 * S_den + 64;
  const int num_stride = A_num + 3 * S_num + 64;
  const int cap4       = den_cap + 32768;      // interleaved capacity (uint4 units)

  // workspace layout
  size_t off = 0;
  auto alloc = [&](size_t bytes, size_t align) -> size_t {
    off = (off + align - 1) / align * align;
    size_t r = off; off += bytes; return r;
  };
  size_t o_den_meta = alloc((size_t)den_cap * 8, 16);
  size_t o_den_ilv  = alloc((size_t)cap4 * 16, 16);
  size_t o_desc     = alloc((size_t)66 * 4, 4);
  size_t o_num_meta = alloc((size_t)B * num_stride * 8, 16);
  size_t o_den_rp   = alloc((size_t)2049 * 4, 4);
  size_t o_num_rp   = alloc((size_t)B * (S_num + 1) * 4, 4);
  size_t o_den_cnt  = alloc((size_t)S_den * 4, 4);
  size_t o_perm     = alloc((size_t)2048 * 4, 4);
  size_t o_inv      = alloc((size_t)S_den * 4, 4);
  size_t o_pc       = alloc((size_t)2048 * 4, 4);
  size_t o_num_pc   = alloc((size_t)B * S_num * 4, 4);
  size_t o_hist     = alloc((size_t)NCH * S_den * 4, 4);   // zeroed region start
  size_t o_num_cnt  = alloc((size_t)B * S_num * 4, 4);     // contiguous with hist
  size_t o_llh      = alloc((size_t)2 * B * 4, 4);
  const bool use_csr = (off <= ws_size) && (S_den >= 1) && (S_den <= 2048) &&
                       (S_num >= 1) && (S_num <= 2048) && (C <= MAX_C) && (C >= 1);

  char* wsb = (char*)d_ws;
  float* llh = (float*)(wsb + (use_csr ? o_llh : 0));

  if (use_csr) {
    uint2* den_meta = (uint2*)(wsb + o_den_meta);
    uint4* den_ilv  = (uint4*)(wsb + o_den_ilv);
    int*   desc     = (int*)(wsb + o_desc);
    uint2* num_meta = (uint2*)(wsb + o_num_meta);
    int*   den_rp   = (int*)(wsb + o_den_rp);
    int*   num_rp   = (int*)(wsb + o_num_rp);
    int*   den_cnt  = (int*)(wsb + o_den_cnt);
    int*   perm     = (int*)(wsb + o_perm);
    int*   inv      = (int*)(wsb + o_inv);
    int*   pc       = (int*)(wsb + o_pc);
    int*   num_pc   = (int*)(wsb + o_num_pc);
    int*   hist     = (int*)(wsb + o_hist);
    int*   num_cnt  = (int*)(wsb + o_num_cnt);

    const int chunk = (A_den + NCH - 1) / NCH;

    // zero hist + num_cnt (contiguous)
    int ztot = NCH * S_den + B * S_num;
    zero_kernel<<<(ztot + 255) / 256, 256, 0, stream>>>(hist, ztot);

    hist_chunk_kernel<<<NCH, 256, 0, stream>>>(den_dst, A_den, chunk, S_den, hist);
    hist_kernel<<<dim3((A_num + 255) / 256, B), 256, 0, stream>>>(num_dst, A_num, A_num,
                                                                  num_cnt, S_num);

    colsum_kernel<<<(S_den + 255) / 256, 256, 0, stream>>>(hist, NCH, S_den, den_cnt);
    rank_perm_kernel<<<1, 1024, 0, stream>>>(den_cnt, S_den, perm, inv);
    pc_kernel<<<8, 256, 0, stream>>>(den_cnt, perm, S_den, pc);
    scan_kernel<<<1, 1024, 0, stream>>>(pc, den_rp, 2048);
    wave_desc_kernel<<<1, 1024, 0, stream>>>(den_rp, cap4, desc);

    padcnt_kernel<<<(B * S_num + 255) / 256, 256, 0, stream>>>(num_cnt, B * S_num, num_pc);
    scan_kernel<<<B, 1024, 0, stream>>>(num_pc, num_rp, S_num);

    off_perm_kernel<<<(S_den + 255) / 256, 256, 0, stream>>>(hist, NCH, S_den, den_rp, perm);
    pad_den_kernel<<<(S_den + 255) / 256, 256, 0, stream>>>(den_rp, den_cnt, perm, S_den, den_meta);
    fill_chunk_kernel<<<dim3((S_den + 255) / 256, NCH), 256, 0, stream>>>(
        den_src, den_dst, den_pdf, den_w, A_den, chunk, S_den, hist, inv, den_meta);
    fill_kernel<<<dim3((S_num + 255) / 256, B), 256, 0, stream>>>(
        num_src, num_dst, num_pdf, num_w, A_num, A_num, num_rp, S_num, num_meta, num_stride);

    repack_greedy_kernel<<<32, 64, 0, stream>>>(den_meta, den_rp, desc, C, (uint2*)den_ilv);

    fsa_forward_lin<<<2 * B, 1024, 0, stream>>>(
        ll, seqlen, den_meta, den_ilv, desc, den_rp, perm, S_den,
        num_meta, num_rp, num_stride, S_num,
        den_init, den_final, num_init, num_final, T, C, B, llh);
  } else {
    fsa_forward_fallback<<<2 * B, 1024, 0, stream>>>(
        ll, seqlen,
        den_src, den_dst, den_pdf, den_w, A_den, den_init, den_final, S_den,
        num_src, num_dst, num_pdf, num_w, A_num, num_init, num_final, S_num,
        T, C, B, llh);
  }

  final_loss_kernel<<<1, 64, 0, stream>>>(llh, B, (float*)d_out);
}

// Round 9
// 3682.043 us; speedup vs baseline: 1.0524x; 1.0524x over previous
//
#include <hip/hip_runtime.h>

#define NEG_INF_F (-1e30f)
#define MAX_S 2048
#define MAX_C 3008
#define NCH   128

// ============================ build helpers (deterministic) ============================

__global__ void zero_kernel(int* __restrict__ p, int n) {
  int i = blockIdx.x * blockDim.x + threadIdx.x;
  if (i < n) p[i] = 0;
}

__global__ void hist_kernel(const int* __restrict__ dst, int A, int A_stride,
                            int* __restrict__ cnt, int S) {
  int b = blockIdx.y;
  int i = blockIdx.x * blockDim.x + threadIdx.x;
  if (i < A) atomicAdd(&cnt[b * S + dst[(size_t)b * A_stride + i]], 1);
}

__global__ void hist_chunk_kernel(const int* __restrict__ dst, int A, int chunk, int S,
                                  int* __restrict__ hist) {
  int c = blockIdx.x;
  int i1 = min(A, (c + 1) * chunk);
  for (int i = c * chunk + threadIdx.x; i < i1; i += blockDim.x)
    atomicAdd(&hist[c * S + dst[i]], 1);
}

__global__ void colsum_kernel(const int* __restrict__ hist, int nch, int S,
                              int* __restrict__ cnt) {
  int s = blockIdx.x * blockDim.x + threadIdx.x;
  if (s < S) {
    int t = 0;
    for (int c = 0; c < nch; ++c) t += hist[c * S + s];
    cnt[s] = t;
  }
}

// Stable in-degree rank (desc) -> slot permutation pairing heavy with light.
__global__ __launch_bounds__(1024)
void rank_perm_kernel(const int* __restrict__ cnt, int S,
                      int* __restrict__ perm, int* __restrict__ invperm) {
  __shared__ int c[2048];
  __shared__ int R[2048];
  const int tid = threadIdx.x;
  for (int i = tid; i < 2048; i += 1024) c[i] = (i < S) ? cnt[i] : -1;
  __syncthreads();
  for (int u = 0; u < 2; ++u) {
    int s = tid + u * 1024;
    if (s < S) {
      int cs = c[s], r = 0;
      for (int j = 0; j < S; ++j) {
        int cj = c[j];
        r += (cj > cs) || (cj == cs && j < s);
      }
      R[r] = s;
    }
  }
  __syncthreads();
  for (int u = 0; u < 2; ++u) {
    int slot = tid + u * 1024;
    if (slot < S) {
      int state = (slot < 1024) ? R[slot] : R[S - 1 - (slot - 1024)];
      perm[slot] = state;
      invperm[state] = slot;
    }
  }
}

__global__ void pc_kernel(const int* __restrict__ cnt, const int* __restrict__ perm,
                          int S, int* __restrict__ pc) {
  int slot = blockIdx.x * blockDim.x + threadIdx.x;
  if (slot < 2048) pc[slot] = (slot < S) ? ((cnt[perm[slot]] + 3) & ~3) : 0;
}

__global__ void padcnt_kernel(const int* __restrict__ cnt, int n, int* __restrict__ out) {
  int i = blockIdx.x * blockDim.x + threadIdx.x;
  if (i < n) out[i] = (cnt[i] + 3) & ~3;
}

__global__ __launch_bounds__(1024) void scan_kernel(const int* __restrict__ cnt,
                                                    int* __restrict__ rp, int S) {
  __shared__ int buf[2][2048];
  const int tid = threadIdx.x;
  const int b = blockIdx.x;
  const int* c = cnt + (size_t)b * S;
  int* r = rp + (size_t)b * (S + 1);
  for (int u = 0; u < 2; ++u) {
    int i = tid + u * 1024;
    buf[0][i] = (i < S) ? c[i] : 0;
  }
  __syncthreads();
  int cur = 0;
  for (int off = 1; off < 2048; off <<= 1) {
    for (int u = 0; u < 2; ++u) {
      int i = tid + u * 1024;
      buf[cur ^ 1][i] = buf[cur][i] + ((i >= off) ? buf[cur][i - off] : 0);
    }
    __syncthreads();
    cur ^= 1;
  }
  for (int u = 0; u < 2; ++u) {
    int i = tid + u * 1024;
    if (i <= S) r[i] = (i == 0) ? 0 : buf[cur][i - 1];
  }
  if (tid == 0) r[S] = buf[cur][S - 1];
}

__global__ void off_perm_kernel(int* __restrict__ hist, int nch, int S,
                                const int* __restrict__ rp, const int* __restrict__ perm) {
  int slot = blockIdx.x * blockDim.x + threadIdx.x;
  if (slot < S) {
    int state = perm[slot];
    int run = rp[slot];
    for (int c = 0; c < nch; ++c) {
      int h = hist[c * S + state];
      hist[c * S + state] = run;
      run += h;
    }
  }
}

// fill pad arcs at row tails (den): y==0 marks pad (ew = 0)
__global__ void pad_den_kernel(const int* __restrict__ rp, const int* __restrict__ cnt,
                               const int* __restrict__ perm, int S, uint2* __restrict__ meta) {
  int slot = blockIdx.x * blockDim.x + threadIdx.x;
  if (slot < S) {
    int p = rp[slot] + cnt[perm[slot]];
    int e = rp[slot + 1];
    uint2 pad = make_uint2(0u, 0u);
    for (; p < e; ++p) meta[p] = pad;
  }
}

// DEN meta: x = (src_slot*4) | ((pdf*4)<<16)  (pre-scaled LDS byte offsets), y = exp(w).
__global__ void fill_chunk_kernel(const int* __restrict__ src, const int* __restrict__ dst,
                                  const int* __restrict__ pdf, const float* __restrict__ w,
                                  int A, int chunk, int S, int* __restrict__ hoff,
                                  const int* __restrict__ inv, uint2* __restrict__ meta) {
  int c = blockIdx.y;
  int s = blockIdx.x * blockDim.x + threadIdx.x;
  if (s >= S) return;
  int i1 = min(A, (c + 1) * chunk);
  int p = hoff[c * S + s];
  for (int i = c * chunk; i < i1; ++i) {
    if (dst[i] == s) {
      meta[p++] = make_uint2((unsigned)(inv[src[i]] * 4) | ((unsigned)(pdf[i] * 4) << 16),
                             __float_as_uint(__expf(w[i])));
    }
  }
}

// numerator meta keeps index packing (src | pdf<<16) + raw w
__global__ void fill_kernel(const int* __restrict__ src, const int* __restrict__ dst,
                            const int* __restrict__ pdf, const float* __restrict__ w,
                            int A, int A_stride, const int* __restrict__ rp, int S,
                            uint2* __restrict__ meta, int meta_stride) {
  int b = blockIdx.y;
  int s = blockIdx.x * blockDim.x + threadIdx.x;
  if (s >= S) return;
  const int*   sb = src + (size_t)b * A_stride;
  const int*   db = dst + (size_t)b * A_stride;
  const int*   pb = pdf + (size_t)b * A_stride;
  const float* wb = w   + (size_t)b * A_stride;
  const int*   rpb = rp + (size_t)b * (S + 1);
  uint2* mb = meta + (size_t)b * meta_stride;
  int p = rpb[s];
  for (int i = 0; i < A; ++i) {
    if (db[i] == s) {
      mb[p++] = make_uint2((unsigned)sb[i] | ((unsigned)pb[i] << 16), __float_as_uint(wb[i]));
    }
  }
  uint2 pad = make_uint2(0u, __float_as_uint(NEG_INF_F));
  int e = rpb[s + 1];
  for (; p < e; ++p) mb[p] = pad;
}

// ---- wave-interleaved den meta: desc = offA[16],offB[16],wmaxA[16],wmaxB[16],ok,total ----
__global__ __launch_bounds__(1024)
void wave_desc_kernel(const int* __restrict__ rp, int cap4, int* __restrict__ desc) {
  __shared__ int wm[32];
  const int tid = threadIdx.x;
  const int w = tid >> 6;
  int cA = (rp[tid + 1] - rp[tid]) >> 2;
  int sB = 2047 - tid;
  int cB = (rp[sB + 1] - rp[sB]) >> 2;
  for (int off = 32; off; off >>= 1) {
    cA = max(cA, __shfl_down(cA, off));
    cB = max(cB, __shfl_down(cB, off));
  }
  if ((tid & 63) == 0) { wm[w] = cA; wm[16 + w] = cB; }
  __syncthreads();
  if (tid == 0) {
    int off = 0;
    for (int i = 0; i < 16; ++i) { desc[i] = off; off += wm[i] * 128; }
    for (int i = 0; i < 16; ++i) { desc[16 + i] = off; off += wm[16 + i] * 128; }
    for (int i = 0; i < 16; ++i) { desc[32 + i] = wm[i]; desc[48 + i] = wm[16 + i]; }
    desc[64] = (off <= cap4) ? 1 : 0;
    desc[65] = off;
  }
}

// Greedy bank-aware arc placement, register-table implementation.
// grid 32 blocks x 64 lanes (single wave). Same algorithm/output as round-8 greedy:
// per row (in lane order), per real arc (in CSR order), place at the free position
// minimizing loadS[p][bank(src)] + loadP[p][bank(pdf)], ties -> lowest p.
// Lane l owns position l: its 32+32 bank counters live in 4 u64 (4-bit saturating).
// Free mask is tracked redundantly in registers by all lanes (no LDS in the loop).
__global__ __launch_bounds__(64)
void repack_greedy_kernel(const uint2* __restrict__ meta, const int* __restrict__ rp,
                          const int* __restrict__ desc, int C, uint2* __restrict__ ilv) {
  if (!desc[64]) return;
  const int w = blockIdx.x & 15;
  const bool isB = blockIdx.x >= 16;
  const int l = threadIdx.x;
  const int base4 = desc[(isB ? 16 : 0) + w];
  const int wmax  = desc[(isB ? 48 : 32) + w];
  const int P = wmax * 4;
  if (P == 0) return;

  // lane l's row/slot (forward-kernel lane l of wave w)
  const int slot_l = isB ? (2047 - (w * 64 + l)) : (w * 64 + l);
  const int r0_l = rp[slot_l];
  const int n_l  = rp[slot_l + 1] - r0_l;

  // wave slab bounds (rows are contiguous in meta for both A and B waves)
  const int slot_lo = isB ? (2047 - (w * 64 + 63)) : (w * 64);
  const int mbase = rp[slot_lo];
  const int total = rp[slot_lo + 64] - mbase;

  __shared__ uint2 smeta[4096];   // 32 KB

  if (P > 64 || total > 4096) {
    // fallback: order-preserving interleave copy
    const int n4 = n_l >> 2;
    for (int c = 0; c < wmax; ++c) {
      for (int part = 0; part < 2; ++part) {
        int u4 = base4 + c * 128 + part * 64 + l;
        uint2 v0 = make_uint2(0u, 0u), v1 = make_uint2(0u, 0u);
        if (c < n4) {
          v0 = meta[r0_l + 4 * c + 2 * part];
          v1 = meta[r0_l + 4 * c + 2 * part + 1];
        }
        ilv[2 * u4]     = v0;
        ilv[2 * u4 + 1] = v1;
      }
    }
    return;
  }

  // stage wave slab into LDS (coalesced)
  for (int i = l; i < total; i += 64) smeta[i] = meta[mbase + i];
  __syncthreads();   // single wave: compiles to wave-level ordering

  unsigned long long tabSlo = 0, tabShi = 0, tabPlo = 0, tabPhi = 0;
  unsigned long long myFree = 0;
  const unsigned long long fullMask = (P >= 64) ? ~0ULL : ((1ULL << P) - 1ULL);
  const int myOff = r0_l - mbase;

  for (int r = 0; r < 64; ++r) {
    const int rr0 = __shfl(myOff, r);
    const int rn  = __shfl(n_l, r);
    unsigned long long freeMask = fullMask;
    for (int k = 0; k < rn; ++k) {
      uint2 a = smeta[rr0 + k];        // uniform -> LDS broadcast
      if (a.y == 0u) continue;         // pad / zero-weight: contributes 0, drop
      const int bs = (a.x >> 2) & 31;
      const int bp = (a.x >> 18) & 31;
      const int cS = (int)(((bs < 16) ? (tabSlo >> (4 * bs)) : (tabShi >> (4 * (bs - 16)))) & 0xF);
      const int cP = (int)(((bp < 16) ? (tabPlo >> (4 * bp)) : (tabPhi >> (4 * (bp - 16)))) & 0xF);
      const bool valid = ((freeMask >> l) & 1ULL) != 0ULL;
      int v = (valid ? (cS + cP) : 0x7FFF) * 64 + l;
      for (int off = 32; off; off >>= 1) v = min(v, __shfl_xor(v, off));
      const int p = v & 63;
      freeMask &= ~(1ULL << p);
      if (l == p) {
        if (cS < 15) { if (bs < 16) tabSlo += (1ULL << (4 * bs)); else tabShi += (1ULL << (4 * (bs - 16))); }
        if (cP < 15) { if (bp < 16) tabPlo += (1ULL << (4 * bp)); else tabPhi += (1ULL << (4 * (bp - 16))); }
        const int idx = 2 * (base4 + (p >> 2) * 128 + (((p >> 1) & 1) * 64) + r) + (p & 1);
        ilv[idx] = a;
      }
    }
    if (l == r) myFree = freeMask;
  }

  // fill own row's remaining positions with bank-spread pads (ew = 0)
  unsigned long long fm = myFree;
  const int pc = min(slot_l, C - 1);
  const uint2 pad = make_uint2((unsigned)(slot_l * 4) | ((unsigned)(pc * 4) << 16), 0u);
  while (fm) {
    const int p = __ffsll(fm) - 1;
    fm &= fm - 1ULL;
    const int idx = 2 * (base4 + (p >> 2) * 128 + (((p >> 1) & 1) * 64) + l) + (p & 1);
    ilv[idx] = pad;
  }
}

// ============================ exact row LSE (numerator path) ============================

__device__ __forceinline__ float row_lse(const uint2* __restrict__ meta, int k, int e,
                                         const float* __restrict__ alpha,
                                         const float* __restrict__ lcur) {
  float mm0 = NEG_INF_F, ss0 = 0.0f, mm1 = NEG_INF_F, ss1 = 0.0f;
  const int n4 = (e - k) >> 2;
  const uint4* p = (const uint4*)(meta + k);
  if (n4 > 0) {
    uint4 A = p[0], Bv = p[1];
    float t0 = alpha[A.x & 0xFFFFu] + __uint_as_float(A.y) + lcur[A.x >> 16];
    float t1 = alpha[A.z & 0xFFFFu] + __uint_as_float(A.w) + lcur[A.z >> 16];
    float t2 = alpha[Bv.x & 0xFFFFu] + __uint_as_float(Bv.y) + lcur[Bv.x >> 16];
    float t3 = alpha[Bv.z & 0xFFFFu] + __uint_as_float(Bv.w) + lcur[Bv.z >> 16];
    for (int c2 = 1; c2 < n4; ++c2) {
      uint4 A2 = p[2 * c2], B2 = p[2 * c2 + 1];
      float u0 = alpha[A2.x & 0xFFFFu] + __uint_as_float(A2.y) + lcur[A2.x >> 16];
      float u1 = alpha[A2.z & 0xFFFFu] + __uint_as_float(A2.w) + lcur[A2.z >> 16];
      float u2 = alpha[B2.x & 0xFFFFu] + __uint_as_float(B2.y) + lcur[B2.x >> 16];
      float u3 = alpha[B2.z & 0xFFFFu] + __uint_as_float(B2.w) + lcur[B2.z >> 16];
      float mc = fmaxf(fmaxf(t0, t1), fmaxf(t2, t3));
      if ((c2 & 1) != 0) {
        float nm = fmaxf(mm0, mc);
        ss0 = ss0 * __expf(mm0 - nm) +
              ((__expf(t0 - nm) + __expf(t1 - nm)) + (__expf(t2 - nm) + __expf(t3 - nm)));
        mm0 = nm;
      } else {
        float nm = fmaxf(mm1, mc);
        ss1 = ss1 * __expf(mm1 - nm) +
              ((__expf(t0 - nm) + __expf(t1 - nm)) + (__expf(t2 - nm) + __expf(t3 - nm)));
        mm1 = nm;
      }
      t0 = u0; t1 = u1; t2 = u2; t3 = u3;
    }
    float mc = fmaxf(fmaxf(t0, t1), fmaxf(t2, t3));
    if ((n4 & 1) != 0) {
      float nm = fmaxf(mm0, mc);
      ss0 = ss0 * __expf(mm0 - nm) +
            ((__expf(t0 - nm) + __expf(t1 - nm)) + (__expf(t2 - nm) + __expf(t3 - nm)));
      mm0 = nm;
    } else {
      float nm = fmaxf(mm1, mc);
      ss1 = ss1 * __expf(mm1 - nm) +
            ((__expf(t0 - nm) + __expf(t1 - nm)) + (__expf(t2 - nm) + __expf(t3 - nm)));
      mm1 = nm;
    }
  }
  float nm = fmaxf(mm0, mm1);
  float ssc = ss0 * __expf(mm0 - nm) + ss1 * __expf(mm1 - nm);
  return (ssc > 0.0f) ? (__logf(ssc) + nm) : NEG_INF_F;
}

__device__ __forceinline__ void stage_row(const float* __restrict__ row,
                                          float* __restrict__ lds, int C, int tid, int nt) {
  if (((C & 3) == 0) && ((((uintptr_t)row) & 15) == 0)) {
    const float4* r4 = (const float4*)row;
    const int n = C >> 2;
    for (int i = tid; i < n; i += nt) ((float4*)lds)[i] = r4[i];
  } else {
    for (int i = tid; i < C; i += nt) lds[i] = row[i];
  }
}

// LDS read with pre-scaled byte offset
__device__ __forceinline__ float ldsF(const float* base, unsigned boff) {
  return *(const float*)((const char*)base + boff);
}

#define ACC4(X, Y, s0, s1, s2, s3)                                                         \
  s0 = fmaf(__uint_as_float((X).y), ldsF(vbuf, (X).x & 0xFFFFu) * ldsF(el, (X).x >> 16), s0); \
  s1 = fmaf(__uint_as_float((X).w), ldsF(vbuf, (X).z & 0xFFFFu) * ldsF(el, (X).z >> 16), s1); \
  s2 = fmaf(__uint_as_float((Y).y), ldsF(vbuf, (Y).x & 0xFFFFu) * ldsF(el, (Y).x >> 16), s2); \
  s3 = fmaf(__uint_as_float((Y).w), ldsF(vbuf, (Y).z & 0xFFFFu) * ldsF(el, (Y).z >> 16), s3);

// ============================ forward: den linear-space (greedy-interleaved), num exact-LSE ============================
__global__ __launch_bounds__(1024, 4)
void fsa_forward_lin(const float* __restrict__ ll, const int* __restrict__ seqlen,
                     const uint2* __restrict__ den_meta, const uint4* __restrict__ den_ilv,
                     const int* __restrict__ den_desc,
                     const int* __restrict__ den_rp, const int* __restrict__ den_perm, int S_den,
                     const uint2* __restrict__ num_meta, const int* __restrict__ num_rp,
                     int num_stride, int S_num,
                     const float* __restrict__ den_init, const float* __restrict__ den_final,
                     const float* __restrict__ num_init, const float* __restrict__ num_final,
                     int T, int C, int B, float* __restrict__ out_llh)
{
  __shared__ float alpha[MAX_S];
  __shared__ float vbuf[MAX_S];
  __shared__ float elbuf[2 * MAX_C];   // den: exp(ll) double-buffered ; num: raw ll (half 0)
  __shared__ float red[16];
  __shared__ int   sdesc[66];

  const int tid = threadIdx.x;
  const int nt  = 1024;
  const bool is_den = ((int)blockIdx.x) < B;
  const int b = is_den ? (int)blockIdx.x : ((int)blockIdx.x - B);
  const int S = is_den ? S_den : S_num;
  const float* fin  = is_den ? den_final : num_final;
  const int*   perm = is_den ? den_perm  : nullptr;

  const int L = seqlen[b];
  const float* llb = ll + ((size_t)b * T) * C;

  if (is_den) {
    // ---- linear-space denominator, 2 barriers/step ----
    for (int i = tid; i < 66; i += nt) sdesc[i] = den_desc[i];

    const int w = tid >> 6, l = tid & 63;
    const int slotA = tid;            // heavy ranks
    const int slotB = 2047 - tid;     // paired light ranks
    const int rA0 = den_rp[slotA], rA1 = den_rp[slotA + 1];
    const int rB0 = den_rp[slotB], rB1 = den_rp[slotB + 1];
    float a0 = (slotA < S) ? den_init[den_perm[slotA]] : NEG_INF_F;
    float a1 = (slotB < S) ? den_init[den_perm[slotB]] : NEG_INF_F;

    const int nvec = C >> 2;
    const bool pf = ((C & 3) == 0) && ((((uintptr_t)llb) & 15) == 0) &&
                    (nvec <= nt) && (C <= MAX_C);

    // initial M reduce + EL stage for row 0 (buffer 0)
    float lm = fmaxf(a0, a1);
    for (int off = 32; off; off >>= 1) lm = fmaxf(lm, __shfl_down(lm, off));
    if ((tid & 63) == 0) red[tid >> 6] = lm;
    if (L > 0) {
      if (pf) {
        if (tid < nvec) {
          float4 r = ((const float4*)llb)[tid];
          elbuf[4 * tid + 0] = __expf(r.x); elbuf[4 * tid + 1] = __expf(r.y);
          elbuf[4 * tid + 2] = __expf(r.z); elbuf[4 * tid + 3] = __expf(r.w);
        }
      } else {
        for (int i = tid; i < C; i += nt) elbuf[i] = __expf(llb[i]);
      }
    }
    __syncthreads();
    float M = red[0];
#pragma unroll
    for (int i = 1; i < 16; ++i) M = fmaxf(M, red[i]);

    const bool ilv_ok = sdesc[64] != 0;
    const uint4* pA4 = den_ilv + sdesc[w] + l;
    const uint4* pB4 = den_ilv + sdesc[16 + w] + l;
    const int nA = sdesc[32 + w], nB = sdesc[48 + w];

    int cur = 0;
    for (int t = 0; t < L; ++t) {
      vbuf[slotA] = __expf(a0 - M);
      vbuf[slotB] = __expf(a1 - M);
      __syncthreads();                       // B1: vbuf + elbuf[cur] ready

      const float* el = elbuf + (cur ? MAX_C : 0);

      float4 nx;
      const bool donx = pf && (t + 1 < L) && (tid < nvec);
      if (donx) nx = ((const float4*)(llb + (size_t)(t + 1) * C))[tid];

      float sA0 = 0, sA1 = 0, sA2 = 0, sA3 = 0;
      float sB0 = 0, sB1 = 0, sB2 = 0, sB3 = 0;
      if (ilv_ok) {
        if (nA > 0) {
          uint4 X0 = pA4[0], Y0 = pA4[64];
          if (nA > 1) {
            uint4 X1 = pA4[128], Y1 = pA4[192];
            for (int c = 2; c < nA; ++c) {
              uint4 X2 = pA4[c * 128], Y2 = pA4[c * 128 + 64];
              ACC4(X0, Y0, sA0, sA1, sA2, sA3);
              X0 = X1; Y0 = Y1; X1 = X2; Y1 = Y2;
            }
            ACC4(X0, Y0, sA0, sA1, sA2, sA3);
            X0 = X1; Y0 = Y1;
          }
          ACC4(X0, Y0, sA0, sA1, sA2, sA3);
        }
        if (nB > 0) {
          uint4 X0 = pB4[0], Y0 = pB4[64];
          for (int c = 1; c < nB; ++c) {
            uint4 X1 = pB4[c * 128], Y1 = pB4[c * 128 + 64];
            ACC4(X0, Y0, sB0, sB1, sB2, sB3);
            X0 = X1; Y0 = Y1;
          }
          ACC4(X0, Y0, sB0, sB1, sB2, sB3);
        }
      } else {
        const uint4* pA = (const uint4*)(den_meta + rA0);
        const uint4* pB = (const uint4*)(den_meta + rB0);
        const int nAr = (rA1 - rA0) >> 2, nBr = (rB1 - rB0) >> 2;
        const int n = nAr > nBr ? nAr : nBr;
        for (int c = 0; c < n; ++c) {
          if (c < nAr) {
            uint4 X = pA[2 * c], Y = pA[2 * c + 1];
            ACC4(X, Y, sA0, sA1, sA2, sA3);
          }
          if (c < nBr) {
            uint4 X = pB[2 * c], Y = pB[2 * c + 1];
            ACC4(X, Y, sB0, sB1, sB2, sB3);
          }
        }
      }
      float sA = (sA0 + sA1) + (sA2 + sA3);
      float sB = (sB0 + sB1) + (sB2 + sB3);

      a0 = (sA > 0.0f) ? (__logf(sA) + M) : NEG_INF_F;
      a1 = (sB > 0.0f) ? (__logf(sB) + M) : NEG_INF_F;

      float* eln = elbuf + (cur ? 0 : MAX_C);
      if (donx) {
        eln[4 * tid + 0] = __expf(nx.x); eln[4 * tid + 1] = __expf(nx.y);
        eln[4 * tid + 2] = __expf(nx.z); eln[4 * tid + 3] = __expf(nx.w);
      } else if (!pf && t + 1 < L) {
        const float* nr = llb + (size_t)(t + 1) * C;
        for (int i = tid; i < C; i += nt) eln[i] = __expf(nr[i]);
      }

      float lm2 = fmaxf(a0, a1);
      for (int off = 32; off; off >>= 1) lm2 = fmaxf(lm2, __shfl_down(lm2, off));
      if ((tid & 63) == 0) red[tid >> 6] = lm2;
      __syncthreads();                       // B2: sums done, red + elbuf[nxt] visible
      M = red[0];
#pragma unroll
      for (int i = 1; i < 16; ++i) M = fmaxf(M, red[i]);
      cur ^= 1;
    }
    alpha[slotA] = a0;
    alpha[slotB] = a1;
    __syncthreads();
  } else {
    // ---- exact-LSE numerator (tiny) ----
    const uint2* meta = num_meta + (size_t)b * num_stride;
    const int*   rp   = num_rp + (size_t)b * (S_num + 1);
    for (int s = tid; s < MAX_S; s += nt) alpha[s] = (s < S) ? num_init[s] : NEG_INF_F;
    int rs[2] = {0, 0}, re[2] = {0, 0};
    for (int u = 0; u < 2; ++u) {
      int s = tid + u * nt;
      if (s < S) { rs[u] = rp[s]; re[u] = rp[s + 1]; }
    }
    __syncthreads();
    for (int t = 0; t < L; ++t) {
      stage_row(llb + (size_t)t * C, elbuf, C, tid, nt);
      __syncthreads();
      float nv[2];
      for (int u = 0; u < 2; ++u) {
        int s = tid + u * nt;
        nv[u] = (s < S) ? row_lse(meta, rs[u], re[u], alpha, elbuf) : NEG_INF_F;
      }
      __syncthreads();
      for (int u = 0; u < 2; ++u) {
        int s = tid + u * nt;
        if (s < S) alpha[s] = nv[u];
      }
      __syncthreads();
    }
  }

  // final logsumexp(alpha + final_logp)
  float lm = -3.0e38f;
  for (int s = tid; s < S; s += nt) lm = fmaxf(lm, alpha[s] + fin[perm ? perm[s] : s]);
  for (int off = 32; off; off >>= 1) lm = fmaxf(lm, __shfl_down(lm, off));
  if ((tid & 63) == 0) red[tid >> 6] = lm;
  __syncthreads();
  if (tid < 64) {
    float v = (tid < 16) ? red[tid] : -3.0e38f;
    for (int off = 32; off; off >>= 1) v = fmaxf(v, __shfl_down(v, off));
    if (tid == 0) red[0] = v;
  }
  __syncthreads();
  const float M = red[0];

  float ls = 0.0f;
  for (int s = tid; s < S; s += nt) ls += __expf(alpha[s] + fin[perm ? perm[s] : s] - M);
  for (int off = 32; off; off >>= 1) ls += __shfl_down(ls, off);
  __syncthreads();
  if ((tid & 63) == 0) red[tid >> 6] = ls;
  __syncthreads();
  if (tid < 64) {
    float v = (tid < 16) ? red[tid] : 0.0f;
    for (int off = 32; off; off >>= 1) v += __shfl_down(v, off);
    if (tid == 0) out_llh[(is_den ? 0 : B) + b] = __logf(v) + M;
  }
}

// ============================ fallback (atomic path, tiny ws) ============================

__device__ __forceinline__ unsigned enc_f(float x) {
  unsigned u = __float_as_uint(x);
  return u ^ (unsigned)(((int)u >> 31) | 0x80000000);
}
__device__ __forceinline__ float dec_f(unsigned e) {
  unsigned mask = ((int)e >= 0) ? 0xFFFFFFFFu : 0x80000000u;
  return __uint_as_float(e ^ mask);
}

__global__ __launch_bounds__(1024)
void fsa_forward_fallback(
    const float* __restrict__ ll, const int* __restrict__ seqlen,
    const int* __restrict__ den_src, const int* __restrict__ den_dst,
    const int* __restrict__ den_pdf, const float* __restrict__ den_w,
    int A_den, const float* __restrict__ den_init, const float* __restrict__ den_final, int S_den,
    const int* __restrict__ num_src, const int* __restrict__ num_dst,
    const int* __restrict__ num_pdf, const float* __restrict__ num_w,
    int A_num, const float* __restrict__ num_init, const float* __restrict__ num_final, int S_num,
    int T, int C, int B, float* __restrict__ out_llh)
{
  __shared__ float    alpha[MAX_S];
  __shared__ unsigned menc[MAX_S];
  __shared__ float    msafe[MAX_S];
  __shared__ float    ssum[MAX_S];
  __shared__ float    llrow[MAX_C];

  const int tid = threadIdx.x;
  const int nt  = blockDim.x;
  const bool is_den = ((int)blockIdx.x) < B;
  const int b = is_den ? (int)blockIdx.x : ((int)blockIdx.x - B);
  const int S = is_den ? S_den : S_num;
  const int A = is_den ? A_den : A_num;
  const float* init = is_den ? den_init  : num_init;
  const float* fin  = is_den ? den_final : num_final;
  const int*   asrc = is_den ? den_src  : (num_src + (size_t)b * A_num);
  const int*   adst = is_den ? den_dst  : (num_dst + (size_t)b * A_num);
  const int*   apdf = is_den ? den_pdf  : (num_pdf + (size_t)b * A_num);
  const float* aw   = is_den ? den_w    : (num_w   + (size_t)b * A_num);

  for (int s = tid; s < S; s += nt) { alpha[s] = init[s]; menc[s] = 0u; ssum[s] = 0.0f; }
  __syncthreads();

  const int L = seqlen[b];
  const float* llb = ll + ((size_t)b * T) * C;

  for (int t = 0; t < L; ++t) {
    const float* row = llb + (size_t)t * C;
    for (int i = tid; i < C; i += nt) llrow[i] = row[i];
    __syncthreads();
    for (int i = tid; i < A; i += nt) {
      float score = alpha[asrc[i]] + aw[i] + llrow[apdf[i]];
      atomicMax(&menc[adst[i]], enc_f(score));
    }
    __syncthreads();
    for (int s = tid; s < S; s += nt) {
      float m = dec_f(menc[s]);
      msafe[s] = (m > -5e29f) ? m : 0.0f;
    }
    __syncthreads();
    for (int i = tid; i < A; i += nt) {
      int d = adst[i];
      float score = alpha[asrc[i]] + aw[i] + llrow[apdf[i]];
      atomicAdd(&ssum[d], __expf(score - msafe[d]));
    }
    __syncthreads();
    for (int s = tid; s < S; s += nt) {
      float sum = ssum[s];
      alpha[s] = (sum > 0.0f) ? (__logf(sum) + msafe[s]) : NEG_INF_F;
      menc[s] = 0u; ssum[s] = 0.0f;
    }
    __syncthreads();
  }

  float lm = -3.0e38f;
  for (int s = tid; s < S; s += nt) lm = fmaxf(lm, alpha[s] + fin[s]);
  for (int off = 32; off; off >>= 1) lm = fmaxf(lm, __shfl_down(lm, off));
  const int nwaves = nt >> 6;
  if ((tid & 63) == 0) msafe[tid >> 6] = lm;
  __syncthreads();
  if (tid < 64) {
    float v = (tid < nwaves) ? msafe[tid] : -3.0e38f;
    for (int off = 32; off; off >>= 1) v = fmaxf(v, __shfl_down(v, off));
    if (tid == 0) msafe[MAX_S - 1] = v;
  }
  __syncthreads();
  const float M = msafe[MAX_S - 1];
  float ls = 0.0f;
  for (int s = tid; s < S; s += nt) ls += __expf(alpha[s] + fin[s] - M);
  for (int off = 32; off; off >>= 1) ls += __shfl_down(ls, off);
  if ((tid & 63) == 0) ssum[tid >> 6] = ls;
  __syncthreads();
  if (tid < 64) {
    float v = (tid < nwaves) ? ssum[tid] : 0.0f;
    for (int off = 32; off; off >>= 1) v += __shfl_down(v, off);
    if (tid == 0) out_llh[(is_den ? 0 : B) + b] = __logf(v) + M;
  }
}

// loss = sum_b (den_llh[b] - num_llh[b])
__global__ void final_loss_kernel(const float* __restrict__ llh, int B, float* __restrict__ out) {
  int lane = threadIdx.x;
  float v = (lane < B) ? (llh[lane] - llh[B + lane]) : 0.0f;
  for (int off = 32; off; off >>= 1) v += __shfl_down(v, off);
  if (lane == 0) out[0] = v;
}

extern "C" void kernel_launch(void* const* d_in, const int* in_sizes, int n_in,
                              void* d_out, int out_size, void* d_ws, size_t ws_size,
                              hipStream_t stream) {
  const float* ll        = (const float*)d_in[0];
  const int*   seqlen    = (const int*)  d_in[1];
  const int*   num_src   = (const int*)  d_in[2];
  const int*   num_dst   = (const int*)  d_in[3];
  const int*   num_pdf   = (const int*)  d_in[4];
  const float* num_w     = (const float*)d_in[5];
  const float* num_init  = (const float*)d_in[6];
  const float* num_final = (const float*)d_in[7];
  const int*   den_src   = (const int*)  d_in[8];
  const int*   den_dst   = (const int*)  d_in[9];
  const int*   den_pdf   = (const int*)  d_in[10];
  const float* den_w     = (const float*)d_in[11];
  const float* den_init  = (const float*)d_in[12];
  const float* den_final = (const float*)d_in[13];

  const int B     = in_sizes[1];
  const int A_num = in_sizes[2] / B;
  const int S_num = in_sizes[6];
  const int A_den = in_sizes[8];
  const int S_den = in_sizes[12];
  const int T     = 500;                       // problem spec
  const int C     = in_sizes[0] / (B * T);

  const int den_cap    = A_den + 3 * S_den + 64;
  const int num_stride = A_num + 3 * S_num + 64;
  const int cap4       = den_cap + 32768;      // interleaved capacity (uint4 units)

  // workspace layout
  size_t off = 0;
  auto alloc = [&](size_t bytes, size_t align) -> size_t {
    off = (off + align - 1) / align * align;
    size_t r = off; off += bytes; return r;
  };
  size_t o_den_meta = alloc((size_t)den_cap * 8, 16);
  size_t o_den_ilv  = alloc((size_t)cap4 * 16, 16);
  size_t o_desc     = alloc((size_t)66 * 4, 4);
  size_t o_num_meta = alloc((size_t)B * num_stride * 8, 16);
  size_t o_den_rp   = alloc((size_t)2049 * 4, 4);
  size_t o_num_rp   = alloc((size_t)B * (S_num + 1) * 4, 4);
  size_t o_den_cnt  = alloc((size_t)S_den * 4, 4);
  size_t o_perm     = alloc((size_t)2048 * 4, 4);
  size_t o_inv      = alloc((size_t)S_den * 4, 4);
  size_t o_pc       = alloc((size_t)2048 * 4, 4);
  size_t o_num_pc   = alloc((size_t)B * S_num * 4, 4);
  size_t o_hist     = alloc((size_t)NCH * S_den * 4, 4);   // zeroed region start
  size_t o_num_cnt  = alloc((size_t)B * S_num * 4, 4);     // contiguous with hist
  size_t o_llh      = alloc((size_t)2 * B * 4, 4);
  const bool use_csr = (off <= ws_size) && (S_den >= 1) && (S_den <= 2048) &&
                       (S_num >= 1) && (S_num <= 2048) && (C <= MAX_C) && (C >= 1);

  char* wsb = (char*)d_ws;
  float* llh = (float*)(wsb + (use_csr ? o_llh : 0));

  if (use_csr) {
    uint2* den_meta = (uint2*)(wsb + o_den_meta);
    uint4* den_ilv  = (uint4*)(wsb + o_den_ilv);
    int*   desc     = (int*)(wsb + o_desc);
    uint2* num_meta = (uint2*)(wsb + o_num_meta);
    int*   den_rp   = (int*)(wsb + o_den_rp);
    int*   num_rp   = (int*)(wsb + o_num_rp);
    int*   den_cnt  = (int*)(wsb + o_den_cnt);
    int*   perm     = (int*)(wsb + o_perm);
    int*   inv      = (int*)(wsb + o_inv);
    int*   pc       = (int*)(wsb + o_pc);
    int*   num_pc   = (int*)(wsb + o_num_pc);
    int*   hist     = (int*)(wsb + o_hist);
    int*   num_cnt  = (int*)(wsb + o_num_cnt);

    const int chunk = (A_den + NCH - 1) / NCH;

    // zero hist + num_cnt (contiguous)
    int ztot = NCH * S_den + B * S_num;
    zero_kernel<<<(ztot + 255) / 256, 256, 0, stream>>>(hist, ztot);

    hist_chunk_kernel<<<NCH, 256, 0, stream>>>(den_dst, A_den, chunk, S_den, hist);
    hist_kernel<<<dim3((A_num + 255) / 256, B), 256, 0, stream>>>(num_dst, A_num, A_num,
                                                                  num_cnt, S_num);

    colsum_kernel<<<(S_den + 255) / 256, 256, 0, stream>>>(hist, NCH, S_den, den_cnt);
    rank_perm_kernel<<<1, 1024, 0, stream>>>(den_cnt, S_den, perm, inv);
    pc_kernel<<<8, 256, 0, stream>>>(den_cnt, perm, S_den, pc);
    scan_kernel<<<1, 1024, 0, stream>>>(pc, den_rp, 2048);
    wave_desc_kernel<<<1, 1024, 0, stream>>>(den_rp, cap4, desc);

    padcnt_kernel<<<(B * S_num + 255) / 256, 256, 0, stream>>>(num_cnt, B * S_num, num_pc);
    scan_kernel<<<B, 1024, 0, stream>>>(num_pc, num_rp, S_num);

    off_perm_kernel<<<(S_den + 255) / 256, 256, 0, stream>>>(hist, NCH, S_den, den_rp, perm);
    pad_den_kernel<<<(S_den + 255) / 256, 256, 0, stream>>>(den_rp, den_cnt, perm, S_den, den_meta);
    fill_chunk_kernel<<<dim3((S_den + 255) / 256, NCH), 256, 0, stream>>>(
        den_src, den_dst, den_pdf, den_w, A_den, chunk, S_den, hist, inv, den_meta);
    fill_kernel<<<dim3((S_num + 255) / 256, B), 256, 0, stream>>>(
        num_src, num_dst, num_pdf, num_w, A_num, A_num, num_rp, S_num, num_meta, num_stride);

    repack_greedy_kernel<<<32, 64, 0, stream>>>(den_meta, den_rp, desc, C, (uint2*)den_ilv);

    fsa_forward_lin<<<2 * B, 1024, 0, stream>>>(
        ll, seqlen, den_meta, den_ilv, desc, den_rp, perm, S_den,
        num_meta, num_rp, num_stride, S_num,
        den_init, den_final, num_init, num_final, T, C, B, llh);
  } else {
    fsa_forward_fallback<<<2 * B, 1024, 0, stream>>>(
        ll, seqlen,
        den_src, den_dst, den_pdf, den_w, A_den, den_init, den_final, S_den,
        num_src, num_dst, num_pdf, num_w, A_num, num_init, num_final, S_num,
        T, C, B, llh);
  }

  final_loss_kernel<<<1, 64, 0, stream>>>(llh, B, (float*)d_out);
}

// Round 10
// 3630.796 us; speedup vs baseline: 1.0672x; 1.0141x over previous
//
#include <hip/hip_runtime.h>

#define NEG_INF_F (-1e30f)
#define MAX_S 2048
#define MAX_C 3008
#define NCH   128

// ============================ build helpers (deterministic) ============================

__global__ void zero_kernel(int* __restrict__ p, int n) {
  int i = blockIdx.x * blockDim.x + threadIdx.x;
  if (i < n) p[i] = 0;
}

__global__ void hist_kernel(const int* __restrict__ dst, int A, int A_stride,
                            int* __restrict__ cnt, int S) {
  int b = blockIdx.y;
  int i = blockIdx.x * blockDim.x + threadIdx.x;
  if (i < A) atomicAdd(&cnt[b * S + dst[(size_t)b * A_stride + i]], 1);
}

__global__ void hist_chunk_kernel(const int* __restrict__ dst, int A, int chunk, int S,
                                  int* __restrict__ hist) {
  int c = blockIdx.x;
  int i1 = min(A, (c + 1) * chunk);
  for (int i = c * chunk + threadIdx.x; i < i1; i += blockDim.x)
    atomicAdd(&hist[c * S + dst[i]], 1);
}

__global__ void colsum_kernel(const int* __restrict__ hist, int nch, int S,
                              int* __restrict__ cnt) {
  int s = blockIdx.x * blockDim.x + threadIdx.x;
  if (s < S) {
    int t = 0;
    for (int c = 0; c < nch; ++c) t += hist[c * S + s];
    cnt[s] = t;
  }
}

// Stable in-degree rank (desc) -> slot permutation pairing heavy with light.
__global__ __launch_bounds__(1024)
void rank_perm_kernel(const int* __restrict__ cnt, int S,
                      int* __restrict__ perm, int* __restrict__ invperm) {
  __shared__ int c[2048];
  __shared__ int R[2048];
  const int tid = threadIdx.x;
  for (int i = tid; i < 2048; i += 1024) c[i] = (i < S) ? cnt[i] : -1;
  __syncthreads();
  for (int u = 0; u < 2; ++u) {
    int s = tid + u * 1024;
    if (s < S) {
      int cs = c[s], r = 0;
      for (int j = 0; j < S; ++j) {
        int cj = c[j];
        r += (cj > cs) || (cj == cs && j < s);
      }
      R[r] = s;
    }
  }
  __syncthreads();
  for (int u = 0; u < 2; ++u) {
    int slot = tid + u * 1024;
    if (slot < S) {
      int state = (slot < 1024) ? R[slot] : R[S - 1 - (slot - 1024)];
      perm[slot] = state;
      invperm[state] = slot;
    }
  }
}

__global__ void pc_kernel(const int* __restrict__ cnt, const int* __restrict__ perm,
                          int S, int* __restrict__ pc) {
  int slot = blockIdx.x * blockDim.x + threadIdx.x;
  if (slot < 2048) pc[slot] = (slot < S) ? ((cnt[perm[slot]] + 3) & ~3) : 0;
}

__global__ void padcnt_kernel(const int* __restrict__ cnt, int n, int* __restrict__ out) {
  int i = blockIdx.x * blockDim.x + threadIdx.x;
  if (i < n) out[i] = (cnt[i] + 3) & ~3;
}

__global__ __launch_bounds__(1024) void scan_kernel(const int* __restrict__ cnt,
                                                    int* __restrict__ rp, int S) {
  __shared__ int buf[2][2048];
  const int tid = threadIdx.x;
  const int b = blockIdx.x;
  const int* c = cnt + (size_t)b * S;
  int* r = rp + (size_t)b * (S + 1);
  for (int u = 0; u < 2; ++u) {
    int i = tid + u * 1024;
    buf[0][i] = (i < S) ? c[i] : 0;
  }
  __syncthreads();
  int cur = 0;
  for (int off = 1; off < 2048; off <<= 1) {
    for (int u = 0; u < 2; ++u) {
      int i = tid + u * 1024;
      buf[cur ^ 1][i] = buf[cur][i] + ((i >= off) ? buf[cur][i - off] : 0);
    }
    __syncthreads();
    cur ^= 1;
  }
  for (int u = 0; u < 2; ++u) {
    int i = tid + u * 1024;
    if (i <= S) r[i] = (i == 0) ? 0 : buf[cur][i - 1];
  }
  if (tid == 0) r[S] = buf[cur][S - 1];
}

__global__ void off_perm_kernel(int* __restrict__ hist, int nch, int S,
                                const int* __restrict__ rp, const int* __restrict__ perm) {
  int slot = blockIdx.x * blockDim.x + threadIdx.x;
  if (slot < S) {
    int state = perm[slot];
    int run = rp[slot];
    for (int c = 0; c < nch; ++c) {
      int h = hist[c * S + state];
      hist[c * S + state] = run;
      run += h;
    }
  }
}

// fill pad arcs at row tails (den): y==0 marks pad (ew = 0)
__global__ void pad_den_kernel(const int* __restrict__ rp, const int* __restrict__ cnt,
                               const int* __restrict__ perm, int S, uint2* __restrict__ meta) {
  int slot = blockIdx.x * blockDim.x + threadIdx.x;
  if (slot < S) {
    int p = rp[slot] + cnt[perm[slot]];
    int e = rp[slot + 1];
    uint2 pad = make_uint2(0u, 0u);
    for (; p < e; ++p) meta[p] = pad;
  }
}

// DEN meta: x = (src_slot*4) | ((pdf*4)<<16)  (pre-scaled LDS byte offsets), y = exp(w).
__global__ void fill_chunk_kernel(const int* __restrict__ src, const int* __restrict__ dst,
                                  const int* __restrict__ pdf, const float* __restrict__ w,
                                  int A, int chunk, int S, int* __restrict__ hoff,
                                  const int* __restrict__ inv, uint2* __restrict__ meta) {
  int c = blockIdx.y;
  int s = blockIdx.x * blockDim.x + threadIdx.x;
  if (s >= S) return;
  int i1 = min(A, (c + 1) * chunk);
  int p = hoff[c * S + s];
  for (int i = c * chunk; i < i1; ++i) {
    if (dst[i] == s) {
      meta[p++] = make_uint2((unsigned)(inv[src[i]] * 4) | ((unsigned)(pdf[i] * 4) << 16),
                             __float_as_uint(__expf(w[i])));
    }
  }
}

// numerator meta keeps index packing (src | pdf<<16) + raw w
__global__ void fill_kernel(const int* __restrict__ src, const int* __restrict__ dst,
                            const int* __restrict__ pdf, const float* __restrict__ w,
                            int A, int A_stride, const int* __restrict__ rp, int S,
                            uint2* __restrict__ meta, int meta_stride) {
  int b = blockIdx.y;
  int s = blockIdx.x * blockDim.x + threadIdx.x;
  if (s >= S) return;
  const int*   sb = src + (size_t)b * A_stride;
  const int*   db = dst + (size_t)b * A_stride;
  const int*   pb = pdf + (size_t)b * A_stride;
  const float* wb = w   + (size_t)b * A_stride;
  const int*   rpb = rp + (size_t)b * (S + 1);
  uint2* mb = meta + (size_t)b * meta_stride;
  int p = rpb[s];
  for (int i = 0; i < A; ++i) {
    if (db[i] == s) {
      mb[p++] = make_uint2((unsigned)sb[i] | ((unsigned)pb[i] << 16), __float_as_uint(wb[i]));
    }
  }
  uint2 pad = make_uint2(0u, __float_as_uint(NEG_INF_F));
  int e = rpb[s + 1];
  for (; p < e; ++p) mb[p] = pad;
}

// ---- wave-interleaved den meta: desc = offA[16],offB[16],wmaxA[16],wmaxB[16],ok,total ----
__global__ __launch_bounds__(1024)
void wave_desc_kernel(const int* __restrict__ rp, int cap4, int* __restrict__ desc) {
  __shared__ int wm[32];
  const int tid = threadIdx.x;
  const int w = tid >> 6;
  int cA = (rp[tid + 1] - rp[tid]) >> 2;
  int sB = 2047 - tid;
  int cB = (rp[sB + 1] - rp[sB]) >> 2;
  for (int off = 32; off; off >>= 1) {
    cA = max(cA, __shfl_down(cA, off));
    cB = max(cB, __shfl_down(cB, off));
  }
  if ((tid & 63) == 0) { wm[w] = cA; wm[16 + w] = cB; }
  __syncthreads();
  if (tid == 0) {
    int off = 0;
    for (int i = 0; i < 16; ++i) { desc[i] = off; off += wm[i] * 128; }
    for (int i = 0; i < 16; ++i) { desc[16 + i] = off; off += wm[16 + i] * 128; }
    for (int i = 0; i < 16; ++i) { desc[32 + i] = wm[i]; desc[48 + i] = wm[16 + i]; }
    desc[64] = (off <= cap4) ? 1 : 0;
    desc[65] = off;
  }
}

// Bank-sort + lane-rotation placement. grid 32 blocks x 64 lanes (single wave).
// Each lane independently handles its own row: rank the row's real arcs by
// bank(src) (stable), place rank j at position (j + lane) % nreal. At any fixed
// position p, the 64 rows present staggered points of their sorted bank order ->
// the vbuf gather's banks are swept/staggered (~2-3-way instead of random ~5-way).
// Sums are order-invariant in linear space, so any within-row permutation is exact.
// No cross-lane dependence: ~n^2 (<=4096) independent ALU iterations per lane.
__global__ __launch_bounds__(64)
void repack_sort_kernel(const uint2* __restrict__ meta, const int* __restrict__ rp,
                        const int* __restrict__ desc, int C, uint2* __restrict__ ilv) {
  if (!desc[64]) return;
  const int w = blockIdx.x & 15;
  const bool isB = blockIdx.x >= 16;
  const int l = threadIdx.x;
  const int base4 = desc[(isB ? 16 : 0) + w];
  const int wmax  = desc[(isB ? 48 : 32) + w];
  const int P = wmax * 4;
  if (P == 0) return;

  const int slot_l = isB ? (2047 - (w * 64 + l)) : (w * 64 + l);
  const int r0_l = rp[slot_l];
  const int n_l  = rp[slot_l + 1] - r0_l;

  const int slot_lo = isB ? (2047 - (w * 64 + 63)) : (w * 64);
  const int mbase = rp[slot_lo];
  const int total = rp[slot_lo + 64] - mbase;

  __shared__ uint2 smeta[4096];   // 32 KB

  if (P > 64 || total > 4096) {
    // fallback: order-preserving interleave copy
    const int n4 = n_l >> 2;
    for (int c = 0; c < wmax; ++c) {
      for (int part = 0; part < 2; ++part) {
        int u4 = base4 + c * 128 + part * 64 + l;
        uint2 v0 = make_uint2(0u, 0u), v1 = make_uint2(0u, 0u);
        if (c < n4) {
          v0 = meta[r0_l + 4 * c + 2 * part];
          v1 = meta[r0_l + 4 * c + 2 * part + 1];
        }
        ilv[2 * u4]     = v0;
        ilv[2 * u4 + 1] = v1;
      }
    }
    return;
  }

  // stage wave slab into LDS (coalesced)
  for (int i = l; i < total; i += 64) smeta[i] = meta[mbase + i];
  __syncthreads();

  const int myOff = r0_l - mbase;

  // count real arcs (ew != 0); zero-weight arcs contribute exactly 0 -> treated as pads
  int nreal = 0;
  for (int k = 0; k < n_l; ++k) nreal += (smeta[myOff + k].y != 0u) ? 1 : 0;

  unsigned long long used = 0ULL;
  if (nreal > 0) {
    const int rot = l % nreal;
    for (int k = 0; k < n_l; ++k) {
      uint2 a = smeta[myOff + k];
      if (a.y == 0u) continue;
      const int bk = (a.x >> 2) & 31;
      int rank = 0;
      for (int k2 = 0; k2 < n_l; ++k2) {
        uint2 a2 = smeta[myOff + k2];
        if (a2.y == 0u) continue;
        const int b2 = (a2.x >> 2) & 31;
        rank += ((b2 < bk) || (b2 == bk && k2 < k)) ? 1 : 0;
      }
      int p = rank + rot;
      if (p >= nreal) p -= nreal;
      used |= (1ULL << p);
      const int idx = 2 * (base4 + (p >> 2) * 128 + (((p >> 1) & 1) * 64) + l) + (p & 1);
      ilv[idx] = a;
    }
  }

  // fill remaining positions with bank-spread pads (ew = 0)
  unsigned long long fm = (~used) & ((P >= 64) ? ~0ULL : ((1ULL << P) - 1ULL));
  const int pc = min(slot_l, C - 1);
  const uint2 pad = make_uint2((unsigned)(slot_l * 4) | ((unsigned)(pc * 4) << 16), 0u);
  while (fm) {
    const int p = __ffsll(fm) - 1;
    fm &= fm - 1ULL;
    const int idx = 2 * (base4 + (p >> 2) * 128 + (((p >> 1) & 1) * 64) + l) + (p & 1);
    ilv[idx] = pad;
  }
}

// ============================ exact row LSE (numerator path) ============================

__device__ __forceinline__ float row_lse(const uint2* __restrict__ meta, int k, int e,
                                         const float* __restrict__ alpha,
                                         const float* __restrict__ lcur) {
  float mm0 = NEG_INF_F, ss0 = 0.0f, mm1 = NEG_INF_F, ss1 = 0.0f;
  const int n4 = (e - k) >> 2;
  const uint4* p = (const uint4*)(meta + k);
  if (n4 > 0) {
    uint4 A = p[0], Bv = p[1];
    float t0 = alpha[A.x & 0xFFFFu] + __uint_as_float(A.y) + lcur[A.x >> 16];
    float t1 = alpha[A.z & 0xFFFFu] + __uint_as_float(A.w) + lcur[A.z >> 16];
    float t2 = alpha[Bv.x & 0xFFFFu] + __uint_as_float(Bv.y) + lcur[Bv.x >> 16];
    float t3 = alpha[Bv.z & 0xFFFFu] + __uint_as_float(Bv.w) + lcur[Bv.z >> 16];
    for (int c2 = 1; c2 < n4; ++c2) {
      uint4 A2 = p[2 * c2], B2 = p[2 * c2 + 1];
      float u0 = alpha[A2.x & 0xFFFFu] + __uint_as_float(A2.y) + lcur[A2.x >> 16];
      float u1 = alpha[A2.z & 0xFFFFu] + __uint_as_float(A2.w) + lcur[A2.z >> 16];
      float u2 = alpha[B2.x & 0xFFFFu] + __uint_as_float(B2.y) + lcur[B2.x >> 16];
      float u3 = alpha[B2.z & 0xFFFFu] + __uint_as_float(B2.w) + lcur[B2.z >> 16];
      float mc = fmaxf(fmaxf(t0, t1), fmaxf(t2, t3));
      if ((c2 & 1) != 0) {
        float nm = fmaxf(mm0, mc);
        ss0 = ss0 * __expf(mm0 - nm) +
              ((__expf(t0 - nm) + __expf(t1 - nm)) + (__expf(t2 - nm) + __expf(t3 - nm)));
        mm0 = nm;
      } else {
        float nm = fmaxf(mm1, mc);
        ss1 = ss1 * __expf(mm1 - nm) +
              ((__expf(t0 - nm) + __expf(t1 - nm)) + (__expf(t2 - nm) + __expf(t3 - nm)));
        mm1 = nm;
      }
      t0 = u0; t1 = u1; t2 = u2; t3 = u3;
    }
    float mc = fmaxf(fmaxf(t0, t1), fmaxf(t2, t3));
    if ((n4 & 1) != 0) {
      float nm = fmaxf(mm0, mc);
      ss0 = ss0 * __expf(mm0 - nm) +
            ((__expf(t0 - nm) + __expf(t1 - nm)) + (__expf(t2 - nm) + __expf(t3 - nm)));
      mm0 = nm;
    } else {
      float nm = fmaxf(mm1, mc);
      ss1 = ss1 * __expf(mm1 - nm) +
            ((__expf(t0 - nm) + __expf(t1 - nm)) + (__expf(t2 - nm) + __expf(t3 - nm)));
      mm1 = nm;
    }
  }
  float nm = fmaxf(mm0, mm1);
  float ssc = ss0 * __expf(mm0 - nm) + ss1 * __expf(mm1 - nm);
  return (ssc > 0.0f) ? (__logf(ssc) + nm) : NEG_INF_F;
}

__device__ __forceinline__ void stage_row(const float* __restrict__ row,
                                          float* __restrict__ lds, int C, int tid, int nt) {
  if (((C & 3) == 0) && ((((uintptr_t)row) & 15) == 0)) {
    const float4* r4 = (const float4*)row;
    const int n = C >> 2;
    for (int i = tid; i < n; i += nt) ((float4*)lds)[i] = r4[i];
  } else {
    for (int i = tid; i < C; i += nt) lds[i] = row[i];
  }
}

// LDS read with pre-scaled byte offset
__device__ __forceinline__ float ldsF(const float* base, unsigned boff) {
  return *(const float*)((const char*)base + boff);
}

#define ACC4(X, Y, s0, s1, s2, s3)                                                         \
  s0 = fmaf(__uint_as_float((X).y), ldsF(vbuf, (X).x & 0xFFFFu) * ldsF(el, (X).x >> 16), s0); \
  s1 = fmaf(__uint_as_float((X).w), ldsF(vbuf, (X).z & 0xFFFFu) * ldsF(el, (X).z >> 16), s1); \
  s2 = fmaf(__uint_as_float((Y).y), ldsF(vbuf, (Y).x & 0xFFFFu) * ldsF(el, (Y).x >> 16), s2); \
  s3 = fmaf(__uint_as_float((Y).w), ldsF(vbuf, (Y).z & 0xFFFFu) * ldsF(el, (Y).z >> 16), s3);

// ============================ forward: den linear-space (sorted-interleaved), num exact-LSE ============================
__global__ __launch_bounds__(1024, 4)
void fsa_forward_lin(const float* __restrict__ ll, const int* __restrict__ seqlen,
                     const uint2* __restrict__ den_meta, const uint4* __restrict__ den_ilv,
                     const int* __restrict__ den_desc,
                     const int* __restrict__ den_rp, const int* __restrict__ den_perm, int S_den,
                     const uint2* __restrict__ num_meta, const int* __restrict__ num_rp,
                     int num_stride, int S_num,
                     const float* __restrict__ den_init, const float* __restrict__ den_final,
                     const float* __restrict__ num_init, const float* __restrict__ num_final,
                     int T, int C, int B, float* __restrict__ out_llh)
{
  __shared__ float alpha[MAX_S];
  __shared__ float vbuf[MAX_S];
  __shared__ float elbuf[2 * MAX_C];   // den: exp(ll) double-buffered ; num: raw ll (half 0)
  __shared__ float red[16];
  __shared__ int   sdesc[66];

  const int tid = threadIdx.x;
  const int nt  = 1024;
  const bool is_den = ((int)blockIdx.x) < B;
  const int b = is_den ? (int)blockIdx.x : ((int)blockIdx.x - B);
  const int S = is_den ? S_den : S_num;
  const float* fin  = is_den ? den_final : num_final;
  const int*   perm = is_den ? den_perm  : nullptr;

  const int L = seqlen[b];
  const float* llb = ll + ((size_t)b * T) * C;

  if (is_den) {
    // ---- linear-space denominator, 2 barriers/step ----
    for (int i = tid; i < 66; i += nt) sdesc[i] = den_desc[i];

    const int w = tid >> 6, l = tid & 63;
    const int slotA = tid;            // heavy ranks
    const int slotB = 2047 - tid;     // paired light ranks
    const int rA0 = den_rp[slotA], rA1 = den_rp[slotA + 1];
    const int rB0 = den_rp[slotB], rB1 = den_rp[slotB + 1];
    float a0 = (slotA < S) ? den_init[den_perm[slotA]] : NEG_INF_F;
    float a1 = (slotB < S) ? den_init[den_perm[slotB]] : NEG_INF_F;

    const int nvec = C >> 2;
    const bool pf = ((C & 3) == 0) && ((((uintptr_t)llb) & 15) == 0) &&
                    (nvec <= nt) && (C <= MAX_C);

    // initial M reduce + EL stage for row 0 (buffer 0)
    float lm = fmaxf(a0, a1);
    for (int off = 32; off; off >>= 1) lm = fmaxf(lm, __shfl_down(lm, off));
    if ((tid & 63) == 0) red[tid >> 6] = lm;
    if (L > 0) {
      if (pf) {
        if (tid < nvec) {
          float4 r = ((const float4*)llb)[tid];
          elbuf[4 * tid + 0] = __expf(r.x); elbuf[4 * tid + 1] = __expf(r.y);
          elbuf[4 * tid + 2] = __expf(r.z); elbuf[4 * tid + 3] = __expf(r.w);
        }
      } else {
        for (int i = tid; i < C; i += nt) elbuf[i] = __expf(llb[i]);
      }
    }
    __syncthreads();
    float M = red[0];
#pragma unroll
    for (int i = 1; i < 16; ++i) M = fmaxf(M, red[i]);

    const bool ilv_ok = sdesc[64] != 0;
    const uint4* pA4 = den_ilv + sdesc[w] + l;
    const uint4* pB4 = den_ilv + sdesc[16 + w] + l;
    const int nA = sdesc[32 + w], nB = sdesc[48 + w];

    int cur = 0;
    for (int t = 0; t < L; ++t) {
      vbuf[slotA] = __expf(a0 - M);
      vbuf[slotB] = __expf(a1 - M);
      __syncthreads();                       // B1: vbuf + elbuf[cur] ready

      const float* el = elbuf + (cur ? MAX_C : 0);

      float4 nx;
      const bool donx = pf && (t + 1 < L) && (tid < nvec);
      if (donx) nx = ((const float4*)(llb + (size_t)(t + 1) * C))[tid];

      float sA0 = 0, sA1 = 0, sA2 = 0, sA3 = 0;
      float sB0 = 0, sB1 = 0, sB2 = 0, sB3 = 0;
      if (ilv_ok) {
        if (nA > 0) {
          uint4 X0 = pA4[0], Y0 = pA4[64];
          if (nA > 1) {
            uint4 X1 = pA4[128], Y1 = pA4[192];
            for (int c = 2; c < nA; ++c) {
              uint4 X2 = pA4[c * 128], Y2 = pA4[c * 128 + 64];
              ACC4(X0, Y0, sA0, sA1, sA2, sA3);
              X0 = X1; Y0 = Y1; X1 = X2; Y1 = Y2;
            }
            ACC4(X0, Y0, sA0, sA1, sA2, sA3);
            X0 = X1; Y0 = Y1;
          }
          ACC4(X0, Y0, sA0, sA1, sA2, sA3);
        }
        if (nB > 0) {
          uint4 X0 = pB4[0], Y0 = pB4[64];
          for (int c = 1; c < nB; ++c) {
            uint4 X1 = pB4[c * 128], Y1 = pB4[c * 128 + 64];
            ACC4(X0, Y0, sB0, sB1, sB2, sB3);
            X0 = X1; Y0 = Y1;
          }
          ACC4(X0, Y0, sB0, sB1, sB2, sB3);
        }
      } else {
        const uint4* pA = (const uint4*)(den_meta + rA0);
        const uint4* pB = (const uint4*)(den_meta + rB0);
        const int nAr = (rA1 - rA0) >> 2, nBr = (rB1 - rB0) >> 2;
        const int n = nAr > nBr ? nAr : nBr;
        for (int c = 0; c < n; ++c) {
          if (c < nAr) {
            uint4 X = pA[2 * c], Y = pA[2 * c + 1];
            ACC4(X, Y, sA0, sA1, sA2, sA3);
          }
          if (c < nBr) {
            uint4 X = pB[2 * c], Y = pB[2 * c + 1];
            ACC4(X, Y, sB0, sB1, sB2, sB3);
          }
        }
      }
      float sA = (sA0 + sA1) + (sA2 + sA3);
      float sB = (sB0 + sB1) + (sB2 + sB3);

      a0 = (sA > 0.0f) ? (__logf(sA) + M) : NEG_INF_F;
      a1 = (sB > 0.0f) ? (__logf(sB) + M) : NEG_INF_F;

      float* eln = elbuf + (cur ? 0 : MAX_C);
      if (donx) {
        eln[4 * tid + 0] = __expf(nx.x); eln[4 * tid + 1] = __expf(nx.y);
        eln[4 * tid + 2] = __expf(nx.z); eln[4 * tid + 3] = __expf(nx.w);
      } else if (!pf && t + 1 < L) {
        const float* nr = llb + (size_t)(t + 1) * C;
        for (int i = tid; i < C; i += nt) eln[i] = __expf(nr[i]);
      }

      float lm2 = fmaxf(a0, a1);
      for (int off = 32; off; off >>= 1) lm2 = fmaxf(lm2, __shfl_down(lm2, off));
      if ((tid & 63) == 0) red[tid >> 6] = lm2;
      __syncthreads();                       // B2: sums done, red + elbuf[nxt] visible
      M = red[0];
#pragma unroll
      for (int i = 1; i < 16; ++i) M = fmaxf(M, red[i]);
      cur ^= 1;
    }
    alpha[slotA] = a0;
    alpha[slotB] = a1;
    __syncthreads();
  } else {
    // ---- exact-LSE numerator (tiny) ----
    const uint2* meta = num_meta + (size_t)b * num_stride;
    const int*   rp   = num_rp + (size_t)b * (S_num + 1);
    for (int s = tid; s < MAX_S; s += nt) alpha[s] = (s < S) ? num_init[s] : NEG_INF_F;
    int rs[2] = {0, 0}, re[2] = {0, 0};
    for (int u = 0; u < 2; ++u) {
      int s = tid + u * nt;
      if (s < S) { rs[u] = rp[s]; re[u] = rp[s + 1]; }
    }
    __syncthreads();
    for (int t = 0; t < L; ++t) {
      stage_row(llb + (size_t)t * C, elbuf, C, tid, nt);
      __syncthreads();
      float nv[2];
      for (int u = 0; u < 2; ++u) {
        int s = tid + u * nt;
        nv[u] = (s < S) ? row_lse(meta, rs[u], re[u], alpha, elbuf) : NEG_INF_F;
      }
      __syncthreads();
      for (int u = 0; u < 2; ++u) {
        int s = tid + u * nt;
        if (s < S) alpha[s] = nv[u];
      }
      __syncthreads();
    }
  }

  // final logsumexp(alpha + final_logp)
  float lm = -3.0e38f;
  for (int s = tid; s < S; s += nt) lm = fmaxf(lm, alpha[s] + fin[perm ? perm[s] : s]);
  for (int off = 32; off; off >>= 1) lm = fmaxf(lm, __shfl_down(lm, off));
  if ((tid & 63) == 0) red[tid >> 6] = lm;
  __syncthreads();
  if (tid < 64) {
    float v = (tid < 16) ? red[tid] : -3.0e38f;
    for (int off = 32; off; off >>= 1) v = fmaxf(v, __shfl_down(v, off));
    if (tid == 0) red[0] = v;
  }
  __syncthreads();
  const float M = red[0];

  float ls = 0.0f;
  for (int s = tid; s < S; s += nt) ls += __expf(alpha[s] + fin[perm ? perm[s] : s] - M);
  for (int off = 32; off; off >>= 1) ls += __shfl_down(ls, off);
  __syncthreads();
  if ((tid & 63) == 0) red[tid >> 6] = ls;
  __syncthreads();
  if (tid < 64) {
    float v = (tid < 16) ? red[tid] : 0.0f;
    for (int off = 32; off; off >>= 1) v += __shfl_down(v, off);
    if (tid == 0) out_llh[(is_den ? 0 : B) + b] = __logf(v) + M;
  }
}

// ============================ fallback (atomic path, tiny ws) ============================

__device__ __forceinline__ unsigned enc_f(float x) {
  unsigned u = __float_as_uint(x);
  return u ^ (unsigned)(((int)u >> 31) | 0x80000000);
}
__device__ __forceinline__ float dec_f(unsigned e) {
  unsigned mask = ((int)e >= 0) ? 0xFFFFFFFFu : 0x80000000u;
  return __uint_as_float(e ^ mask);
}

__global__ __launch_bounds__(1024)
void fsa_forward_fallback(
    const float* __restrict__ ll, const int* __restrict__ seqlen,
    const int* __restrict__ den_src, const int* __restrict__ den_dst,
    const int* __restrict__ den_pdf, const float* __restrict__ den_w,
    int A_den, const float* __restrict__ den_init, const float* __restrict__ den_final, int S_den,
    const int* __restrict__ num_src, const int* __restrict__ num_dst,
    const int* __restrict__ num_pdf, const float* __restrict__ num_w,
    int A_num, const float* __restrict__ num_init, const float* __restrict__ num_final, int S_num,
    int T, int C, int B, float* __restrict__ out_llh)
{
  __shared__ float    alpha[MAX_S];
  __shared__ unsigned menc[MAX_S];
  __shared__ float    msafe[MAX_S];
  __shared__ float    ssum[MAX_S];
  __shared__ float    llrow[MAX_C];

  const int tid = threadIdx.x;
  const int nt  = blockDim.x;
  const bool is_den = ((int)blockIdx.x) < B;
  const int b = is_den ? (int)blockIdx.x : ((int)blockIdx.x - B);
  const int S = is_den ? S_den : S_num;
  const int A = is_den ? A_den : A_num;
  const float* init = is_den ? den_init  : num_init;
  const float* fin  = is_den ? den_final : num_final;
  const int*   asrc = is_den ? den_src  : (num_src + (size_t)b * A_num);
  const int*   adst = is_den ? den_dst  : (num_dst + (size_t)b * A_num);
  const int*   apdf = is_den ? den_pdf  : (num_pdf + (size_t)b * A_num);
  const float* aw   = is_den ? den_w    : (num_w   + (size_t)b * A_num);

  for (int s = tid; s < S; s += nt) { alpha[s] = init[s]; menc[s] = 0u; ssum[s] = 0.0f; }
  __syncthreads();

  const int L = seqlen[b];
  const float* llb = ll + ((size_t)b * T) * C;

  for (int t = 0; t < L; ++t) {
    const float* row = llb + (size_t)t * C;
    for (int i = tid; i < C; i += nt) llrow[i] = row[i];
    __syncthreads();
    for (int i = tid; i < A; i += nt) {
      float score = alpha[asrc[i]] + aw[i] + llrow[apdf[i]];
      atomicMax(&menc[adst[i]], enc_f(score));
    }
    __syncthreads();
    for (int s = tid; s < S; s += nt) {
      float m = dec_f(menc[s]);
      msafe[s] = (m > -5e29f) ? m : 0.0f;
    }
    __syncthreads();
    for (int i = tid; i < A; i += nt) {
      int d = adst[i];
      float score = alpha[asrc[i]] + aw[i] + llrow[apdf[i]];
      atomicAdd(&ssum[d], __expf(score - msafe[d]));
    }
    __syncthreads();
    for (int s = tid; s < S; s += nt) {
      float sum = ssum[s];
      alpha[s] = (sum > 0.0f) ? (__logf(sum) + msafe[s]) : NEG_INF_F;
      menc[s] = 0u; ssum[s] = 0.0f;
    }
    __syncthreads();
  }

  float lm = -3.0e38f;
  for (int s = tid; s < S; s += nt) lm = fmaxf(lm, alpha[s] + fin[s]);
  for (int off = 32; off; off >>= 1) lm = fmaxf(lm, __shfl_down(lm, off));
  const int nwaves = nt >> 6;
  if ((tid & 63) == 0) msafe[tid >> 6] = lm;
  __syncthreads();
  if (tid < 64) {
    float v = (tid < nwaves) ? msafe[tid] : -3.0e38f;
    for (int off = 32; off; off >>= 1) v = fmaxf(v, __shfl_down(v, off));
    if (tid == 0) msafe[MAX_S - 1] = v;
  }
  __syncthreads();
  const float M = msafe[MAX_S - 1];
  float ls = 0.0f;
  for (int s = tid; s < S; s += nt) ls += __expf(alpha[s] + fin[s] - M);
  for (int off = 32; off; off >>= 1) ls += __shfl_down(ls, off);
  if ((tid & 63) == 0) ssum[tid >> 6] = ls;
  __syncthreads();
  if (tid < 64) {
    float v = (tid < nwaves) ? ssum[tid] : 0.0f;
    for (int off = 32; off; off >>= 1) v += __shfl_down(v, off);
    if (tid == 0) out_llh[(is_den ? 0 : B) + b] = __logf(v) + M;
  }
}

// loss = sum_b (den_llh[b] - num_llh[b])
__global__ void final_loss_kernel(const float* __restrict__ llh, int B, float* __restrict__ out) {
  int lane = threadIdx.x;
  float v = (lane < B) ? (llh[lane] - llh[B + lane]) : 0.0f;
  for (int off = 32; off; off >>= 1) v += __shfl_down(v, off);
  if (lane == 0) out[0] = v;
}

extern "C" void kernel_launch(void* const* d_in, const int* in_sizes, int n_in,
                              void* d_out, int out_size, void* d_ws, size_t ws_size,
                              hipStream_t stream) {
  const float* ll        = (const float*)d_in[0];
  const int*   seqlen    = (const int*)  d_in[1];
  const int*   num_src   = (const int*)  d_in[2];
  const int*   num_dst   = (const int*)  d_in[3];
  const int*   num_pdf   = (const int*)  d_in[4];
  const float* num_w     = (const float*)d_in[5];
  const float* num_init  = (const float*)d_in[6];
  const float* num_final = (const float*)d_in[7];
  const int*   den_src   = (const int*)  d_in[8];
  const int*   den_dst   = (const int*)  d_in[9];
  const int*   den_pdf   = (const int*)  d_in[10];
  const float* den_w     = (const float*)d_in[11];
  const float* den_init  = (const float*)d_in[12];
  const float* den_final = (const float*)d_in[13];

  const int B     = in_sizes[1];
  const int A_num = in_sizes[2] / B;
  const int S_num = in_sizes[6];
  const int A_den = in_sizes[8];
  const int S_den = in_sizes[12];
  const int T     = 500;                       // problem spec
  const int C     = in_sizes[0] / (B * T);

  const int den_cap    = A_den + 3 * S_den + 64;
  const int num_stride = A_num + 3 * S_num + 64;
  const int cap4       = den_cap + 32768;      // interleaved capacity (uint4 units)

  // workspace layout
  size_t off = 0;
  auto alloc = [&](size_t bytes, size_t align) -> size_t {
    off = (off + align - 1) / align * align;
    size_t r = off; off += bytes; return r;
  };
  size_t o_den_meta = alloc((size_t)den_cap * 8, 16);
  size_t o_den_ilv  = alloc((size_t)cap4 * 16, 16);
  size_t o_desc     = alloc((size_t)66 * 4, 4);
  size_t o_num_meta = alloc((size_t)B * num_stride * 8, 16);
  size_t o_den_rp   = alloc((size_t)2049 * 4, 4);
  size_t o_num_rp   = alloc((size_t)B * (S_num + 1) * 4, 4);
  size_t o_den_cnt  = alloc((size_t)S_den * 4, 4);
  size_t o_perm     = alloc((size_t)2048 * 4, 4);
  size_t o_inv      = alloc((size_t)S_den * 4, 4);
  size_t o_pc       = alloc((size_t)2048 * 4, 4);
  size_t o_num_pc   = alloc((size_t)B * S_num * 4, 4);
  size_t o_hist     = alloc((size_t)NCH * S_den * 4, 4);   // zeroed region start
  size_t o_num_cnt  = alloc((size_t)B * S_num * 4, 4);     // contiguous with hist
  size_t o_llh      = alloc((size_t)2 * B * 4, 4);
  const bool use_csr = (off <= ws_size) && (S_den >= 1) && (S_den <= 2048) &&
                       (S_num >= 1) && (S_num <= 2048) && (C <= MAX_C) && (C >= 1);

  char* wsb = (char*)d_ws;
  float* llh = (float*)(wsb + (use_csr ? o_llh : 0));

  if (use_csr) {
    uint2* den_meta = (uint2*)(wsb + o_den_meta);
    uint4* den_ilv  = (uint4*)(wsb + o_den_ilv);
    int*   desc     = (int*)(wsb + o_desc);
    uint2* num_meta = (uint2*)(wsb + o_num_meta);
    int*   den_rp   = (int*)(wsb + o_den_rp);
    int*   num_rp   = (int*)(wsb + o_num_rp);
    int*   den_cnt  = (int*)(wsb + o_den_cnt);
    int*   perm     = (int*)(wsb + o_perm);
    int*   inv      = (int*)(wsb + o_inv);
    int*   pc       = (int*)(wsb + o_pc);
    int*   num_pc   = (int*)(wsb + o_num_pc);
    int*   hist     = (int*)(wsb + o_hist);
    int*   num_cnt  = (int*)(wsb + o_num_cnt);

    const int chunk = (A_den + NCH - 1) / NCH;

    // zero hist + num_cnt (contiguous)
    int ztot = NCH * S_den + B * S_num;
    zero_kernel<<<(ztot + 255) / 256, 256, 0, stream>>>(hist, ztot);

    hist_chunk_kernel<<<NCH, 256, 0, stream>>>(den_dst, A_den, chunk, S_den, hist);
    hist_kernel<<<dim3((A_num + 255) / 256, B), 256, 0, stream>>>(num_dst, A_num, A_num,
                                                                  num_cnt, S_num);

    colsum_kernel<<<(S_den + 255) / 256, 256, 0, stream>>>(hist, NCH, S_den, den_cnt);
    rank_perm_kernel<<<1, 1024, 0, stream>>>(den_cnt, S_den, perm, inv);
    pc_kernel<<<8, 256, 0, stream>>>(den_cnt, perm, S_den, pc);
    scan_kernel<<<1, 1024, 0, stream>>>(pc, den_rp, 2048);
    wave_desc_kernel<<<1, 1024, 0, stream>>>(den_rp, cap4, desc);

    padcnt_kernel<<<(B * S_num + 255) / 256, 256, 0, stream>>>(num_cnt, B * S_num, num_pc);
    scan_kernel<<<B, 1024, 0, stream>>>(num_pc, num_rp, S_num);

    off_perm_kernel<<<(S_den + 255) / 256, 256, 0, stream>>>(hist, NCH, S_den, den_rp, perm);
    pad_den_kernel<<<(S_den + 255) / 256, 256, 0, stream>>>(den_rp, den_cnt, perm, S_den, den_meta);
    fill_chunk_kernel<<<dim3((S_den + 255) / 256, NCH), 256, 0, stream>>>(
        den_src, den_dst, den_pdf, den_w, A_den, chunk, S_den, hist, inv, den_meta);
    fill_kernel<<<dim3((S_num + 255) / 256, B), 256, 0, stream>>>(
        num_src, num_dst, num_pdf, num_w, A_num, A_num, num_rp, S_num, num_meta, num_stride);

    repack_sort_kernel<<<32, 64, 0, stream>>>(den_meta, den_rp, desc, C, (uint2*)den_ilv);

    fsa_forward_lin<<<2 * B, 1024, 0, stream>>>(
        ll, seqlen, den_meta, den_ilv, desc, den_rp, perm, S_den,
        num_meta, num_rp, num_stride, S_num,
        den_init, den_final, num_init, num_final, T, C, B, llh);
  } else {
    fsa_forward_fallback<<<2 * B, 1024, 0, stream>>>(
        ll, seqlen,
        den_src, den_dst, den_pdf, den_w, A_den, den_init, den_final, S_den,
        num_src, num_dst, num_pdf, num_w, A_num, num_init, num_final, S_num,
        T, C, B, llh);
  }

  final_loss_kernel<<<1, 64, 0, stream>>>(llh, B, (float*)d_out);
}

// Round 11
// 2908.154 us; speedup vs baseline: 1.3324x; 1.2485x over previous
//
#include <hip/hip_runtime.h>

#define NEG_INF_F (-1e30f)
#define MAX_S 2048
#define MAX_C 3008
#define NCH   128

// vbuf: 4 copies, float offsets 0/2056/4112/6168 (bank shifts 0/8/16/24)
#define VB_SIZE 8216
// elbuf: 2 copies per buffer (+3016 floats, bank shift 8), double-buffered
#define EL_COPY 3016
#define EL_BUF  6032
#define EL_SIZE 12064

// ============================ build helpers (deterministic) ============================

__global__ void zero_kernel(int* __restrict__ p, int n) {
  int i = blockIdx.x * blockDim.x + threadIdx.x;
  if (i < n) p[i] = 0;
}

__global__ void hist_kernel(const int* __restrict__ dst, int A, int A_stride,
                            int* __restrict__ cnt, int S) {
  int b = blockIdx.y;
  int i = blockIdx.x * blockDim.x + threadIdx.x;
  if (i < A) atomicAdd(&cnt[b * S + dst[(size_t)b * A_stride + i]], 1);
}

__global__ void hist_chunk_kernel(const int* __restrict__ dst, int A, int chunk, int S,
                                  int* __restrict__ hist) {
  int c = blockIdx.x;
  int i1 = min(A, (c + 1) * chunk);
  for (int i = c * chunk + threadIdx.x; i < i1; i += blockDim.x)
    atomicAdd(&hist[c * S + dst[i]], 1);
}

__global__ void colsum_kernel(const int* __restrict__ hist, int nch, int S,
                              int* __restrict__ cnt) {
  int s = blockIdx.x * blockDim.x + threadIdx.x;
  if (s < S) {
    int t = 0;
    for (int c = 0; c < nch; ++c) t += hist[c * S + s];
    cnt[s] = t;
  }
}

// Stable in-degree rank (desc) -> slot permutation pairing heavy with light.
__global__ __launch_bounds__(1024)
void rank_perm_kernel(const int* __restrict__ cnt, int S,
                      int* __restrict__ perm, int* __restrict__ invperm) {
  __shared__ int c[2048];
  __shared__ int R[2048];
  const int tid = threadIdx.x;
  for (int i = tid; i < 2048; i += 1024) c[i] = (i < S) ? cnt[i] : -1;
  __syncthreads();
  for (int u = 0; u < 2; ++u) {
    int s = tid + u * 1024;
    if (s < S) {
      int cs = c[s], r = 0;
      for (int j = 0; j < S; ++j) {
        int cj = c[j];
        r += (cj > cs) || (cj == cs && j < s);
      }
      R[r] = s;
    }
  }
  __syncthreads();
  for (int u = 0; u < 2; ++u) {
    int slot = tid + u * 1024;
    if (slot < S) {
      int state = (slot < 1024) ? R[slot] : R[S - 1 - (slot - 1024)];
      perm[slot] = state;
      invperm[state] = slot;
    }
  }
}

__global__ void pc_kernel(const int* __restrict__ cnt, const int* __restrict__ perm,
                          int S, int* __restrict__ pc) {
  int slot = blockIdx.x * blockDim.x + threadIdx.x;
  if (slot < 2048) pc[slot] = (slot < S) ? ((cnt[perm[slot]] + 3) & ~3) : 0;
}

__global__ void padcnt_kernel(const int* __restrict__ cnt, int n, int* __restrict__ out) {
  int i = blockIdx.x * blockDim.x + threadIdx.x;
  if (i < n) out[i] = (cnt[i] + 3) & ~3;
}

__global__ __launch_bounds__(1024) void scan_kernel(const int* __restrict__ cnt,
                                                    int* __restrict__ rp, int S) {
  __shared__ int buf[2][2048];
  const int tid = threadIdx.x;
  const int b = blockIdx.x;
  const int* c = cnt + (size_t)b * S;
  int* r = rp + (size_t)b * (S + 1);
  for (int u = 0; u < 2; ++u) {
    int i = tid + u * 1024;
    buf[0][i] = (i < S) ? c[i] : 0;
  }
  __syncthreads();
  int cur = 0;
  for (int off = 1; off < 2048; off <<= 1) {
    for (int u = 0; u < 2; ++u) {
      int i = tid + u * 1024;
      buf[cur ^ 1][i] = buf[cur][i] + ((i >= off) ? buf[cur][i - off] : 0);
    }
    __syncthreads();
    cur ^= 1;
  }
  for (int u = 0; u < 2; ++u) {
    int i = tid + u * 1024;
    if (i <= S) r[i] = (i == 0) ? 0 : buf[cur][i - 1];
  }
  if (tid == 0) r[S] = buf[cur][S - 1];
}

__global__ void off_perm_kernel(int* __restrict__ hist, int nch, int S,
                                const int* __restrict__ rp, const int* __restrict__ perm) {
  int slot = blockIdx.x * blockDim.x + threadIdx.x;
  if (slot < S) {
    int state = perm[slot];
    int run = rp[slot];
    for (int c = 0; c < nch; ++c) {
      int h = hist[c * S + state];
      hist[c * S + state] = run;
      run += h;
    }
  }
}

// fill pad arcs at row tails (den): y==0 marks pad (ew = 0)
__global__ void pad_den_kernel(const int* __restrict__ rp, const int* __restrict__ cnt,
                               const int* __restrict__ perm, int S, uint2* __restrict__ meta) {
  int slot = blockIdx.x * blockDim.x + threadIdx.x;
  if (slot < S) {
    int p = rp[slot] + cnt[perm[slot]];
    int e = rp[slot + 1];
    uint2 pad = make_uint2(0u, 0u);
    for (; p < e; ++p) meta[p] = pad;
  }
}

// DEN meta: x = (src_slot*4) | ((pdf*4)<<16)  (pre-scaled LDS byte offsets), y = exp(w).
__global__ void fill_chunk_kernel(const int* __restrict__ src, const int* __restrict__ dst,
                                  const int* __restrict__ pdf, const float* __restrict__ w,
                                  int A, int chunk, int S, int* __restrict__ hoff,
                                  const int* __restrict__ inv, uint2* __restrict__ meta) {
  int c = blockIdx.y;
  int s = blockIdx.x * blockDim.x + threadIdx.x;
  if (s >= S) return;
  int i1 = min(A, (c + 1) * chunk);
  int p = hoff[c * S + s];
  for (int i = c * chunk; i < i1; ++i) {
    if (dst[i] == s) {
      meta[p++] = make_uint2((unsigned)(inv[src[i]] * 4) | ((unsigned)(pdf[i] * 4) << 16),
                             __float_as_uint(__expf(w[i])));
    }
  }
}

// numerator meta keeps index packing (src | pdf<<16) + raw w
__global__ void fill_kernel(const int* __restrict__ src, const int* __restrict__ dst,
                            const int* __restrict__ pdf, const float* __restrict__ w,
                            int A, int A_stride, const int* __restrict__ rp, int S,
                            uint2* __restrict__ meta, int meta_stride) {
  int b = blockIdx.y;
  int s = blockIdx.x * blockDim.x + threadIdx.x;
  if (s >= S) return;
  const int*   sb = src + (size_t)b * A_stride;
  const int*   db = dst + (size_t)b * A_stride;
  const int*   pb = pdf + (size_t)b * A_stride;
  const float* wb = w   + (size_t)b * A_stride;
  const int*   rpb = rp + (size_t)b * (S + 1);
  uint2* mb = meta + (size_t)b * meta_stride;
  int p = rpb[s];
  for (int i = 0; i < A; ++i) {
    if (db[i] == s) {
      mb[p++] = make_uint2((unsigned)sb[i] | ((unsigned)pb[i] << 16), __float_as_uint(wb[i]));
    }
  }
  uint2 pad = make_uint2(0u, __float_as_uint(NEG_INF_F));
  int e = rpb[s + 1];
  for (; p < e; ++p) mb[p] = pad;
}

// ---- wave-interleaved den meta: desc = offA[16],offB[16],wmaxA[16],wmaxB[16],ok,total ----
__global__ __launch_bounds__(1024)
void wave_desc_kernel(const int* __restrict__ rp, int cap4, int* __restrict__ desc) {
  __shared__ int wm[32];
  const int tid = threadIdx.x;
  const int w = tid >> 6;
  int cA = (rp[tid + 1] - rp[tid]) >> 2;
  int sB = 2047 - tid;
  int cB = (rp[sB + 1] - rp[sB]) >> 2;
  for (int off = 32; off; off >>= 1) {
    cA = max(cA, __shfl_down(cA, off));
    cB = max(cB, __shfl_down(cB, off));
  }
  if ((tid & 63) == 0) { wm[w] = cA; wm[16 + w] = cB; }
  __syncthreads();
  if (tid == 0) {
    int off = 0;
    for (int i = 0; i < 16; ++i) { desc[i] = off; off += wm[i] * 128; }
    for (int i = 0; i < 16; ++i) { desc[16 + i] = off; off += wm[16 + i] * 128; }
    for (int i = 0; i < 16; ++i) { desc[32 + i] = wm[i]; desc[48 + i] = wm[16 + i]; }
    desc[64] = (off <= cap4) ? 1 : 0;
    desc[65] = off;
  }
}

// Simple order-preserving interleave copy (fast). grid 32 blocks x 64 lanes.
__global__ void repack_kernel(const uint2* __restrict__ meta, const int* __restrict__ rp,
                              const int* __restrict__ desc, uint2* __restrict__ ilv) {
  if (!desc[64]) return;
  const int w = blockIdx.x & 15;
  const bool isB = blockIdx.x >= 16;
  const int l = threadIdx.x;
  const int tid = w * 64 + l;
  const int s = isB ? (2047 - tid) : tid;
  const int base4 = desc[(isB ? 16 : 0) + w];
  const int wmax  = desc[(isB ? 48 : 32) + w];
  const int r0 = rp[s];
  const int n = (rp[s + 1] - r0) >> 2;
  for (int c = 0; c < wmax; ++c) {
    for (int part = 0; part < 2; ++part) {
      int u4 = base4 + c * 128 + part * 64 + l;
      uint2 v0 = make_uint2(0u, 0u), v1 = make_uint2(0u, 0u);
      if (c < n) {
        v0 = meta[r0 + 4 * c + 2 * part];
        v1 = meta[r0 + 4 * c + 2 * part + 1];
      }
      ilv[2 * u4]     = v0;
      ilv[2 * u4 + 1] = v1;
    }
  }
}

// Replica-choice balancing: per gather-instruction position, sequentially (with
// feedback) pick which of 4 vbuf copies (bank shifts 0/8/16/24) and 2 elbuf
// copies (shift 0/8) each of the 64 rows' arcs reads, minimizing per-bank load.
// Positions are independent -> one lane per position, tables in registers.
// Copies hold identical values -> numerics unchanged.
__global__ __launch_bounds__(64)
void choice_kernel(uint2* __restrict__ ilv, const int* __restrict__ desc) {
  if (!desc[64]) return;
  const int w = blockIdx.x & 15;
  const bool isB = blockIdx.x >= 16;
  const int base4 = desc[(isB ? 16 : 0) + w];
  const int wmax  = desc[(isB ? 48 : 32) + w];
  const int P = wmax * 4;
  for (int p = threadIdx.x; p < P; p += 64) {
    const int pbase = 2 * (base4 + (p >> 2) * 128 + (((p >> 1) & 1) * 64)) + (p & 1);
    unsigned long long cs[4]  = {0, 0, 0, 0};   // 32 x 8-bit src-bank counts
    unsigned long long cp2[4] = {0, 0, 0, 0};   // 32 x 8-bit pdf-bank counts
    for (int r = 0; r < 64; ++r) {
      const int idx = pbase + 2 * r;
      uint2 a = ilv[idx];
      unsigned srcoff = a.x & 0xFFFFu;
      unsigned pdfoff = a.x >> 16;
      // src: 4 choices, bank shifts {0,8,16,24}
      const int b0 = (int)((srcoff >> 2) & 31u);
      int bestk = 0, bestc = 256;
#pragma unroll
      for (int k = 0; k < 4; ++k) {
        int bb = (b0 + 8 * k) & 31;
        int c = (int)((cs[bb >> 3] >> ((bb & 7) * 8)) & 0xFFull);
        if (c < bestc) { bestc = c; bestk = k; }
      }
      const int bs = (b0 + 8 * bestk) & 31;
      cs[bs >> 3] += (1ULL << ((bs & 7) * 8));
      // pdf: 2 choices, bank shifts {0,8}
      const int q0 = (int)((pdfoff >> 2) & 31u);
      const int q1 = (q0 + 8) & 31;
      const int c0 = (int)((cp2[q0 >> 3] >> ((q0 & 7) * 8)) & 0xFFull);
      const int c1 = (int)((cp2[q1 >> 3] >> ((q1 & 7) * 8)) & 0xFFull);
      const int bj = (c1 < c0) ? 1 : 0;
      const int qb = bj ? q1 : q0;
      cp2[qb >> 3] += (1ULL << ((qb & 7) * 8));
      a.x = (srcoff + (unsigned)bestk * 8224u) | ((pdfoff + (unsigned)bj * 12064u) << 16);
      ilv[idx] = a;
    }
  }
}

// ============================ exact row LSE (numerator path) ============================

__device__ __forceinline__ float row_lse(const uint2* __restrict__ meta, int k, int e,
                                         const float* __restrict__ alpha,
                                         const float* __restrict__ lcur) {
  float mm0 = NEG_INF_F, ss0 = 0.0f, mm1 = NEG_INF_F, ss1 = 0.0f;
  const int n4 = (e - k) >> 2;
  const uint4* p = (const uint4*)(meta + k);
  if (n4 > 0) {
    uint4 A = p[0], Bv = p[1];
    float t0 = alpha[A.x & 0xFFFFu] + __uint_as_float(A.y) + lcur[A.x >> 16];
    float t1 = alpha[A.z & 0xFFFFu] + __uint_as_float(A.w) + lcur[A.z >> 16];
    float t2 = alpha[Bv.x & 0xFFFFu] + __uint_as_float(Bv.y) + lcur[Bv.x >> 16];
    float t3 = alpha[Bv.z & 0xFFFFu] + __uint_as_float(Bv.w) + lcur[Bv.z >> 16];
    for (int c2 = 1; c2 < n4; ++c2) {
      uint4 A2 = p[2 * c2], B2 = p[2 * c2 + 1];
      float u0 = alpha[A2.x & 0xFFFFu] + __uint_as_float(A2.y) + lcur[A2.x >> 16];
      float u1 = alpha[A2.z & 0xFFFFu] + __uint_as_float(A2.w) + lcur[A2.z >> 16];
      float u2 = alpha[B2.x & 0xFFFFu] + __uint_as_float(B2.y) + lcur[B2.x >> 16];
      float u3 = alpha[B2.z & 0xFFFFu] + __uint_as_float(B2.w) + lcur[B2.z >> 16];
      float mc = fmaxf(fmaxf(t0, t1), fmaxf(t2, t3));
      if ((c2 & 1) != 0) {
        float nm = fmaxf(mm0, mc);
        ss0 = ss0 * __expf(mm0 - nm) +
              ((__expf(t0 - nm) + __expf(t1 - nm)) + (__expf(t2 - nm) + __expf(t3 - nm)));
        mm0 = nm;
      } else {
        float nm = fmaxf(mm1, mc);
        ss1 = ss1 * __expf(mm1 - nm) +
              ((__expf(t0 - nm) + __expf(t1 - nm)) + (__expf(t2 - nm) + __expf(t3 - nm)));
        mm1 = nm;
      }
      t0 = u0; t1 = u1; t2 = u2; t3 = u3;
    }
    float mc = fmaxf(fmaxf(t0, t1), fmaxf(t2, t3));
    if ((n4 & 1) != 0) {
      float nm = fmaxf(mm0, mc);
      ss0 = ss0 * __expf(mm0 - nm) +
            ((__expf(t0 - nm) + __expf(t1 - nm)) + (__expf(t2 - nm) + __expf(t3 - nm)));
      mm0 = nm;
    } else {
      float nm = fmaxf(mm1, mc);
      ss1 = ss1 * __expf(mm1 - nm) +
            ((__expf(t0 - nm) + __expf(t1 - nm)) + (__expf(t2 - nm) + __expf(t3 - nm)));
      mm1 = nm;
    }
  }
  float nm = fmaxf(mm0, mm1);
  float ssc = ss0 * __expf(mm0 - nm) + ss1 * __expf(mm1 - nm);
  return (ssc > 0.0f) ? (__logf(ssc) + nm) : NEG_INF_F;
}

__device__ __forceinline__ void stage_row(const float* __restrict__ row,
                                          float* __restrict__ lds, int C, int tid, int nt) {
  if (((C & 3) == 0) && ((((uintptr_t)row) & 15) == 0)) {
    const float4* r4 = (const float4*)row;
    const int n = C >> 2;
    for (int i = tid; i < n; i += nt) ((float4*)lds)[i] = r4[i];
  } else {
    for (int i = tid; i < C; i += nt) lds[i] = row[i];
  }
}

// LDS read with pre-scaled byte offset
__device__ __forceinline__ float ldsF(const float* base, unsigned boff) {
  return *(const float*)((const char*)base + boff);
}

#define ACC4(X, Y, s0, s1, s2, s3)                                                         \
  s0 = fmaf(__uint_as_float((X).y), ldsF(vbuf, (X).x & 0xFFFFu) * ldsF(el, (X).x >> 16), s0); \
  s1 = fmaf(__uint_as_float((X).w), ldsF(vbuf, (X).z & 0xFFFFu) * ldsF(el, (X).z >> 16), s1); \
  s2 = fmaf(__uint_as_float((Y).y), ldsF(vbuf, (Y).x & 0xFFFFu) * ldsF(el, (Y).x >> 16), s2); \
  s3 = fmaf(__uint_as_float((Y).w), ldsF(vbuf, (Y).z & 0xFFFFu) * ldsF(el, (Y).z >> 16), s3);

// ============================ forward: den linear-space (replica-choice), num exact-LSE ============================
__global__ __launch_bounds__(1024, 1)
void fsa_forward_lin(const float* __restrict__ ll, const int* __restrict__ seqlen,
                     const uint2* __restrict__ den_meta, const uint4* __restrict__ den_ilv,
                     const int* __restrict__ den_desc,
                     const int* __restrict__ den_rp, const int* __restrict__ den_perm, int S_den,
                     const uint2* __restrict__ num_meta, const int* __restrict__ num_rp,
                     int num_stride, int S_num,
                     const float* __restrict__ den_init, const float* __restrict__ den_final,
                     const float* __restrict__ num_init, const float* __restrict__ num_final,
                     int T, int C, int B, float* __restrict__ out_llh)
{
  __shared__ float alpha[MAX_S];
  __shared__ float vbuf[VB_SIZE];      // 4 copies (bank shifts 0/8/16/24)
  __shared__ float elbuf[EL_SIZE];     // den: exp(ll), 2 copies x 2 buffers; num: raw ll
  __shared__ float red[16];
  __shared__ int   sdesc[66];

  const int tid = threadIdx.x;
  const int nt  = 1024;
  const bool is_den = ((int)blockIdx.x) < B;
  const int b = is_den ? (int)blockIdx.x : ((int)blockIdx.x - B);
  const int S = is_den ? S_den : S_num;
  const float* fin  = is_den ? den_final : num_final;
  const int*   perm = is_den ? den_perm  : nullptr;

  const int L = seqlen[b];
  const float* llb = ll + ((size_t)b * T) * C;

  if (is_den) {
    // ---- linear-space denominator, 2 barriers/step ----
    for (int i = tid; i < 66; i += nt) sdesc[i] = den_desc[i];

    const int w = tid >> 6, l = tid & 63;
    const int slotA = tid;            // heavy ranks
    const int slotB = 2047 - tid;     // paired light ranks
    const int rA0 = den_rp[slotA], rA1 = den_rp[slotA + 1];
    const int rB0 = den_rp[slotB], rB1 = den_rp[slotB + 1];
    float a0 = (slotA < S) ? den_init[den_perm[slotA]] : NEG_INF_F;
    float a1 = (slotB < S) ? den_init[den_perm[slotB]] : NEG_INF_F;

    const int nvec = C >> 2;
    const bool pf = ((C & 3) == 0) && ((((uintptr_t)llb) & 15) == 0) &&
                    (nvec <= nt) && (C <= MAX_C);

    // initial M reduce + EL stage for row 0 (buffer 0, both copies)
    float lm = fmaxf(a0, a1);
    for (int off = 32; off; off >>= 1) lm = fmaxf(lm, __shfl_down(lm, off));
    if ((tid & 63) == 0) red[tid >> 6] = lm;
    if (L > 0) {
      if (pf) {
        if (tid < nvec) {
          float4 r = ((const float4*)llb)[tid];
          float4 e = make_float4(__expf(r.x), __expf(r.y), __expf(r.z), __expf(r.w));
          ((float4*)elbuf)[tid] = e;
          ((float4*)(elbuf + EL_COPY))[tid] = e;
        }
      } else {
        for (int i = tid; i < C; i += nt) {
          float e = __expf(llb[i]);
          elbuf[i] = e;
          elbuf[i + EL_COPY] = e;
        }
      }
    }
    __syncthreads();
    float M = red[0];
#pragma unroll
    for (int i = 1; i < 16; ++i) M = fmaxf(M, red[i]);

    const bool ilv_ok = sdesc[64] != 0;
    const uint4* pA4 = den_ilv + sdesc[w] + l;
    const uint4* pB4 = den_ilv + sdesc[16 + w] + l;
    const int nA = sdesc[32 + w], nB = sdesc[48 + w];

    int cur = 0;
    for (int t = 0; t < L; ++t) {
      {
        float va = __expf(a0 - M), vb = __expf(a1 - M);
        vbuf[slotA] = va; vbuf[slotA + 2056] = va;
        vbuf[slotA + 4112] = va; vbuf[slotA + 6168] = va;
        vbuf[slotB] = vb; vbuf[slotB + 2056] = vb;
        vbuf[slotB + 4112] = vb; vbuf[slotB + 6168] = vb;
      }
      __syncthreads();                       // B1: vbuf + elbuf[cur] ready

      const float* el = elbuf + (cur ? EL_BUF : 0);

      float4 nx;
      const bool donx = pf && (t + 1 < L) && (tid < nvec);
      if (donx) nx = ((const float4*)(llb + (size_t)(t + 1) * C))[tid];

      float sA0 = 0, sA1 = 0, sA2 = 0, sA3 = 0;
      float sB0 = 0, sB1 = 0, sB2 = 0, sB3 = 0;
      if (ilv_ok) {
        if (nA > 0) {
          uint4 X0 = pA4[0], Y0 = pA4[64];
          if (nA > 1) {
            uint4 X1 = pA4[128], Y1 = pA4[192];
            for (int c = 2; c < nA; ++c) {
              uint4 X2 = pA4[c * 128], Y2 = pA4[c * 128 + 64];
              ACC4(X0, Y0, sA0, sA1, sA2, sA3);
              X0 = X1; Y0 = Y1; X1 = X2; Y1 = Y2;
            }
            ACC4(X0, Y0, sA0, sA1, sA2, sA3);
            X0 = X1; Y0 = Y1;
          }
          ACC4(X0, Y0, sA0, sA1, sA2, sA3);
        }
        if (nB > 0) {
          uint4 X0 = pB4[0], Y0 = pB4[64];
          for (int c = 1; c < nB; ++c) {
            uint4 X1 = pB4[c * 128], Y1 = pB4[c * 128 + 64];
            ACC4(X0, Y0, sB0, sB1, sB2, sB3);
            X0 = X1; Y0 = Y1;
          }
          ACC4(X0, Y0, sB0, sB1, sB2, sB3);
        }
      } else {
        const uint4* pA = (const uint4*)(den_meta + rA0);
        const uint4* pB = (const uint4*)(den_meta + rB0);
        const int nAr = (rA1 - rA0) >> 2, nBr = (rB1 - rB0) >> 2;
        const int n = nAr > nBr ? nAr : nBr;
        for (int c = 0; c < n; ++c) {
          if (c < nAr) {
            uint4 X = pA[2 * c], Y = pA[2 * c + 1];
            ACC4(X, Y, sA0, sA1, sA2, sA3);
          }
          if (c < nBr) {
            uint4 X = pB[2 * c], Y = pB[2 * c + 1];
            ACC4(X, Y, sB0, sB1, sB2, sB3);
          }
        }
      }
      float sA = (sA0 + sA1) + (sA2 + sA3);
      float sB = (sB0 + sB1) + (sB2 + sB3);

      a0 = (sA > 0.0f) ? (__logf(sA) + M) : NEG_INF_F;
      a1 = (sB > 0.0f) ? (__logf(sB) + M) : NEG_INF_F;

      float* eln = elbuf + (cur ? 0 : EL_BUF);
      if (donx) {
        float4 e = make_float4(__expf(nx.x), __expf(nx.y), __expf(nx.z), __expf(nx.w));
        ((float4*)eln)[tid] = e;
        ((float4*)(eln + EL_COPY))[tid] = e;
      } else if (!pf && t + 1 < L) {
        const float* nr = llb + (size_t)(t + 1) * C;
        for (int i = tid; i < C; i += nt) {
          float e = __expf(nr[i]);
          eln[i] = e;
          eln[i + EL_COPY] = e;
        }
      }

      float lm2 = fmaxf(a0, a1);
      for (int off = 32; off; off >>= 1) lm2 = fmaxf(lm2, __shfl_down(lm2, off));
      if ((tid & 63) == 0) red[tid >> 6] = lm2;
      __syncthreads();                       // B2: sums done, red + elbuf[nxt] visible
      M = red[0];
#pragma unroll
      for (int i = 1; i < 16; ++i) M = fmaxf(M, red[i]);
      cur ^= 1;
    }
    alpha[slotA] = a0;
    alpha[slotB] = a1;
    __syncthreads();
  } else {
    // ---- exact-LSE numerator (tiny) ----
    const uint2* meta = num_meta + (size_t)b * num_stride;
    const int*   rp   = num_rp + (size_t)b * (S_num + 1);
    for (int s = tid; s < MAX_S; s += nt) alpha[s] = (s < S) ? num_init[s] : NEG_INF_F;
    int rs[2] = {0, 0}, re[2] = {0, 0};
    for (int u = 0; u < 2; ++u) {
      int s = tid + u * nt;
      if (s < S) { rs[u] = rp[s]; re[u] = rp[s + 1]; }
    }
    __syncthreads();
    for (int t = 0; t < L; ++t) {
      stage_row(llb + (size_t)t * C, elbuf, C, tid, nt);
      __syncthreads();
      float nv[2];
      for (int u = 0; u < 2; ++u) {
        int s = tid + u * nt;
        nv[u] = (s < S) ? row_lse(meta, rs[u], re[u], alpha, elbuf) : NEG_INF_F;
      }
      __syncthreads();
      for (int u = 0; u < 2; ++u) {
        int s = tid + u * nt;
        if (s < S) alpha[s] = nv[u];
      }
      __syncthreads();
    }
  }

  // final logsumexp(alpha + final_logp)
  float lm = -3.0e38f;
  for (int s = tid; s < S; s += nt) lm = fmaxf(lm, alpha[s] + fin[perm ? perm[s] : s]);
  for (int off = 32; off; off >>= 1) lm = fmaxf(lm, __shfl_down(lm, off));
  if ((tid & 63) == 0) red[tid >> 6] = lm;
  __syncthreads();
  if (tid < 64) {
    float v = (tid < 16) ? red[tid] : -3.0e38f;
    for (int off = 32; off; off >>= 1) v = fmaxf(v, __shfl_down(v, off));
    if (tid == 0) red[0] = v;
  }
  __syncthreads();
  const float M = red[0];

  float ls = 0.0f;
  for (int s = tid; s < S; s += nt) ls += __expf(alpha[s] + fin[perm ? perm[s] : s] - M);
  for (int off = 32; off; off >>= 1) ls += __shfl_down(ls, off);
  __syncthreads();
  if ((tid & 63) == 0) red[tid >> 6] = ls;
  __syncthreads();
  if (tid < 64) {
    float v = (tid < 16) ? red[tid] : 0.0f;
    for (int off = 32; off; off >>= 1) v += __shfl_down(v, off);
    if (tid == 0) out_llh[(is_den ? 0 : B) + b] = __logf(v) + M;
  }
}

// ============================ fallback (atomic path, tiny ws) ============================

__device__ __forceinline__ unsigned enc_f(float x) {
  unsigned u = __float_as_uint(x);
  return u ^ (unsigned)(((int)u >> 31) | 0x80000000);
}
__device__ __forceinline__ float dec_f(unsigned e) {
  unsigned mask = ((int)e >= 0) ? 0xFFFFFFFFu : 0x80000000u;
  return __uint_as_float(e ^ mask);
}

__global__ __launch_bounds__(1024)
void fsa_forward_fallback(
    const float* __restrict__ ll, const int* __restrict__ seqlen,
    const int* __restrict__ den_src, const int* __restrict__ den_dst,
    const int* __restrict__ den_pdf, const float* __restrict__ den_w,
    int A_den, const float* __restrict__ den_init, const float* __restrict__ den_final, int S_den,
    const int* __restrict__ num_src, const int* __restrict__ num_dst,
    const int* __restrict__ num_pdf, const float* __restrict__ num_w,
    int A_num, const float* __restrict__ num_init, const float* __restrict__ num_final, int S_num,
    int T, int C, int B, float* __restrict__ out_llh)
{
  __shared__ float    alpha[MAX_S];
  __shared__ unsigned menc[MAX_S];
  __shared__ float    msafe[MAX_S];
  __shared__ float    ssum[MAX_S];
  __shared__ float    llrow[MAX_C];

  const int tid = threadIdx.x;
  const int nt  = blockDim.x;
  const bool is_den = ((int)blockIdx.x) < B;
  const int b = is_den ? (int)blockIdx.x : ((int)blockIdx.x - B);
  const int S = is_den ? S_den : S_num;
  const int A = is_den ? A_den : A_num;
  const float* init = is_den ? den_init  : num_init;
  const float* fin  = is_den ? den_final : num_final;
  const int*   asrc = is_den ? den_src  : (num_src + (size_t)b * A_num);
  const int*   adst = is_den ? den_dst  : (num_dst + (size_t)b * A_num);
  const int*   apdf = is_den ? den_pdf  : (num_pdf + (size_t)b * A_num);
  const float* aw   = is_den ? den_w    : (num_w   + (size_t)b * A_num);

  for (int s = tid; s < S; s += nt) { alpha[s] = init[s]; menc[s] = 0u; ssum[s] = 0.0f; }
  __syncthreads();

  const int L = seqlen[b];
  const float* llb = ll + ((size_t)b * T) * C;

  for (int t = 0; t < L; ++t) {
    const float* row = llb + (size_t)t * C;
    for (int i = tid; i < C; i += nt) llrow[i] = row[i];
    __syncthreads();
    for (int i = tid; i < A; i += nt) {
      float score = alpha[asrc[i]] + aw[i] + llrow[apdf[i]];
      atomicMax(&menc[adst[i]], enc_f(score));
    }
    __syncthreads();
    for (int s = tid; s < S; s += nt) {
      float m = dec_f(menc[s]);
      msafe[s] = (m > -5e29f) ? m : 0.0f;
    }
    __syncthreads();
    for (int i = tid; i < A; i += nt) {
      int d = adst[i];
      float score = alpha[asrc[i]] + aw[i] + llrow[apdf[i]];
      atomicAdd(&ssum[d], __expf(score - msafe[d]));
    }
    __syncthreads();
    for (int s = tid; s < S; s += nt) {
      float sum = ssum[s];
      alpha[s] = (sum > 0.0f) ? (__logf(sum) + msafe[s]) : NEG_INF_F;
      menc[s] = 0u; ssum[s] = 0.0f;
    }
    __syncthreads();
  }

  float lm = -3.0e38f;
  for (int s = tid; s < S; s += nt) lm = fmaxf(lm, alpha[s] + fin[s]);
  for (int off = 32; off; off >>= 1) lm = fmaxf(lm, __shfl_down(lm, off));
  const int nwaves = nt >> 6;
  if ((tid & 63) == 0) msafe[tid >> 6] = lm;
  __syncthreads();
  if (tid < 64) {
    float v = (tid < nwaves) ? msafe[tid] : -3.0e38f;
    for (int off = 32; off; off >>= 1) v = fmaxf(v, __shfl_down(v, off));
    if (tid == 0) msafe[MAX_S - 1] = v;
  }
  __syncthreads();
  const float M = msafe[MAX_S - 1];
  float ls = 0.0f;
  for (int s = tid; s < S; s += nt) ls += __expf(alpha[s] + fin[s] - M);
  for (int off = 32; off; off >>= 1) ls += __shfl_down(ls, off);
  if ((tid & 63) == 0) ssum[tid >> 6] = ls;
  __syncthreads();
  if (tid < 64) {
    float v = (tid < nwaves) ? ssum[tid] : 0.0f;
    for (int off = 32; off; off >>= 1) v += __shfl_down(v, off);
    if (tid == 0) out_llh[(is_den ? 0 : B) + b] = __logf(v) + M;
  }
}

// loss = sum_b (den_llh[b] - num_llh[b])
__global__ void final_loss_kernel(const float* __restrict__ llh, int B, float* __restrict__ out) {
  int lane = threadIdx.x;
  float v = (lane < B) ? (llh[lane] - llh[B + lane]) : 0.0f;
  for (int off = 32; off; off >>= 1) v += __shfl_down(v, off);
  if (lane == 0) out[0] = v;
}

extern "C" void kernel_launch(void* const* d_in, const int* in_sizes, int n_in,
                              void* d_out, int out_size, void* d_ws, size_t ws_size,
                              hipStream_t stream) {
  const float* ll        = (const float*)d_in[0];
  const int*   seqlen    = (const int*)  d_in[1];
  const int*   num_src   = (const int*)  d_in[2];
  const int*   num_dst   = (const int*)  d_in[3];
  const int*   num_pdf   = (const int*)  d_in[4];
  const float* num_w     = (const float*)d_in[5];
  const float* num_init  = (const float*)d_in[6];
  const float* num_final = (const float*)d_in[7];
  const int*   den_src   = (const int*)  d_in[8];
  const int*   den_dst   = (const int*)  d_in[9];
  const int*   den_pdf   = (const int*)  d_in[10];
  const float* den_w     = (const float*)d_in[11];
  const float* den_init  = (const float*)d_in[12];
  const float* den_final = (const float*)d_in[13];

  const int B     = in_sizes[1];
  const int A_num = in_sizes[2] / B;
  const int S_num = in_sizes[6];
  const int A_den = in_sizes[8];
  const int S_den = in_sizes[12];
  const int T     = 500;                       // problem spec
  const int C     = in_sizes[0] / (B * T);

  const int den_cap    = A_den + 3 * S_den + 64;
  const int num_stride = A_num + 3 * S_num + 64;
  const int cap4       = den_cap + 32768;      // interleaved capacity (uint4 units)

  // workspace layout
  size_t off = 0;
  auto alloc = [&](size_t bytes, size_t align) -> size_t {
    off = (off + align - 1) / align * align;
    size_t r = off; off += bytes; return r;
  };
  size_t o_den_meta = alloc((size_t)den_cap * 8, 16);
  size_t o_den_ilv  = alloc((size_t)cap4 * 16, 16);
  size_t o_desc     = alloc((size_t)66 * 4, 4);
  size_t o_num_meta = alloc((size_t)B * num_stride * 8, 16);
  size_t o_den_rp   = alloc((size_t)2049 * 4, 4);
  size_t o_num_rp   = alloc((size_t)B * (S_num + 1) * 4, 4);
  size_t o_den_cnt  = alloc((size_t)S_den * 4, 4);
  size_t o_perm     = alloc((size_t)2048 * 4, 4);
  size_t o_inv      = alloc((size_t)S_den * 4, 4);
  size_t o_pc       = alloc((size_t)2048 * 4, 4);
  size_t o_num_pc   = alloc((size_t)B * S_num * 4, 4);
  size_t o_hist     = alloc((size_t)NCH * S_den * 4, 4);   // zeroed region start
  size_t o_num_cnt  = alloc((size_t)B * S_num * 4, 4);     // contiguous with hist
  size_t o_llh      = alloc((size_t)2 * B * 4, 4);
  const bool use_csr = (off <= ws_size) && (S_den >= 1) && (S_den <= 2048) &&
                       (S_num >= 1) && (S_num <= 2048) && (C <= MAX_C) && (C >= 1);

  char* wsb = (char*)d_ws;
  float* llh = (float*)(wsb + (use_csr ? o_llh : 0));

  if (use_csr) {
    uint2* den_meta = (uint2*)(wsb + o_den_meta);
    uint4* den_ilv  = (uint4*)(wsb + o_den_ilv);
    int*   desc     = (int*)(wsb + o_desc);
    uint2* num_meta = (uint2*)(wsb + o_num_meta);
    int*   den_rp   = (int*)(wsb + o_den_rp);
    int*   num_rp   = (int*)(wsb + o_num_rp);
    int*   den_cnt  = (int*)(wsb + o_den_cnt);
    int*   perm     = (int*)(wsb + o_perm);
    int*   inv      = (int*)(wsb + o_inv);
    int*   pc       = (int*)(wsb + o_pc);
    int*   num_pc   = (int*)(wsb + o_num_pc);
    int*   hist     = (int*)(wsb + o_hist);
    int*   num_cnt  = (int*)(wsb + o_num_cnt);

    const int chunk = (A_den + NCH - 1) / NCH;

    // zero hist + num_cnt (contiguous)
    int ztot = NCH * S_den + B * S_num;
    zero_kernel<<<(ztot + 255) / 256, 256, 0, stream>>>(hist, ztot);

    hist_chunk_kernel<<<NCH, 256, 0, stream>>>(den_dst, A_den, chunk, S_den, hist);
    hist_kernel<<<dim3((A_num + 255) / 256, B), 256, 0, stream>>>(num_dst, A_num, A_num,
                                                                  num_cnt, S_num);

    colsum_kernel<<<(S_den + 255) / 256, 256, 0, stream>>>(hist, NCH, S_den, den_cnt);
    rank_perm_kernel<<<1, 1024, 0, stream>>>(den_cnt, S_den, perm, inv);
    pc_kernel<<<8, 256, 0, stream>>>(den_cnt, perm, S_den, pc);
    scan_kernel<<<1, 1024, 0, stream>>>(pc, den_rp, 2048);
    wave_desc_kernel<<<1, 1024, 0, stream>>>(den_rp, cap4, desc);

    padcnt_kernel<<<(B * S_num + 255) / 256, 256, 0, stream>>>(num_cnt, B * S_num, num_pc);
    scan_kernel<<<B, 1024, 0, stream>>>(num_pc, num_rp, S_num);

    off_perm_kernel<<<(S_den + 255) / 256, 256, 0, stream>>>(hist, NCH, S_den, den_rp, perm);
    pad_den_kernel<<<(S_den + 255) / 256, 256, 0, stream>>>(den_rp, den_cnt, perm, S_den, den_meta);
    fill_chunk_kernel<<<dim3((S_den + 255) / 256, NCH), 256, 0, stream>>>(
        den_src, den_dst, den_pdf, den_w, A_den, chunk, S_den, hist, inv, den_meta);
    fill_kernel<<<dim3((S_num + 255) / 256, B), 256, 0, stream>>>(
        num_src, num_dst, num_pdf, num_w, A_num, A_num, num_rp, S_num, num_meta, num_stride);

    repack_kernel<<<32, 64, 0, stream>>>(den_meta, den_rp, desc, (uint2*)den_ilv);
    choice_kernel<<<32, 64, 0, stream>>>((uint2*)den_ilv, desc);

    fsa_forward_lin<<<2 * B, 1024, 0, stream>>>(
        ll, seqlen, den_meta, den_ilv, desc, den_rp, perm, S_den,
        num_meta, num_rp, num_stride, S_num,
        den_init, den_final, num_init, num_final, T, C, B, llh);
  } else {
    fsa_forward_fallback<<<2 * B, 1024, 0, stream>>>(
        ll, seqlen,
        den_src, den_dst, den_pdf, den_w, A_den, den_init, den_final, S_den,
        num_src, num_dst, num_pdf, num_w, A_num, num_init, num_final, S_num,
        T, C, B, llh);
  }

  final_loss_kernel<<<1, 64, 0, stream>>>(llh, B, (float*)d_out);
}

// Round 12
// 2899.972 us; speedup vs baseline: 1.3362x; 1.0028x over previous
//
#include <hip/hip_runtime.h>

#define NEG_INF_F (-1e30f)
#define MAX_S 2048
#define MAX_C 3008
#define NCH   128

// vbuf: 4 copies, float offsets 0/2056/4112/6168 (bank shifts 0/8/16/24)
#define VB_SIZE 8216
// elbuf: 2 copies per buffer (+3016 floats, bank shift 8), double-buffered
#define EL_COPY 3016
#define EL_BUF  6032
#define EL_SIZE 12064

// ============================ build helpers (deterministic) ============================

__global__ void zero_kernel(int* __restrict__ p, int n) {
  int i = blockIdx.x * blockDim.x + threadIdx.x;
  if (i < n) p[i] = 0;
}

__global__ void hist_kernel(const int* __restrict__ dst, int A, int A_stride,
                            int* __restrict__ cnt, int S) {
  int b = blockIdx.y;
  int i = blockIdx.x * blockDim.x + threadIdx.x;
  if (i < A) atomicAdd(&cnt[b * S + dst[(size_t)b * A_stride + i]], 1);
}

__global__ void hist_chunk_kernel(const int* __restrict__ dst, int A, int chunk, int S,
                                  int* __restrict__ hist) {
  int c = blockIdx.x;
  int i1 = min(A, (c + 1) * chunk);
  for (int i = c * chunk + threadIdx.x; i < i1; i += blockDim.x)
    atomicAdd(&hist[c * S + dst[i]], 1);
}

__global__ void colsum_kernel(const int* __restrict__ hist, int nch, int S,
                              int* __restrict__ cnt) {
  int s = blockIdx.x * blockDim.x + threadIdx.x;
  if (s < S) {
    int t = 0;
    for (int c = 0; c < nch; ++c) t += hist[c * S + s];
    cnt[s] = t;
  }
}

// Stable in-degree rank (desc) -> slot permutation pairing heavy with light.
__global__ __launch_bounds__(1024)
void rank_perm_kernel(const int* __restrict__ cnt, int S,
                      int* __restrict__ perm, int* __restrict__ invperm) {
  __shared__ int c[2048];
  __shared__ int R[2048];
  const int tid = threadIdx.x;
  for (int i = tid; i < 2048; i += 1024) c[i] = (i < S) ? cnt[i] : -1;
  __syncthreads();
  for (int u = 0; u < 2; ++u) {
    int s = tid + u * 1024;
    if (s < S) {
      int cs = c[s], r = 0;
      for (int j = 0; j < S; ++j) {
        int cj = c[j];
        r += (cj > cs) || (cj == cs && j < s);
      }
      R[r] = s;
    }
  }
  __syncthreads();
  for (int u = 0; u < 2; ++u) {
    int slot = tid + u * 1024;
    if (slot < S) {
      int state = (slot < 1024) ? R[slot] : R[S - 1 - (slot - 1024)];
      perm[slot] = state;
      invperm[state] = slot;
    }
  }
}

__global__ void pc_kernel(const int* __restrict__ cnt, const int* __restrict__ perm,
                          int S, int* __restrict__ pc) {
  int slot = blockIdx.x * blockDim.x + threadIdx.x;
  if (slot < 2048) pc[slot] = (slot < S) ? ((cnt[perm[slot]] + 3) & ~3) : 0;
}

__global__ void padcnt_kernel(const int* __restrict__ cnt, int n, int* __restrict__ out) {
  int i = blockIdx.x * blockDim.x + threadIdx.x;
  if (i < n) out[i] = (cnt[i] + 3) & ~3;
}

__global__ __launch_bounds__(1024) void scan_kernel(const int* __restrict__ cnt,
                                                    int* __restrict__ rp, int S) {
  __shared__ int buf[2][2048];
  const int tid = threadIdx.x;
  const int b = blockIdx.x;
  const int* c = cnt + (size_t)b * S;
  int* r = rp + (size_t)b * (S + 1);
  for (int u = 0; u < 2; ++u) {
    int i = tid + u * 1024;
    buf[0][i] = (i < S) ? c[i] : 0;
  }
  __syncthreads();
  int cur = 0;
  for (int off = 1; off < 2048; off <<= 1) {
    for (int u = 0; u < 2; ++u) {
      int i = tid + u * 1024;
      buf[cur ^ 1][i] = buf[cur][i] + ((i >= off) ? buf[cur][i - off] : 0);
    }
    __syncthreads();
    cur ^= 1;
  }
  for (int u = 0; u < 2; ++u) {
    int i = tid + u * 1024;
    if (i <= S) r[i] = (i == 0) ? 0 : buf[cur][i - 1];
  }
  if (tid == 0) r[S] = buf[cur][S - 1];
}

__global__ void off_perm_kernel(int* __restrict__ hist, int nch, int S,
                                const int* __restrict__ rp, const int* __restrict__ perm) {
  int slot = blockIdx.x * blockDim.x + threadIdx.x;
  if (slot < S) {
    int state = perm[slot];
    int run = rp[slot];
    for (int c = 0; c < nch; ++c) {
      int h = hist[c * S + state];
      hist[c * S + state] = run;
      run += h;
    }
  }
}

// fill pad arcs at row tails (den): y==0 marks pad (ew = 0), bank-spread x
__global__ void pad_den_kernel(const int* __restrict__ rp, const int* __restrict__ cnt,
                               const int* __restrict__ perm, int S, int C,
                               uint2* __restrict__ meta) {
  int slot = blockIdx.x * blockDim.x + threadIdx.x;
  if (slot < S) {
    int p = rp[slot] + cnt[perm[slot]];
    int e = rp[slot + 1];
    const int pc = min(slot, C - 1);
    uint2 pad = make_uint2((unsigned)(slot * 4) | ((unsigned)(pc * 4) << 16), 0u);
    for (; p < e; ++p) meta[p] = pad;
  }
}

// DEN meta: x = (src_slot*4) | ((pdf*4)<<16)  (pre-scaled LDS byte offsets), y = exp(w).
__global__ void fill_chunk_kernel(const int* __restrict__ src, const int* __restrict__ dst,
                                  const int* __restrict__ pdf, const float* __restrict__ w,
                                  int A, int chunk, int S, int* __restrict__ hoff,
                                  const int* __restrict__ inv, uint2* __restrict__ meta) {
  int c = blockIdx.y;
  int s = blockIdx.x * blockDim.x + threadIdx.x;
  if (s >= S) return;
  int i1 = min(A, (c + 1) * chunk);
  int p = hoff[c * S + s];
  for (int i = c * chunk; i < i1; ++i) {
    if (dst[i] == s) {
      meta[p++] = make_uint2((unsigned)(inv[src[i]] * 4) | ((unsigned)(pdf[i] * 4) << 16),
                             __float_as_uint(__expf(w[i])));
    }
  }
}

// numerator meta keeps index packing (src | pdf<<16) + raw w
__global__ void fill_kernel(const int* __restrict__ src, const int* __restrict__ dst,
                            const int* __restrict__ pdf, const float* __restrict__ w,
                            int A, int A_stride, const int* __restrict__ rp, int S,
                            uint2* __restrict__ meta, int meta_stride) {
  int b = blockIdx.y;
  int s = blockIdx.x * blockDim.x + threadIdx.x;
  if (s >= S) return;
  const int*   sb = src + (size_t)b * A_stride;
  const int*   db = dst + (size_t)b * A_stride;
  const int*   pb = pdf + (size_t)b * A_stride;
  const float* wb = w   + (size_t)b * A_stride;
  const int*   rpb = rp + (size_t)b * (S + 1);
  uint2* mb = meta + (size_t)b * meta_stride;
  int p = rpb[s];
  for (int i = 0; i < A; ++i) {
    if (db[i] == s) {
      mb[p++] = make_uint2((unsigned)sb[i] | ((unsigned)pb[i] << 16), __float_as_uint(wb[i]));
    }
  }
  uint2 pad = make_uint2(0u, __float_as_uint(NEG_INF_F));
  int e = rpb[s + 1];
  for (; p < e; ++p) mb[p] = pad;
}

// ---- wave-interleaved den meta: desc = offA[16],offB[16],wmaxA[16],wmaxB[16],ok,total ----
__global__ __launch_bounds__(1024)
void wave_desc_kernel(const int* __restrict__ rp, int cap4, int* __restrict__ desc) {
  __shared__ int wm[32];
  const int tid = threadIdx.x;
  const int w = tid >> 6;
  int cA = (rp[tid + 1] - rp[tid]) >> 2;
  int sB = 2047 - tid;
  int cB = (rp[sB + 1] - rp[sB]) >> 2;
  for (int off = 32; off; off >>= 1) {
    cA = max(cA, __shfl_down(cA, off));
    cB = max(cB, __shfl_down(cB, off));
  }
  if ((tid & 63) == 0) { wm[w] = cA; wm[16 + w] = cB; }
  __syncthreads();
  if (tid == 0) {
    int off = 0;
    for (int i = 0; i < 16; ++i) { desc[i] = off; off += wm[i] * 128; }
    for (int i = 0; i < 16; ++i) { desc[16 + i] = off; off += wm[16 + i] * 128; }
    for (int i = 0; i < 16; ++i) { desc[32 + i] = wm[i]; desc[48 + i] = wm[16 + i]; }
    desc[64] = (off <= cap4) ? 1 : 0;
    desc[65] = off;
  }
}

// Fused repack + replica-choice, fully LDS-staged. grid 32 blocks x 64 lanes.
// Stage each lane's row (padded to P with bank-spread y==0 pads) into sp[64][65],
// run the per-position sequential-feedback replica choice in registers (lane l
// owns position l; P<=64 on the fast path), write the interleaved slab once,
// coalesced. Copies hold identical values -> numerics unchanged vs. base copy.
__global__ __launch_bounds__(64)
void repack_choice_kernel(const uint2* __restrict__ meta, const int* __restrict__ rp,
                          const int* __restrict__ desc, int C, uint2* __restrict__ ilv) {
  if (!desc[64]) return;
  const int w = blockIdx.x & 15;
  const bool isB = blockIdx.x >= 16;
  const int l = threadIdx.x;
  const int base4 = desc[(isB ? 16 : 0) + w];
  const int wmax  = desc[(isB ? 48 : 32) + w];
  const int P = wmax * 4;
  if (P == 0) return;

  const int slot_l = isB ? (2047 - (w * 64 + l)) : (w * 64 + l);
  const int r0_l = rp[slot_l];
  const int n_l  = rp[slot_l + 1] - r0_l;   // padded to multiple of 4
  const int pc_l = min(slot_l, C - 1);
  const uint2 pad_l = make_uint2((unsigned)(slot_l * 4) | ((unsigned)(pc_l * 4) << 16), 0u);

  if (P > 64) {
    // order-preserving interleave copy, no choice (not expected for typical shapes)
    const int n4 = n_l >> 2;
    for (int c = 0; c < wmax; ++c) {
      for (int part = 0; part < 2; ++part) {
        int u4 = base4 + c * 128 + part * 64 + l;
        uint2 v0 = pad_l, v1 = pad_l;
        if (c < n4) {
          v0 = meta[r0_l + 4 * c + 2 * part];
          v1 = meta[r0_l + 4 * c + 2 * part + 1];
        }
        ilv[2 * u4]     = v0;
        ilv[2 * u4 + 1] = v1;
      }
    }
    return;
  }

  __shared__ uint2 sp[64][65];   // padded row stride to break bank alignment

  for (int p = 0; p < P; ++p)
    sp[l][p] = (p < n_l) ? meta[r0_l + p] : pad_l;
  __syncthreads();

  if (l < P) {
    unsigned long long cs[4]  = {0, 0, 0, 0};   // 32 x 8-bit src-bank counts
    unsigned long long cp2[4] = {0, 0, 0, 0};   // 32 x 8-bit pdf-bank counts
    for (int r = 0; r < 64; ++r) {
      uint2 a = sp[r][l];
      unsigned srcoff = a.x & 0xFFFFu;
      unsigned pdfoff = a.x >> 16;
      // src: 4 choices, bank shifts {0,8,16,24}
      const int b0 = (int)((srcoff >> 2) & 31u);
      int bestk = 0, bestc = 256;
#pragma unroll
      for (int k = 0; k < 4; ++k) {
        int bb = (b0 + 8 * k) & 31;
        int c = (int)((cs[bb >> 3] >> ((bb & 7) * 8)) & 0xFFull);
        if (c < bestc) { bestc = c; bestk = k; }
      }
      const int bs = (b0 + 8 * bestk) & 31;
      cs[bs >> 3] += (1ULL << ((bs & 7) * 8));
      // pdf: 2 choices, bank shifts {0,8}
      const int q0 = (int)((pdfoff >> 2) & 31u);
      const int q1 = (q0 + 8) & 31;
      const int c0 = (int)((cp2[q0 >> 3] >> ((q0 & 7) * 8)) & 0xFFull);
      const int c1 = (int)((cp2[q1 >> 3] >> ((q1 & 7) * 8)) & 0xFFull);
      const int bj = (c1 < c0) ? 1 : 0;
      const int qb = bj ? q1 : q0;
      cp2[qb >> 3] += (1ULL << ((qb & 7) * 8));
      a.x = (srcoff + (unsigned)bestk * 8224u) | ((pdfoff + (unsigned)bj * 12064u) << 16);
      sp[r][l] = a;
    }
  }
  __syncthreads();

  // coalesced writeout: lane l = row l
  for (int c = 0; c < wmax; ++c) {
    for (int part = 0; part < 2; ++part) {
      int u4 = base4 + c * 128 + part * 64 + l;
      ilv[2 * u4]     = sp[l][4 * c + 2 * part];
      ilv[2 * u4 + 1] = sp[l][4 * c + 2 * part + 1];
    }
  }
}

// ============================ exact row LSE (numerator path) ============================

__device__ __forceinline__ float row_lse(const uint2* __restrict__ meta, int k, int e,
                                         const float* __restrict__ alpha,
                                         const float* __restrict__ lcur) {
  float mm0 = NEG_INF_F, ss0 = 0.0f, mm1 = NEG_INF_F, ss1 = 0.0f;
  const int n4 = (e - k) >> 2;
  const uint4* p = (const uint4*)(meta + k);
  if (n4 > 0) {
    uint4 A = p[0], Bv = p[1];
    float t0 = alpha[A.x & 0xFFFFu] + __uint_as_float(A.y) + lcur[A.x >> 16];
    float t1 = alpha[A.z & 0xFFFFu] + __uint_as_float(A.w) + lcur[A.z >> 16];
    float t2 = alpha[Bv.x & 0xFFFFu] + __uint_as_float(Bv.y) + lcur[Bv.x >> 16];
    float t3 = alpha[Bv.z & 0xFFFFu] + __uint_as_float(Bv.w) + lcur[Bv.z >> 16];
    for (int c2 = 1; c2 < n4; ++c2) {
      uint4 A2 = p[2 * c2], B2 = p[2 * c2 + 1];
      float u0 = alpha[A2.x & 0xFFFFu] + __uint_as_float(A2.y) + lcur[A2.x >> 16];
      float u1 = alpha[A2.z & 0xFFFFu] + __uint_as_float(A2.w) + lcur[A2.z >> 16];
      float u2 = alpha[B2.x & 0xFFFFu] + __uint_as_float(B2.y) + lcur[B2.x >> 16];
      float u3 = alpha[B2.z & 0xFFFFu] + __uint_as_float(B2.w) + lcur[B2.z >> 16];
      float mc = fmaxf(fmaxf(t0, t1), fmaxf(t2, t3));
      if ((c2 & 1) != 0) {
        float nm = fmaxf(mm0, mc);
        ss0 = ss0 * __expf(mm0 - nm) +
              ((__expf(t0 - nm) + __expf(t1 - nm)) + (__expf(t2 - nm) + __expf(t3 - nm)));
        mm0 = nm;
      } else {
        float nm = fmaxf(mm1, mc);
        ss1 = ss1 * __expf(mm1 - nm) +
              ((__expf(t0 - nm) + __expf(t1 - nm)) + (__expf(t2 - nm) + __expf(t3 - nm)));
        mm1 = nm;
      }
      t0 = u0; t1 = u1; t2 = u2; t3 = u3;
    }
    float mc = fmaxf(fmaxf(t0, t1), fmaxf(t2, t3));
    if ((n4 & 1) != 0) {
      float nm = fmaxf(mm0, mc);
      ss0 = ss0 * __expf(mm0 - nm) +
            ((__expf(t0 - nm) + __expf(t1 - nm)) + (__expf(t2 - nm) + __expf(t3 - nm)));
      mm0 = nm;
    } else {
      float nm = fmaxf(mm1, mc);
      ss1 = ss1 * __expf(mm1 - nm) +
            ((__expf(t0 - nm) + __expf(t1 - nm)) + (__expf(t2 - nm) + __expf(t3 - nm)));
      mm1 = nm;
    }
  }
  float nm = fmaxf(mm0, mm1);
  float ssc = ss0 * __expf(mm0 - nm) + ss1 * __expf(mm1 - nm);
  return (ssc > 0.0f) ? (__logf(ssc) + nm) : NEG_INF_F;
}

__device__ __forceinline__ void stage_row(const float* __restrict__ row,
                                          float* __restrict__ lds, int C, int tid, int nt) {
  if (((C & 3) == 0) && ((((uintptr_t)row) & 15) == 0)) {
    const float4* r4 = (const float4*)row;
    const int n = C >> 2;
    for (int i = tid; i < n; i += nt) ((float4*)lds)[i] = r4[i];
  } else {
    for (int i = tid; i < C; i += nt) lds[i] = row[i];
  }
}

// LDS read with pre-scaled byte offset
__device__ __forceinline__ float ldsF(const float* base, unsigned boff) {
  return *(const float*)((const char*)base + boff);
}

#define ACC4(X, Y, s0, s1, s2, s3)                                                         \
  s0 = fmaf(__uint_as_float((X).y), ldsF(vbuf, (X).x & 0xFFFFu) * ldsF(el, (X).x >> 16), s0); \
  s1 = fmaf(__uint_as_float((X).w), ldsF(vbuf, (X).z & 0xFFFFu) * ldsF(el, (X).z >> 16), s1); \
  s2 = fmaf(__uint_as_float((Y).y), ldsF(vbuf, (Y).x & 0xFFFFu) * ldsF(el, (Y).x >> 16), s2); \
  s3 = fmaf(__uint_as_float((Y).w), ldsF(vbuf, (Y).z & 0xFFFFu) * ldsF(el, (Y).z >> 16), s3);

// ============================ forward: den linear-space (replica-choice), num exact-LSE ============================
__global__ __launch_bounds__(1024, 1)
void fsa_forward_lin(const float* __restrict__ ll, const int* __restrict__ seqlen,
                     const uint2* __restrict__ den_meta, const uint4* __restrict__ den_ilv,
                     const int* __restrict__ den_desc,
                     const int* __restrict__ den_rp, const int* __restrict__ den_perm, int S_den,
                     const uint2* __restrict__ num_meta, const int* __restrict__ num_rp,
                     int num_stride, int S_num,
                     const float* __restrict__ den_init, const float* __restrict__ den_final,
                     const float* __restrict__ num_init, const float* __restrict__ num_final,
                     int T, int C, int B, float* __restrict__ out_llh)
{
  __shared__ float alpha[MAX_S];
  __shared__ float vbuf[VB_SIZE];      // 4 copies (bank shifts 0/8/16/24)
  __shared__ float elbuf[EL_SIZE];     // den: exp(ll), 2 copies x 2 buffers; num: raw ll
  __shared__ float red[16];
  __shared__ int   sdesc[66];

  const int tid = threadIdx.x;
  const int nt  = 1024;
  const bool is_den = ((int)blockIdx.x) < B;
  const int b = is_den ? (int)blockIdx.x : ((int)blockIdx.x - B);
  const int S = is_den ? S_den : S_num;
  const float* fin  = is_den ? den_final : num_final;
  const int*   perm = is_den ? den_perm  : nullptr;

  const int L = seqlen[b];
  const float* llb = ll + ((size_t)b * T) * C;

  if (is_den) {
    // ---- linear-space denominator, 2 barriers/step ----
    for (int i = tid; i < 66; i += nt) sdesc[i] = den_desc[i];

    const int w = tid >> 6, l = tid & 63;
    const int slotA = tid;            // heavy ranks
    const int slotB = 2047 - tid;     // paired light ranks
    const int rA0 = den_rp[slotA], rA1 = den_rp[slotA + 1];
    const int rB0 = den_rp[slotB], rB1 = den_rp[slotB + 1];
    float a0 = (slotA < S) ? den_init[den_perm[slotA]] : NEG_INF_F;
    float a1 = (slotB < S) ? den_init[den_perm[slotB]] : NEG_INF_F;

    const int nvec = C >> 2;
    const bool pf = ((C & 3) == 0) && ((((uintptr_t)llb) & 15) == 0) &&
                    (nvec <= nt) && (C <= MAX_C);

    // initial M reduce + EL stage for row 0 (buffer 0, both copies)
    float lm = fmaxf(a0, a1);
    for (int off = 32; off; off >>= 1) lm = fmaxf(lm, __shfl_down(lm, off));
    if ((tid & 63) == 0) red[tid >> 6] = lm;
    if (L > 0) {
      if (pf) {
        if (tid < nvec) {
          float4 r = ((const float4*)llb)[tid];
          float4 e = make_float4(__expf(r.x), __expf(r.y), __expf(r.z), __expf(r.w));
          ((float4*)elbuf)[tid] = e;
          ((float4*)(elbuf + EL_COPY))[tid] = e;
        }
      } else {
        for (int i = tid; i < C; i += nt) {
          float e = __expf(llb[i]);
          elbuf[i] = e;
          elbuf[i + EL_COPY] = e;
        }
      }
    }
    __syncthreads();
    float M = red[0];
#pragma unroll
    for (int i = 1; i < 16; ++i) M = fmaxf(M, red[i]);

    const bool ilv_ok = sdesc[64] != 0;
    const uint4* pA4 = den_ilv + sdesc[w] + l;
    const uint4* pB4 = den_ilv + sdesc[16 + w] + l;
    const int nA = sdesc[32 + w], nB = sdesc[48 + w];

    int cur = 0;
    for (int t = 0; t < L; ++t) {
      {
        float va = __expf(a0 - M), vb = __expf(a1 - M);
        vbuf[slotA] = va; vbuf[slotA + 2056] = va;
        vbuf[slotA + 4112] = va; vbuf[slotA + 6168] = va;
        vbuf[slotB] = vb; vbuf[slotB + 2056] = vb;
        vbuf[slotB + 4112] = vb; vbuf[slotB + 6168] = vb;
      }
      __syncthreads();                       // B1: vbuf + elbuf[cur] ready

      const float* el = elbuf + (cur ? EL_BUF : 0);

      float4 nx;
      const bool donx = pf && (t + 1 < L) && (tid < nvec);
      if (donx) nx = ((const float4*)(llb + (size_t)(t + 1) * C))[tid];

      float sA0 = 0, sA1 = 0, sA2 = 0, sA3 = 0;
      float sB0 = 0, sB1 = 0, sB2 = 0, sB3 = 0;
      if (ilv_ok) {
        if (nA > 0) {
          uint4 X0 = pA4[0], Y0 = pA4[64];
          if (nA > 1) {
            uint4 X1 = pA4[128], Y1 = pA4[192];
            for (int c = 2; c < nA; ++c) {
              uint4 X2 = pA4[c * 128], Y2 = pA4[c * 128 + 64];
              ACC4(X0, Y0, sA0, sA1, sA2, sA3);
              X0 = X1; Y0 = Y1; X1 = X2; Y1 = Y2;
            }
            ACC4(X0, Y0, sA0, sA1, sA2, sA3);
            X0 = X1; Y0 = Y1;
          }
          ACC4(X0, Y0, sA0, sA1, sA2, sA3);
        }
        if (nB > 0) {
          uint4 X0 = pB4[0], Y0 = pB4[64];
          for (int c = 1; c < nB; ++c) {
            uint4 X1 = pB4[c * 128], Y1 = pB4[c * 128 + 64];
            ACC4(X0, Y0, sB0, sB1, sB2, sB3);
            X0 = X1; Y0 = Y1;
          }
          ACC4(X0, Y0, sB0, sB1, sB2, sB3);
        }
      } else {
        const uint4* pA = (const uint4*)(den_meta + rA0);
        const uint4* pB = (const uint4*)(den_meta + rB0);
        const int nAr = (rA1 - rA0) >> 2, nBr = (rB1 - rB0) >> 2;
        const int n = nAr > nBr ? nAr : nBr;
        for (int c = 0; c < n; ++c) {
          if (c < nAr) {
            uint4 X = pA[2 * c], Y = pA[2 * c + 1];
            ACC4(X, Y, sA0, sA1, sA2, sA3);
          }
          if (c < nBr) {
            uint4 X = pB[2 * c], Y = pB[2 * c + 1];
            ACC4(X, Y, sB0, sB1, sB2, sB3);
          }
        }
      }
      float sA = (sA0 + sA1) + (sA2 + sA3);
      float sB = (sB0 + sB1) + (sB2 + sB3);

      a0 = (sA > 0.0f) ? (__logf(sA) + M) : NEG_INF_F;
      a1 = (sB > 0.0f) ? (__logf(sB) + M) : NEG_INF_F;

      float* eln = elbuf + (cur ? 0 : EL_BUF);
      if (donx) {
        float4 e = make_float4(__expf(nx.x), __expf(nx.y), __expf(nx.z), __expf(nx.w));
        ((float4*)eln)[tid] = e;
        ((float4*)(eln + EL_COPY))[tid] = e;
      } else if (!pf && t + 1 < L) {
        const float* nr = llb + (size_t)(t + 1) * C;
        for (int i = tid; i < C; i += nt) {
          float e = __expf(nr[i]);
          eln[i] = e;
          eln[i + EL_COPY] = e;
        }
      }

      float lm2 = fmaxf(a0, a1);
      for (int off = 32; off; off >>= 1) lm2 = fmaxf(lm2, __shfl_down(lm2, off));
      if ((tid & 63) == 0) red[tid >> 6] = lm2;
      __syncthreads();                       // B2: sums done, red + elbuf[nxt] visible
      M = red[0];
#pragma unroll
      for (int i = 1; i < 16; ++i) M = fmaxf(M, red[i]);
      cur ^= 1;
    }
    alpha[slotA] = a0;
    alpha[slotB] = a1;
    __syncthreads();
  } else {
    // ---- exact-LSE numerator (tiny) ----
    const uint2* meta = num_meta + (size_t)b * num_stride;
    const int*   rp   = num_rp + (size_t)b * (S_num + 1);
    for (int s = tid; s < MAX_S; s += nt) alpha[s] = (s < S) ? num_init[s] : NEG_INF_F;
    int rs[2] = {0, 0}, re[2] = {0, 0};
    for (int u = 0; u < 2; ++u) {
      int s = tid + u * nt;
      if (s < S) { rs[u] = rp[s]; re[u] = rp[s + 1]; }
    }
    __syncthreads();
    for (int t = 0; t < L; ++t) {
      stage_row(llb + (size_t)t * C, elbuf, C, tid, nt);
      __syncthreads();
      float nv[2];
      for (int u = 0; u < 2; ++u) {
        int s = tid + u * nt;
        nv[u] = (s < S) ? row_lse(meta, rs[u], re[u], alpha, elbuf) : NEG_INF_F;
      }
      __syncthreads();
      for (int u = 0; u < 2; ++u) {
        int s = tid + u * nt;
        if (s < S) alpha[s] = nv[u];
      }
      __syncthreads();
    }
  }

  // final logsumexp(alpha + final_logp)
  float lm = -3.0e38f;
  for (int s = tid; s < S; s += nt) lm = fmaxf(lm, alpha[s] + fin[perm ? perm[s] : s]);
  for (int off = 32; off; off >>= 1) lm = fmaxf(lm, __shfl_down(lm, off));
  if ((tid & 63) == 0) red[tid >> 6] = lm;
  __syncthreads();
  if (tid < 64) {
    float v = (tid < 16) ? red[tid] : -3.0e38f;
    for (int off = 32; off; off >>= 1) v = fmaxf(v, __shfl_down(v, off));
    if (tid == 0) red[0] = v;
  }
  __syncthreads();
  const float M = red[0];

  float ls = 0.0f;
  for (int s = tid; s < S; s += nt) ls += __expf(alpha[s] + fin[perm ? perm[s] : s] - M);
  for (int off = 32; off; off >>= 1) ls += __shfl_down(ls, off);
  __syncthreads();
  if ((tid & 63) == 0) red[tid >> 6] = ls;
  __syncthreads();
  if (tid < 64) {
    float v = (tid < 16) ? red[tid] : 0.0f;
    for (int off = 32; off; off >>= 1) v += __shfl_down(v, off);
    if (tid == 0) out_llh[(is_den ? 0 : B) + b] = __logf(v) + M;
  }
}

// ============================ fallback (atomic path, tiny ws) ============================

__device__ __forceinline__ unsigned enc_f(float x) {
  unsigned u = __float_as_uint(x);
  return u ^ (unsigned)(((int)u >> 31) | 0x80000000);
}
__device__ __forceinline__ float dec_f(unsigned e) {
  unsigned mask = ((int)e >= 0) ? 0xFFFFFFFFu : 0x80000000u;
  return __uint_as_float(e ^ mask);
}

__global__ __launch_bounds__(1024)
void fsa_forward_fallback(
    const float* __restrict__ ll, const int* __restrict__ seqlen,
    const int* __restrict__ den_src, const int* __restrict__ den_dst,
    const int* __restrict__ den_pdf, const float* __restrict__ den_w,
    int A_den, const float* __restrict__ den_init, const float* __restrict__ den_final, int S_den,
    const int* __restrict__ num_src, const int* __restrict__ num_dst,
    const int* __restrict__ num_pdf, const float* __restrict__ num_w,
    int A_num, const float* __restrict__ num_init, const float* __restrict__ num_final, int S_num,
    int T, int C, int B, float* __restrict__ out_llh)
{
  __shared__ float    alpha[MAX_S];
  __shared__ unsigned menc[MAX_S];
  __shared__ float    msafe[MAX_S];
  __shared__ float    ssum[MAX_S];
  __shared__ float    llrow[MAX_C];

  const int tid = threadIdx.x;
  const int nt  = blockDim.x;
  const bool is_den = ((int)blockIdx.x) < B;
  const int b = is_den ? (int)blockIdx.x : ((int)blockIdx.x - B);
  const int S = is_den ? S_den : S_num;
  const int A = is_den ? A_den : A_num;
  const float* init = is_den ? den_init  : num_init;
  const float* fin  = is_den ? den_final : num_final;
  const int*   asrc = is_den ? den_src  : (num_src + (size_t)b * A_num);
  const int*   adst = is_den ? den_dst  : (num_dst + (size_t)b * A_num);
  const int*   apdf = is_den ? den_pdf  : (num_pdf + (size_t)b * A_num);
  const float* aw   = is_den ? den_w    : (num_w   + (size_t)b * A_num);

  for (int s = tid; s < S; s += nt) { alpha[s] = init[s]; menc[s] = 0u; ssum[s] = 0.0f; }
  __syncthreads();

  const int L = seqlen[b];
  const float* llb = ll + ((size_t)b * T) * C;

  for (int t = 0; t < L; ++t) {
    const float* row = llb + (size_t)t * C;
    for (int i = tid; i < C; i += nt) llrow[i] = row[i];
    __syncthreads();
    for (int i = tid; i < A; i += nt) {
      float score = alpha[asrc[i]] + aw[i] + llrow[apdf[i]];
      atomicMax(&menc[adst[i]], enc_f(score));
    }
    __syncthreads();
    for (int s = tid; s < S; s += nt) {
      float m = dec_f(menc[s]);
      msafe[s] = (m > -5e29f) ? m : 0.0f;
    }
    __syncthreads();
    for (int i = tid; i < A; i += nt) {
      int d = adst[i];
      float score = alpha[asrc[i]] + aw[i] + llrow[apdf[i]];
      atomicAdd(&ssum[d], __expf(score - msafe[d]));
    }
    __syncthreads();
    for (int s = tid; s < S; s += nt) {
      float sum = ssum[s];
      alpha[s] = (sum > 0.0f) ? (__logf(sum) + msafe[s]) : NEG_INF_F;
      menc[s] = 0u; ssum[s] = 0.0f;
    }
    __syncthreads();
  }

  float lm = -3.0e38f;
  for (int s = tid; s < S; s += nt) lm = fmaxf(lm, alpha[s] + fin[s]);
  for (int off = 32; off; off >>= 1) lm = fmaxf(lm, __shfl_down(lm, off));
  const int nwaves = nt >> 6;
  if ((tid & 63) == 0) msafe[tid >> 6] = lm;
  __syncthreads();
  if (tid < 64) {
    float v = (tid < nwaves) ? msafe[tid] : -3.0e38f;
    for (int off = 32; off; off >>= 1) v = fmaxf(v, __shfl_down(v, off));
    if (tid == 0) msafe[MAX_S - 1] = v;
  }
  __syncthreads();
  const float M = msafe[MAX_S - 1];
  float ls = 0.0f;
  for (int s = tid; s < S; s += nt) ls += __expf(alpha[s] + fin[s] - M);
  for (int off = 32; off; off >>= 1) ls += __shfl_down(ls, off);
  if ((tid & 63) == 0) ssum[tid >> 6] = ls;
  __syncthreads();
  if (tid < 64) {
    float v = (tid < nwaves) ? ssum[tid] : 0.0f;
    for (int off = 32; off; off >>= 1) v += __shfl_down(v, off);
    if (tid == 0) out_llh[(is_den ? 0 : B) + b] = __logf(v) + M;
  }
}

// loss = sum_b (den_llh[b] - num_llh[b])
__global__ void final_loss_kernel(const float* __restrict__ llh, int B, float* __restrict__ out) {
  int lane = threadIdx.x;
  float v = (lane < B) ? (llh[lane] - llh[B + lane]) : 0.0f;
  for (int off = 32; off; off >>= 1) v += __shfl_down(v, off);
  if (lane == 0) out[0] = v;
}

extern "C" void kernel_launch(void* const* d_in, const int* in_sizes, int n_in,
                              void* d_out, int out_size, void* d_ws, size_t ws_size,
                              hipStream_t stream) {
  const float* ll        = (const float*)d_in[0];
  const int*   seqlen    = (const int*)  d_in[1];
  const int*   num_src   = (const int*)  d_in[2];
  const int*   num_dst   = (const int*)  d_in[3];
  const int*   num_pdf   = (const int*)  d_in[4];
  const float* num_w     = (const float*)d_in[5];
  const float* num_init  = (const float*)d_in[6];
  const float* num_final = (const float*)d_in[7];
  const int*   den_src   = (const int*)  d_in[8];
  const int*   den_dst   = (const int*)  d_in[9];
  const int*   den_pdf   = (const int*)  d_in[10];
  const float* den_w     = (const float*)d_in[11];
  const float* den_init  = (const float*)d_in[12];
  const float* den_final = (const float*)d_in[13];

  const int B     = in_sizes[1];
  const int A_num = in_sizes[2] / B;
  const int S_num = in_sizes[6];
  const int A_den = in_sizes[8];
  const int S_den = in_sizes[12];
  const int T     = 500;                       // problem spec
  const int C     = in_sizes[0] / (B * T);

  const int den_cap    = A_den + 3 * S_den + 64;
  const int num_stride = A_num + 3 * S_num + 64;
  const int cap4       = den_cap + 32768;      // interleaved capacity (uint4 units)

  // workspace layout
  size_t off = 0;
  auto alloc = [&](size_t bytes, size_t align) -> size_t {
    off = (off + align - 1) / align * align;
    size_t r = off; off += bytes; return r;
  };
  size_t o_den_meta = alloc((size_t)den_cap * 8, 16);
  size_t o_den_ilv  = alloc((size_t)cap4 * 16, 16);
  size_t o_desc     = alloc((size_t)66 * 4, 4);
  size_t o_num_meta = alloc((size_t)B * num_stride * 8, 16);
  size_t o_den_rp   = alloc((size_t)2049 * 4, 4);
  size_t o_num_rp   = alloc((size_t)B * (S_num + 1) * 4, 4);
  size_t o_den_cnt  = alloc((size_t)S_den * 4, 4);
  size_t o_perm     = alloc((size_t)2048 * 4, 4);
  size_t o_inv      = alloc((size_t)S_den * 4, 4);
  size_t o_pc       = alloc((size_t)2048 * 4, 4);
  size_t o_num_pc   = alloc((size_t)B * S_num * 4, 4);
  size_t o_hist     = alloc((size_t)NCH * S_den * 4, 4);   // zeroed region start
  size_t o_num_cnt  = alloc((size_t)B * S_num * 4, 4);     // contiguous with hist
  size_t o_llh      = alloc((size_t)2 * B * 4, 4);
  const bool use_csr = (off <= ws_size) && (S_den >= 1) && (S_den <= 2048) &&
                       (S_num >= 1) && (S_num <= 2048) && (C <= MAX_C) && (C >= 1);

  char* wsb = (char*)d_ws;
  float* llh = (float*)(wsb + (use_csr ? o_llh : 0));

  if (use_csr) {
    uint2* den_meta = (uint2*)(wsb + o_den_meta);
    uint4* den_ilv  = (uint4*)(wsb + o_den_ilv);
    int*   desc     = (int*)(wsb + o_desc);
    uint2* num_meta = (uint2*)(wsb + o_num_meta);
    int*   den_rp   = (int*)(wsb + o_den_rp);
    int*   num_rp   = (int*)(wsb + o_num_rp);
    int*   den_cnt  = (int*)(wsb + o_den_cnt);
    int*   perm     = (int*)(wsb + o_perm);
    int*   inv      = (int*)(wsb + o_inv);
    int*   pc       = (int*)(wsb + o_pc);
    int*   num_pc   = (int*)(wsb + o_num_pc);
    int*   hist     = (int*)(wsb + o_hist);
    int*   num_cnt  = (int*)(wsb + o_num_cnt);

    const int chunk = (A_den + NCH - 1) / NCH;

    // zero hist + num_cnt (contiguous)
    int ztot = NCH * S_den + B * S_num;
    zero_kernel<<<(ztot + 255) / 256, 256, 0, stream>>>(hist, ztot);

    hist_chunk_kernel<<<NCH, 256, 0, stream>>>(den_dst, A_den, chunk, S_den, hist);
    hist_kernel<<<dim3((A_num + 255) / 256, B), 256, 0, stream>>>(num_dst, A_num, A_num,
                                                                  num_cnt, S_num);

    colsum_kernel<<<(S_den + 255) / 256, 256, 0, stream>>>(hist, NCH, S_den, den_cnt);
    rank_perm_kernel<<<1, 1024, 0, stream>>>(den_cnt, S_den, perm, inv);
    pc_kernel<<<8, 256, 0, stream>>>(den_cnt, perm, S_den, pc);
    scan_kernel<<<1, 1024, 0, stream>>>(pc, den_rp, 2048);
    wave_desc_kernel<<<1, 1024, 0, stream>>>(den_rp, cap4, desc);

    padcnt_kernel<<<(B * S_num + 255) / 256, 256, 0, stream>>>(num_cnt, B * S_num, num_pc);
    scan_kernel<<<B, 1024, 0, stream>>>(num_pc, num_rp, S_num);

    off_perm_kernel<<<(S_den + 255) / 256, 256, 0, stream>>>(hist, NCH, S_den, den_rp, perm);
    pad_den_kernel<<<(S_den + 255) / 256, 256, 0, stream>>>(den_rp, den_cnt, perm, S_den, C,
                                                            den_meta);
    fill_chunk_kernel<<<dim3((S_den + 255) / 256, NCH), 256, 0, stream>>>(
        den_src, den_dst, den_pdf, den_w, A_den, chunk, S_den, hist, inv, den_meta);
    fill_kernel<<<dim3((S_num + 255) / 256, B), 256, 0, stream>>>(
        num_src, num_dst, num_pdf, num_w, A_num, A_num, num_rp, S_num, num_meta, num_stride);

    repack_choice_kernel<<<32, 64, 0, stream>>>(den_meta, den_rp, desc, C, (uint2*)den_ilv);

    fsa_forward_lin<<<2 * B, 1024, 0, stream>>>(
        ll, seqlen, den_meta, den_ilv, desc, den_rp, perm, S_den,
        num_meta, num_rp, num_stride, S_num,
        den_init, den_final, num_init, num_final, T, C, B, llh);
  } else {
    fsa_forward_fallback<<<2 * B, 1024, 0, stream>>>(
        ll, seqlen,
        den_src, den_dst, den_pdf, den_w, A_den, den_init, den_final, S_den,
        num_src, num_dst, num_pdf, num_w, A_num, num_init, num_final, S_num,
        T, C, B, llh);
  }

  final_loss_kernel<<<1, 64, 0, stream>>>(llh, B, (float*)d_out);
}

// Round 13
// 2861.331 us; speedup vs baseline: 1.3542x; 1.0135x over previous
//
#include <hip/hip_runtime.h>

#define NEG_INF_F (-1e30f)
#define MAX_S 2048
#define MAX_C 3008
#define NCH   128

// vbuf: 4 copies, float offsets 0/2056/4112/6168 (bank shifts 0/8/16/24)
#define VB_SIZE 8216
// elbuf: 2 copies per buffer (+3016 floats, bank shift 8), double-buffered
#define EL_COPY 3016
#define EL_BUF  6032
#define EL_SIZE 12064

// ============================ build (6 launches total) ============================

// Block c zeroes ITS OWN hist slice then counts its chunk (no global pre-zero needed).
__global__ void hist_chunk_kernel(const int* __restrict__ dst, int A, int chunk, int S,
                                  int* __restrict__ hist) {
  const int c = blockIdx.x;
  int* h = hist + (size_t)c * S;
  for (int i = threadIdx.x; i < S; i += blockDim.x) h[i] = 0;
  __syncthreads();
  int i1 = min(A, (c + 1) * chunk);
  for (int i = c * chunk + threadIdx.x; i < i1; i += blockDim.x)
    atomicAdd(&h[dst[i]], 1);
}

// Single-block fused den stats: LDS histogram -> stable desc-rank -> heavy/light slot
// permutation -> padded-count exclusive scan -> rp/perm/inv/cnt + wave desc.
__global__ __launch_bounds__(1024)
void den_stats_kernel(const int* __restrict__ dst, int A, int S, int cap4,
                      int* __restrict__ rp_g, int* __restrict__ perm_g,
                      int* __restrict__ inv_g, int* __restrict__ cnt_g,
                      int* __restrict__ desc) {
  __shared__ int cnt[2048];
  __shared__ int R[2048];
  __shared__ int P2[2048];
  __shared__ int buf[2][2048];
  __shared__ int wm[32];
  const int tid = threadIdx.x;
  for (int i = tid; i < 2048; i += 1024) cnt[i] = 0;
  __syncthreads();
  for (int i = tid; i < A; i += 1024) atomicAdd(&cnt[dst[i]], 1);
  __syncthreads();
  // stable in-degree rank (desc)
  for (int u = 0; u < 2; ++u) {
    int s = tid + u * 1024;
    if (s < S) {
      int cs = cnt[s], r = 0;
      for (int j = 0; j < S; ++j) {
        int cj = cnt[j];
        r += (cj > cs) || (cj == cs && j < s);
      }
      R[r] = s;
    }
  }
  __syncthreads();
  // heavy/light pairing permutation + padded counts
  for (int u = 0; u < 2; ++u) {
    int slot = tid + u * 1024;
    int state = (slot < S) ? ((slot < 1024) ? R[slot] : R[S - 1 - (slot - 1024)]) : -1;
    P2[slot] = state;
    if (slot < S) { perm_g[slot] = state; inv_g[state] = slot; }
    buf[0][slot] = (slot < S) ? ((cnt[state] + 3) & ~3) : 0;
  }
  for (int i = tid; i < S; i += 1024) cnt_g[i] = cnt[i];
  __syncthreads();
  // Hillis-Steele inclusive scan over 2048 padded counts
  int cur = 0;
  for (int off = 1; off < 2048; off <<= 1) {
    for (int u = 0; u < 2; ++u) {
      int i = tid + u * 1024;
      buf[cur ^ 1][i] = buf[cur][i] + ((i >= off) ? buf[cur][i - off] : 0);
    }
    __syncthreads();
    cur ^= 1;
  }
  for (int u = 0; u < 2; ++u) {
    int i = tid + u * 1024;
    rp_g[i] = (i == 0) ? 0 : buf[cur][i - 1];
  }
  if (tid == 0) rp_g[2048] = buf[cur][2047];
  // wave desc: per-wave max padded-count/4 for A-slots (tid) and B-slots (2047-tid)
  int cA = ((P2[tid] >= 0) ? ((cnt[P2[tid]] + 3) & ~3) : 0) >> 2;
  const int sB = 2047 - tid;
  int cB = ((P2[sB] >= 0) ? ((cnt[P2[sB]] + 3) & ~3) : 0) >> 2;
  for (int off = 32; off; off >>= 1) {
    cA = max(cA, __shfl_down(cA, off));
    cB = max(cB, __shfl_down(cB, off));
  }
  if ((tid & 63) == 0) { wm[tid >> 6] = cA; wm[16 + (tid >> 6)] = cB; }
  __syncthreads();
  if (tid == 0) {
    int off = 0;
    for (int i = 0; i < 16; ++i) { desc[i] = off; off += wm[i] * 128; }
    for (int i = 0; i < 16; ++i) { desc[16 + i] = off; off += wm[16 + i] * 128; }
    for (int i = 0; i < 16; ++i) { desc[32 + i] = wm[i]; desc[48 + i] = wm[16 + i]; }
    desc[64] = (off <= cap4) ? 1 : 0;
    desc[65] = off;
  }
}

// Fused: hist[c][state] -> running write offsets (counting-sort bases) + pad row tails.
__global__ void offpad_kernel(int* __restrict__ hist, int nch, int S,
                              const int* __restrict__ rp, const int* __restrict__ perm,
                              const int* __restrict__ cnt, int C, uint2* __restrict__ meta) {
  int slot = blockIdx.x * blockDim.x + threadIdx.x;
  if (slot >= S) return;
  int state = perm[slot];
  int run = rp[slot];
  for (int c = 0; c < nch; ++c) {
    int h = hist[c * S + state];
    hist[c * S + state] = run;
    run += h;
  }
  int p = rp[slot] + cnt[state];
  int e = rp[slot + 1];
  const int pc = min(slot, C - 1);
  uint2 pad = make_uint2((unsigned)(slot * 4) | ((unsigned)(pc * 4) << 16), 0u);
  for (; p < e; ++p) meta[p] = pad;
}

// DEN meta: x = (src_slot*4) | ((pdf*4)<<16)  (pre-scaled LDS byte offsets), y = exp(w).
__global__ void fill_chunk_kernel(const int* __restrict__ src, const int* __restrict__ dst,
                                  const int* __restrict__ pdf, const float* __restrict__ w,
                                  int A, int chunk, int S, int* __restrict__ hoff,
                                  const int* __restrict__ inv, uint2* __restrict__ meta) {
  int c = blockIdx.y;
  int s = blockIdx.x * blockDim.x + threadIdx.x;
  if (s >= S) return;
  int i1 = min(A, (c + 1) * chunk);
  int p = hoff[c * S + s];
  for (int i = c * chunk; i < i1; ++i) {
    if (dst[i] == s) {
      meta[p++] = make_uint2((unsigned)(inv[src[i]] * 4) | ((unsigned)(pdf[i] * 4) << 16),
                             __float_as_uint(__expf(w[i])));
    }
  }
}

// Per-b fused numerator build: LDS hist -> padded scan -> stable fill + pad.
// Meta keeps index packing (src | pdf<<16) + raw w; pads x=0, y=NEG_INF.
__global__ __launch_bounds__(256)
void num_build_kernel(const int* __restrict__ src, const int* __restrict__ dst,
                      const int* __restrict__ pdf, const float* __restrict__ w,
                      int A, int S, int* __restrict__ rp_g,
                      uint2* __restrict__ meta, int meta_stride) {
  __shared__ int cnt[2048];
  __shared__ int rp[2049];
  const int b = blockIdx.x;
  const int tid = threadIdx.x;
  const int*   sb = src + (size_t)b * A;
  const int*   db = dst + (size_t)b * A;
  const int*   pb = pdf + (size_t)b * A;
  const float* wb = w   + (size_t)b * A;
  uint2* mb = meta + (size_t)b * meta_stride;
  for (int i = tid; i < S; i += 256) cnt[i] = 0;
  __syncthreads();
  for (int i = tid; i < A; i += 256) atomicAdd(&cnt[db[i]], 1);
  __syncthreads();
  if (tid == 0) {
    int run = 0;
    for (int s = 0; s < S; ++s) { rp[s] = run; run += (cnt[s] + 3) & ~3; }
    rp[S] = run;
  }
  __syncthreads();
  for (int i = tid; i <= S; i += 256) rp_g[(size_t)b * (S + 1) + i] = rp[i];
  const uint2 pad = make_uint2(0u, __float_as_uint(NEG_INF_F));
  for (int s = tid; s < S; s += 256) {
    int p = rp[s];
    for (int i = 0; i < A; ++i) {
      if (db[i] == s) {
        mb[p++] = make_uint2((unsigned)sb[i] | ((unsigned)pb[i] << 16),
                             __float_as_uint(wb[i]));
      }
    }
    for (int e = rp[s + 1]; p < e; ++p) mb[p] = pad;
  }
}

// Fused repack + replica-choice, fully LDS-staged. grid 32 blocks x 64 lanes.
__global__ __launch_bounds__(64)
void repack_choice_kernel(const uint2* __restrict__ meta, const int* __restrict__ rp,
                          const int* __restrict__ desc, int C, uint2* __restrict__ ilv) {
  if (!desc[64]) return;
  const int w = blockIdx.x & 15;
  const bool isB = blockIdx.x >= 16;
  const int l = threadIdx.x;
  const int base4 = desc[(isB ? 16 : 0) + w];
  const int wmax  = desc[(isB ? 48 : 32) + w];
  const int P = wmax * 4;
  if (P == 0) return;

  const int slot_l = isB ? (2047 - (w * 64 + l)) : (w * 64 + l);
  const int r0_l = rp[slot_l];
  const int n_l  = rp[slot_l + 1] - r0_l;
  const int pc_l = min(slot_l, C - 1);
  const uint2 pad_l = make_uint2((unsigned)(slot_l * 4) | ((unsigned)(pc_l * 4) << 16), 0u);

  if (P > 64) {
    const int n4 = n_l >> 2;
    for (int c = 0; c < wmax; ++c) {
      for (int part = 0; part < 2; ++part) {
        int u4 = base4 + c * 128 + part * 64 + l;
        uint2 v0 = pad_l, v1 = pad_l;
        if (c < n4) {
          v0 = meta[r0_l + 4 * c + 2 * part];
          v1 = meta[r0_l + 4 * c + 2 * part + 1];
        }
        ilv[2 * u4]     = v0;
        ilv[2 * u4 + 1] = v1;
      }
    }
    return;
  }

  __shared__ uint2 sp[64][65];

  for (int p = 0; p < P; ++p)
    sp[l][p] = (p < n_l) ? meta[r0_l + p] : pad_l;
  __syncthreads();

  if (l < P) {
    unsigned long long cs[4]  = {0, 0, 0, 0};
    unsigned long long cp2[4] = {0, 0, 0, 0};
    for (int r = 0; r < 64; ++r) {
      uint2 a = sp[r][l];
      unsigned srcoff = a.x & 0xFFFFu;
      unsigned pdfoff = a.x >> 16;
      const int b0 = (int)((srcoff >> 2) & 31u);
      int bestk = 0, bestc = 256;
#pragma unroll
      for (int k = 0; k < 4; ++k) {
        int bb = (b0 + 8 * k) & 31;
        int c = (int)((cs[bb >> 3] >> ((bb & 7) * 8)) & 0xFFull);
        if (c < bestc) { bestc = c; bestk = k; }
      }
      const int bs = (b0 + 8 * bestk) & 31;
      cs[bs >> 3] += (1ULL << ((bs & 7) * 8));
      const int q0 = (int)((pdfoff >> 2) & 31u);
      const int q1 = (q0 + 8) & 31;
      const int c0 = (int)((cp2[q0 >> 3] >> ((q0 & 7) * 8)) & 0xFFull);
      const int c1 = (int)((cp2[q1 >> 3] >> ((q1 & 7) * 8)) & 0xFFull);
      const int bj = (c1 < c0) ? 1 : 0;
      const int qb = bj ? q1 : q0;
      cp2[qb >> 3] += (1ULL << ((qb & 7) * 8));
      a.x = (srcoff + (unsigned)bestk * 8224u) | ((pdfoff + (unsigned)bj * 12064u) << 16);
      sp[r][l] = a;
    }
  }
  __syncthreads();

  for (int c = 0; c < wmax; ++c) {
    for (int part = 0; part < 2; ++part) {
      int u4 = base4 + c * 128 + part * 64 + l;
      ilv[2 * u4]     = sp[l][4 * c + 2 * part];
      ilv[2 * u4 + 1] = sp[l][4 * c + 2 * part + 1];
    }
  }
}

// ============================ exact row LSE (numerator path) ============================

__device__ __forceinline__ float row_lse(const uint2* __restrict__ meta, int k, int e,
                                         const float* __restrict__ alpha,
                                         const float* __restrict__ lcur) {
  float mm0 = NEG_INF_F, ss0 = 0.0f, mm1 = NEG_INF_F, ss1 = 0.0f;
  const int n4 = (e - k) >> 2;
  const uint4* p = (const uint4*)(meta + k);
  if (n4 > 0) {
    uint4 A = p[0], Bv = p[1];
    float t0 = alpha[A.x & 0xFFFFu] + __uint_as_float(A.y) + lcur[A.x >> 16];
    float t1 = alpha[A.z & 0xFFFFu] + __uint_as_float(A.w) + lcur[A.z >> 16];
    float t2 = alpha[Bv.x & 0xFFFFu] + __uint_as_float(Bv.y) + lcur[Bv.x >> 16];
    float t3 = alpha[Bv.z & 0xFFFFu] + __uint_as_float(Bv.w) + lcur[Bv.z >> 16];
    for (int c2 = 1; c2 < n4; ++c2) {
      uint4 A2 = p[2 * c2], B2 = p[2 * c2 + 1];
      float u0 = alpha[A2.x & 0xFFFFu] + __uint_as_float(A2.y) + lcur[A2.x >> 16];
      float u1 = alpha[A2.z & 0xFFFFu] + __uint_as_float(A2.w) + lcur[A2.z >> 16];
      float u2 = alpha[B2.x & 0xFFFFu] + __uint_as_float(B2.y) + lcur[B2.x >> 16];
      float u3 = alpha[B2.z & 0xFFFFu] + __uint_as_float(B2.w) + lcur[B2.z >> 16];
      float mc = fmaxf(fmaxf(t0, t1), fmaxf(t2, t3));
      if ((c2 & 1) != 0) {
        float nm = fmaxf(mm0, mc);
        ss0 = ss0 * __expf(mm0 - nm) +
              ((__expf(t0 - nm) + __expf(t1 - nm)) + (__expf(t2 - nm) + __expf(t3 - nm)));
        mm0 = nm;
      } else {
        float nm = fmaxf(mm1, mc);
        ss1 = ss1 * __expf(mm1 - nm) +
              ((__expf(t0 - nm) + __expf(t1 - nm)) + (__expf(t2 - nm) + __expf(t3 - nm)));
        mm1 = nm;
      }
      t0 = u0; t1 = u1; t2 = u2; t3 = u3;
    }
    float mc = fmaxf(fmaxf(t0, t1), fmaxf(t2, t3));
    if ((n4 & 1) != 0) {
      float nm = fmaxf(mm0, mc);
      ss0 = ss0 * __expf(mm0 - nm) +
            ((__expf(t0 - nm) + __expf(t1 - nm)) + (__expf(t2 - nm) + __expf(t3 - nm)));
      mm0 = nm;
    } else {
      float nm = fmaxf(mm1, mc);
      ss1 = ss1 * __expf(mm1 - nm) +
            ((__expf(t0 - nm) + __expf(t1 - nm)) + (__expf(t2 - nm) + __expf(t3 - nm)));
      mm1 = nm;
    }
  }
  float nm = fmaxf(mm0, mm1);
  float ssc = ss0 * __expf(mm0 - nm) + ss1 * __expf(mm1 - nm);
  return (ssc > 0.0f) ? (__logf(ssc) + nm) : NEG_INF_F;
}

__device__ __forceinline__ void stage_row(const float* __restrict__ row,
                                          float* __restrict__ lds, int C, int tid, int nt) {
  if (((C & 3) == 0) && ((((uintptr_t)row) & 15) == 0)) {
    const float4* r4 = (const float4*)row;
    const int n = C >> 2;
    for (int i = tid; i < n; i += nt) ((float4*)lds)[i] = r4[i];
  } else {
    for (int i = tid; i < C; i += nt) lds[i] = row[i];
  }
}

// LDS read with pre-scaled byte offset
__device__ __forceinline__ float ldsF(const float* base, unsigned boff) {
  return *(const float*)((const char*)base + boff);
}

#define ACC4(X, Y, s0, s1, s2, s3)                                                         \
  s0 = fmaf(__uint_as_float((X).y), ldsF(vbuf, (X).x & 0xFFFFu) * ldsF(el, (X).x >> 16), s0); \
  s1 = fmaf(__uint_as_float((X).w), ldsF(vbuf, (X).z & 0xFFFFu) * ldsF(el, (X).z >> 16), s1); \
  s2 = fmaf(__uint_as_float((Y).y), ldsF(vbuf, (Y).x & 0xFFFFu) * ldsF(el, (Y).x >> 16), s2); \
  s3 = fmaf(__uint_as_float((Y).w), ldsF(vbuf, (Y).z & 0xFFFFu) * ldsF(el, (Y).z >> 16), s3);

// ============================ forward: den linear-space (replica-choice), num exact-LSE ============================
__global__ __launch_bounds__(1024, 1)
void fsa_forward_lin(const float* __restrict__ ll, const int* __restrict__ seqlen,
                     const uint2* __restrict__ den_meta, const uint4* __restrict__ den_ilv,
                     const int* __restrict__ den_desc,
                     const int* __restrict__ den_rp, const int* __restrict__ den_perm, int S_den,
                     const uint2* __restrict__ num_meta, const int* __restrict__ num_rp,
                     int num_stride, int S_num,
                     const float* __restrict__ den_init, const float* __restrict__ den_final,
                     const float* __restrict__ num_init, const float* __restrict__ num_final,
                     int T, int C, int B, float* __restrict__ out_llh)
{
  __shared__ float alpha[MAX_S];
  __shared__ float vbuf[VB_SIZE];
  __shared__ float elbuf[EL_SIZE];
  __shared__ float red[16];
  __shared__ int   sdesc[66];

  const int tid = threadIdx.x;
  const int nt  = 1024;
  const bool is_den = ((int)blockIdx.x) < B;
  const int b = is_den ? (int)blockIdx.x : ((int)blockIdx.x - B);
  const int S = is_den ? S_den : S_num;
  const float* fin  = is_den ? den_final : num_final;
  const int*   perm = is_den ? den_perm  : nullptr;

  const int L = seqlen[b];
  const float* llb = ll + ((size_t)b * T) * C;

  if (is_den) {
    for (int i = tid; i < 66; i += nt) sdesc[i] = den_desc[i];

    const int w = tid >> 6, l = tid & 63;
    const int slotA = tid;
    const int slotB = 2047 - tid;
    const int rA0 = den_rp[slotA], rA1 = den_rp[slotA + 1];
    const int rB0 = den_rp[slotB], rB1 = den_rp[slotB + 1];
    float a0 = (slotA < S) ? den_init[den_perm[slotA]] : NEG_INF_F;
    float a1 = (slotB < S) ? den_init[den_perm[slotB]] : NEG_INF_F;

    const int nvec = C >> 2;
    const bool pf = ((C & 3) == 0) && ((((uintptr_t)llb) & 15) == 0) &&
                    (nvec <= nt) && (C <= MAX_C);

    float lm = fmaxf(a0, a1);
    for (int off = 32; off; off >>= 1) lm = fmaxf(lm, __shfl_down(lm, off));
    if ((tid & 63) == 0) red[tid >> 6] = lm;
    if (L > 0) {
      if (pf) {
        if (tid < nvec) {
          float4 r = ((const float4*)llb)[tid];
          float4 e = make_float4(__expf(r.x), __expf(r.y), __expf(r.z), __expf(r.w));
          ((float4*)elbuf)[tid] = e;
          ((float4*)(elbuf + EL_COPY))[tid] = e;
        }
      } else {
        for (int i = tid; i < C; i += nt) {
          float e = __expf(llb[i]);
          elbuf[i] = e;
          elbuf[i + EL_COPY] = e;
        }
      }
    }
    __syncthreads();
    float M = red[0];
#pragma unroll
    for (int i = 1; i < 16; ++i) M = fmaxf(M, red[i]);

    const bool ilv_ok = sdesc[64] != 0;
    const uint4* pA4 = den_ilv + sdesc[w] + l;
    const uint4* pB4 = den_ilv + sdesc[16 + w] + l;
    const int nA = sdesc[32 + w], nB = sdesc[48 + w];

    int cur = 0;
    for (int t = 0; t < L; ++t) {
      {
        float va = __expf(a0 - M), vb = __expf(a1 - M);
        vbuf[slotA] = va; vbuf[slotA + 2056] = va;
        vbuf[slotA + 4112] = va; vbuf[slotA + 6168] = va;
        vbuf[slotB] = vb; vbuf[slotB + 2056] = vb;
        vbuf[slotB + 4112] = vb; vbuf[slotB + 6168] = vb;
      }
      __syncthreads();                       // B1: vbuf + elbuf[cur] ready

      const float* el = elbuf + (cur ? EL_BUF : 0);

      float4 nx;
      const bool donx = pf && (t + 1 < L) && (tid < nvec);
      if (donx) nx = ((const float4*)(llb + (size_t)(t + 1) * C))[tid];

      float sA0 = 0, sA1 = 0, sA2 = 0, sA3 = 0;
      float sB0 = 0, sB1 = 0, sB2 = 0, sB3 = 0;
      if (ilv_ok) {
        if (nA > 0) {
          uint4 X0 = pA4[0], Y0 = pA4[64];
          if (nA > 1) {
            uint4 X1 = pA4[128], Y1 = pA4[192];
            for (int c = 2; c < nA; ++c) {
              uint4 X2 = pA4[c * 128], Y2 = pA4[c * 128 + 64];
              ACC4(X0, Y0, sA0, sA1, sA2, sA3);
              X0 = X1; Y0 = Y1; X1 = X2; Y1 = Y2;
            }
            ACC4(X0, Y0, sA0, sA1, sA2, sA3);
            X0 = X1; Y0 = Y1;
          }
          ACC4(X0, Y0, sA0, sA1, sA2, sA3);
        }
        if (nB > 0) {
          uint4 X0 = pB4[0], Y0 = pB4[64];
          for (int c = 1; c < nB; ++c) {
            uint4 X1 = pB4[c * 128], Y1 = pB4[c * 128 + 64];
            ACC4(X0, Y0, sB0, sB1, sB2, sB3);
            X0 = X1; Y0 = Y1;
          }
          ACC4(X0, Y0, sB0, sB1, sB2, sB3);
        }
      } else {
        const uint4* pA = (const uint4*)(den_meta + rA0);
        const uint4* pB = (const uint4*)(den_meta + rB0);
        const int nAr = (rA1 - rA0) >> 2, nBr = (rB1 - rB0) >> 2;
        const int n = nAr > nBr ? nAr : nBr;
        for (int c = 0; c < n; ++c) {
          if (c < nAr) {
            uint4 X = pA[2 * c], Y = pA[2 * c + 1];
            ACC4(X, Y, sA0, sA1, sA2, sA3);
          }
          if (c < nBr) {
            uint4 X = pB[2 * c], Y = pB[2 * c + 1];
            ACC4(X, Y, sB0, sB1, sB2, sB3);
          }
        }
      }
      float sA = (sA0 + sA1) + (sA2 + sA3);
      float sB = (sB0 + sB1) + (sB2 + sB3);

      a0 = (sA > 0.0f) ? (__logf(sA) + M) : NEG_INF_F;
      a1 = (sB > 0.0f) ? (__logf(sB) + M) : NEG_INF_F;

      float* eln = elbuf + (cur ? 0 : EL_BUF);
      if (donx) {
        float4 e = make_float4(__expf(nx.x), __expf(nx.y), __expf(nx.z), __expf(nx.w));
        ((float4*)eln)[tid] = e;
        ((float4*)(eln + EL_COPY))[tid] = e;
      } else if (!pf && t + 1 < L) {
        const float* nr = llb + (size_t)(t + 1) * C;
        for (int i = tid; i < C; i += nt) {
          float e = __expf(nr[i]);
          eln[i] = e;
          eln[i + EL_COPY] = e;
        }
      }

      float lm2 = fmaxf(a0, a1);
      for (int off = 32; off; off >>= 1) lm2 = fmaxf(lm2, __shfl_down(lm2, off));
      if ((tid & 63) == 0) red[tid >> 6] = lm2;
      __syncthreads();                       // B2: sums done, red + elbuf[nxt] visible
      M = red[0];
#pragma unroll
      for (int i = 1; i < 16; ++i) M = fmaxf(M, red[i]);
      cur ^= 1;
    }
    alpha[slotA] = a0;
    alpha[slotB] = a1;
    __syncthreads();
  } else {
    // ---- exact-LSE numerator (tiny) ----
    const uint2* meta = num_meta + (size_t)b * num_stride;
    const int*   rp   = num_rp + (size_t)b * (S_num + 1);
    for (int s = tid; s < MAX_S; s += nt) alpha[s] = (s < S) ? num_init[s] : NEG_INF_F;
    int rs[2] = {0, 0}, re[2] = {0, 0};
    for (int u = 0; u < 2; ++u) {
      int s = tid + u * nt;
      if (s < S) { rs[u] = rp[s]; re[u] = rp[s + 1]; }
    }
    __syncthreads();
    for (int t = 0; t < L; ++t) {
      stage_row(llb + (size_t)t * C, elbuf, C, tid, nt);
      __syncthreads();
      float nv[2];
      for (int u = 0; u < 2; ++u) {
        int s = tid + u * nt;
        nv[u] = (s < S) ? row_lse(meta, rs[u], re[u], alpha, elbuf) : NEG_INF_F;
      }
      __syncthreads();
      for (int u = 0; u < 2; ++u) {
        int s = tid + u * nt;
        if (s < S) alpha[s] = nv[u];
      }
      __syncthreads();
    }
  }

  // final logsumexp(alpha + final_logp)
  float lm = -3.0e38f;
  for (int s = tid; s < S; s += nt) lm = fmaxf(lm, alpha[s] + fin[perm ? perm[s] : s]);
  for (int off = 32; off; off >>= 1) lm = fmaxf(lm, __shfl_down(lm, off));
  if ((tid & 63) == 0) red[tid >> 6] = lm;
  __syncthreads();
  if (tid < 64) {
    float v = (tid < 16) ? red[tid] : -3.0e38f;
    for (int off = 32; off; off >>= 1) v = fmaxf(v, __shfl_down(v, off));
    if (tid == 0) red[0] = v;
  }
  __syncthreads();
  const float M = red[0];

  float ls = 0.0f;
  for (int s = tid; s < S; s += nt) ls += __expf(alpha[s] + fin[perm ? perm[s] : s] - M);
  for (int off = 32; off; off >>= 1) ls += __shfl_down(ls, off);
  __syncthreads();
  if ((tid & 63) == 0) red[tid >> 6] = ls;
  __syncthreads();
  if (tid < 64) {
    float v = (tid < 16) ? red[tid] : 0.0f;
    for (int off = 32; off; off >>= 1) v += __shfl_down(v, off);
    if (tid == 0) out_llh[(is_den ? 0 : B) + b] = __logf(v) + M;
  }
}

// ============================ fallback (atomic path, tiny ws) ============================

__device__ __forceinline__ unsigned enc_f(float x) {
  unsigned u = __float_as_uint(x);
  return u ^ (unsigned)(((int)u >> 31) | 0x80000000);
}
__device__ __forceinline__ float dec_f(unsigned e) {
  unsigned mask = ((int)e >= 0) ? 0xFFFFFFFFu : 0x80000000u;
  return __uint_as_float(e ^ mask);
}

__global__ __launch_bounds__(1024)
void fsa_forward_fallback(
    const float* __restrict__ ll, const int* __restrict__ seqlen,
    const int* __restrict__ den_src, const int* __restrict__ den_dst,
    const int* __restrict__ den_pdf, const float* __restrict__ den_w,
    int A_den, const float* __restrict__ den_init, const float* __restrict__ den_final, int S_den,
    const int* __restrict__ num_src, const int* __restrict__ num_dst,
    const int* __restrict__ num_pdf, const float* __restrict__ num_w,
    int A_num, const float* __restrict__ num_init, const float* __restrict__ num_final, int S_num,
    int T, int C, int B, float* __restrict__ out_llh)
{
  __shared__ float    alpha[MAX_S];
  __shared__ unsigned menc[MAX_S];
  __shared__ float    msafe[MAX_S];
  __shared__ float    ssum[MAX_S];
  __shared__ float    llrow[MAX_C];

  const int tid = threadIdx.x;
  const int nt  = blockDim.x;
  const bool is_den = ((int)blockIdx.x) < B;
  const int b = is_den ? (int)blockIdx.x : ((int)blockIdx.x - B);
  const int S = is_den ? S_den : S_num;
  const int A = is_den ? A_den : A_num;
  const float* init = is_den ? den_init  : num_init;
  const float* fin  = is_den ? den_final : num_final;
  const int*   asrc = is_den ? den_src  : (num_src + (size_t)b * A_num);
  const int*   adst = is_den ? den_dst  : (num_dst + (size_t)b * A_num);
  const int*   apdf = is_den ? den_pdf  : (num_pdf + (size_t)b * A_num);
  const float* aw   = is_den ? den_w    : (num_w   + (size_t)b * A_num);

  for (int s = tid; s < S; s += nt) { alpha[s] = init[s]; menc[s] = 0u; ssum[s] = 0.0f; }
  __syncthreads();

  const int L = seqlen[b];
  const float* llb = ll + ((size_t)b * T) * C;

  for (int t = 0; t < L; ++t) {
    const float* row = llb + (size_t)t * C;
    for (int i = tid; i < C; i += nt) llrow[i] = row[i];
    __syncthreads();
    for (int i = tid; i < A; i += nt) {
      float score = alpha[asrc[i]] + aw[i] + llrow[apdf[i]];
      atomicMax(&menc[adst[i]], enc_f(score));
    }
    __syncthreads();
    for (int s = tid; s < S; s += nt) {
      float m = dec_f(menc[s]);
      msafe[s] = (m > -5e29f) ? m : 0.0f;
    }
    __syncthreads();
    for (int i = tid; i < A; i += nt) {
      int d = adst[i];
      float score = alpha[asrc[i]] + aw[i] + llrow[apdf[i]];
      atomicAdd(&ssum[d], __expf(score - msafe[d]));
    }
    __syncthreads();
    for (int s = tid; s < S; s += nt) {
      float sum = ssum[s];
      alpha[s] = (sum > 0.0f) ? (__logf(sum) + msafe[s]) : NEG_INF_F;
      menc[s] = 0u; ssum[s] = 0.0f;
    }
    __syncthreads();
  }

  float lm = -3.0e38f;
  for (int s = tid; s < S; s += nt) lm = fmaxf(lm, alpha[s] + fin[s]);
  for (int off = 32; off; off >>= 1) lm = fmaxf(lm, __shfl_down(lm, off));
  const int nwaves = nt >> 6;
  if ((tid & 63) == 0) msafe[tid >> 6] = lm;
  __syncthreads();
  if (tid < 64) {
    float v = (tid < nwaves) ? msafe[tid] : -3.0e38f;
    for (int off = 32; off; off >>= 1) v = fmaxf(v, __shfl_down(v, off));
    if (tid == 0) msafe[MAX_S - 1] = v;
  }
  __syncthreads();
  const float M = msafe[MAX_S - 1];
  float ls = 0.0f;
  for (int s = tid; s < S; s += nt) ls += __expf(alpha[s] + fin[s] - M);
  for (int off = 32; off; off >>= 1) ls += __shfl_down(ls, off);
  if ((tid & 63) == 0) ssum[tid >> 6] = ls;
  __syncthreads();
  if (tid < 64) {
    float v = (tid < nwaves) ? ssum[tid] : 0.0f;
    for (int off = 32; off; off >>= 1) v += __shfl_down(v, off);
    if (tid == 0) out_llh[(is_den ? 0 : B) + b] = __logf(v) + M;
  }
}

// loss = sum_b (den_llh[b] - num_llh[b])
__global__ void final_loss_kernel(const float* __restrict__ llh, int B, float* __restrict__ out) {
  int lane = threadIdx.x;
  float v = (lane < B) ? (llh[lane] - llh[B + lane]) : 0.0f;
  for (int off = 32; off; off >>= 1) v += __shfl_down(v, off);
  if (lane == 0) out[0] = v;
}

extern "C" void kernel_launch(void* const* d_in, const int* in_sizes, int n_in,
                              void* d_out, int out_size, void* d_ws, size_t ws_size,
                              hipStream_t stream) {
  const float* ll        = (const float*)d_in[0];
  const int*   seqlen    = (const int*)  d_in[1];
  const int*   num_src   = (const int*)  d_in[2];
  const int*   num_dst   = (const int*)  d_in[3];
  const int*   num_pdf   = (const int*)  d_in[4];
  const float* num_w     = (const float*)d_in[5];
  const float* num_init  = (const float*)d_in[6];
  const float* num_final = (const float*)d_in[7];
  const int*   den_src   = (const int*)  d_in[8];
  const int*   den_dst   = (const int*)  d_in[9];
  const int*   den_pdf   = (const int*)  d_in[10];
  const float* den_w     = (const float*)d_in[11];
  const float* den_init  = (const float*)d_in[12];
  const float* den_final = (const float*)d_in[13];

  const int B     = in_sizes[1];
  const int A_num = in_sizes[2] / B;
  const int S_num = in_sizes[6];
  const int A_den = in_sizes[8];
  const int S_den = in_sizes[12];
  const int T     = 500;                       // problem spec
  const int C     = in_sizes[0] / (B * T);

  const int den_cap    = A_den + 3 * S_den + 64;
  const int num_stride = A_num + 3 * S_num + 64;
  const int cap4       = den_cap + 32768;      // interleaved capacity (uint4 units)

  // workspace layout
  size_t off = 0;
  auto alloc = [&](size_t bytes, size_t align) -> size_t {
    off = (off + align - 1) / align * align;
    size_t r = off; off += bytes; return r;
  };
  size_t o_den_meta = alloc((size_t)den_cap * 8, 16);
  size_t o_den_ilv  = alloc((size_t)cap4 * 16, 16);
  size_t o_desc     = alloc((size_t)66 * 4, 4);
  size_t o_num_meta = alloc((size_t)B * num_stride * 8, 16);
  size_t o_den_rp   = alloc((size_t)2049 * 4, 4);
  size_t o_num_rp   = alloc((size_t)B * (S_num + 1) * 4, 4);
  size_t o_den_cnt  = alloc((size_t)S_den * 4, 4);
  size_t o_perm     = alloc((size_t)2048 * 4, 4);
  size_t o_inv      = alloc((size_t)S_den * 4, 4);
  size_t o_hist     = alloc((size_t)NCH * S_den * 4, 4);
  size_t o_llh      = alloc((size_t)2 * B * 4, 4);
  const bool use_csr = (off <= ws_size) && (S_den >= 1) && (S_den <= 2048) &&
                       (S_num >= 1) && (S_num <= 2048) && (C <= MAX_C) && (C >= 1);

  char* wsb = (char*)d_ws;
  float* llh = (float*)(wsb + (use_csr ? o_llh : 0));

  if (use_csr) {
    uint2* den_meta = (uint2*)(wsb + o_den_meta);
    uint4* den_ilv  = (uint4*)(wsb + o_den_ilv);
    int*   desc     = (int*)(wsb + o_desc);
    uint2* num_meta = (uint2*)(wsb + o_num_meta);
    int*   den_rp   = (int*)(wsb + o_den_rp);
    int*   num_rp   = (int*)(wsb + o_num_rp);
    int*   den_cnt  = (int*)(wsb + o_den_cnt);
    int*   perm     = (int*)(wsb + o_perm);
    int*   inv      = (int*)(wsb + o_inv);
    int*   hist     = (int*)(wsb + o_hist);

    const int chunk = (A_den + NCH - 1) / NCH;

    hist_chunk_kernel<<<NCH, 256, 0, stream>>>(den_dst, A_den, chunk, S_den, hist);
    den_stats_kernel<<<1, 1024, 0, stream>>>(den_dst, A_den, S_den, cap4,
                                             den_rp, perm, inv, den_cnt, desc);
    offpad_kernel<<<(S_den + 255) / 256, 256, 0, stream>>>(hist, NCH, S_den, den_rp, perm,
                                                           den_cnt, C, den_meta);
    fill_chunk_kernel<<<dim3((S_den + 255) / 256, NCH), 256, 0, stream>>>(
        den_src, den_dst, den_pdf, den_w, A_den, chunk, S_den, hist, inv, den_meta);
    num_build_kernel<<<B, 256, 0, stream>>>(num_src, num_dst, num_pdf, num_w,
                                            A_num, S_num, num_rp, num_meta, num_stride);
    repack_choice_kernel<<<32, 64, 0, stream>>>(den_meta, den_rp, desc, C, (uint2*)den_ilv);

    fsa_forward_lin<<<2 * B, 1024, 0, stream>>>(
        ll, seqlen, den_meta, den_ilv, desc, den_rp, perm, S_den,
        num_meta, num_rp, num_stride, S_num,
        den_init, den_final, num_init, num_final, T, C, B, llh);
  } else {
    fsa_forward_fallback<<<2 * B, 1024, 0, stream>>>(
        ll, seqlen,
        den_src, den_dst, den_pdf, den_w, A_den, den_init, den_final, S_den,
        num_src, num_dst, num_pdf, num_w, A_num, num_init, num_final, S_num,
        T, C, B, llh);
  }

  final_loss_kernel<<<1, 64, 0, stream>>>(llh, B, (float*)d_out);
}